// Round 1
// baseline (15344.624 us; speedup 1.0000x reference)
//
#include <hip/hip_runtime.h>
#include <hip/hip_bf16.h>

// Performer (FAVOR+) classifier forward, f32 baseline.
// DEPTH=4, HEADS=2, DH=32, DE=64, N=16384, B=8, F=110, DFF=256, K=10

constexpr int B_   = 8;
constexpr int N_   = 16384;
constexpr int DE_  = 64;
constexpr int F_   = 110;
constexpr int NTOK = B_ * N_;          // 131072
constexpr float DN    = 0.42044820762685725f;   // 32^-0.25
constexpr float RATIO = 0.09534625892455922f;   // 110^-0.5
constexpr float KEPS  = 1e-4f;

__device__ __forceinline__ float wsum64(float v) {
#pragma unroll
  for (int m = 32; m > 0; m >>= 1) v += __shfl_xor(v, m);
  return v;
}
__device__ __forceinline__ float wsum32(float v) {
#pragma unroll
  for (int m = 16; m > 0; m >>= 1) v += __shfl_xor(v, m);
  return v;
}
__device__ __forceinline__ float wmax64(float v) {
#pragma unroll
  for (int m = 32; m > 0; m >>= 1) v = fmaxf(v, __shfl_xor(v, m));
  return v;
}
// uniform-lane broadcast via readlane (scalar pipe, not LDS)
__device__ __forceinline__ float bcastf(float v, int lane) {
  return __uint_as_float((unsigned)__builtin_amdgcn_readlane((int)__float_as_uint(v), lane));
}

// ---------------- h = concat(emb_w, x) ----------------
__global__ __launch_bounds__(256) void k_embed(const float* __restrict__ x,
                                               const float* __restrict__ emb,
                                               float* __restrict__ hbuf) {
  int gidx = blockIdx.x * 256 + threadIdx.x;
  int tok = gidx >> 6, c = gidx & 63;
  float v;
  if (c < 63) v = emb[(size_t)(tok & (N_ - 1)) * 63 + c];
  else        v = x[tok];
  hbuf[gidx] = v;
}

// ---------------- LN + K,V projection + global max of dd_k ----------------
__global__ __launch_bounds__(512) void k_ln_kv(
    const float* __restrict__ hbuf, const float* __restrict__ lng, const float* __restrict__ lnb,
    const float* __restrict__ wk, const float* __restrict__ bk,
    const float* __restrict__ wv, const float* __restrict__ bv,
    const float* __restrict__ proj,
    float* __restrict__ kout, float* __restrict__ vout, unsigned int* __restrict__ kmaxu) {
  __shared__ float wk_s[64 * 64];
  __shared__ float wv_s[64 * 64];
  __shared__ float proj_s[F_ * 33];
  __shared__ float kd_s[8][4][64];
  __shared__ float wm_s[8];
  const int tid = threadIdx.x, w = tid >> 6, j = tid & 63;
  for (int i = tid; i < 64 * 64; i += 512) { wk_s[i] = wk[i]; wv_s[i] = wv[i]; }
  for (int i = tid; i < F_ * 32; i += 512) proj_s[(i >> 5) * 33 + (i & 31)] = proj[i];
  const float gj = lng[j], bj = lnb[j], bkj = bk[j], bvj = bv[j];
  __syncthreads();
  const int tokbase = blockIdx.x * 128 + w * 16;
  float mymax = -3.0e38f;
  for (int q4 = 0; q4 < 4; q4++) {
    const int t0 = tokbase + q4 * 4;
    float yv[4], acck[4], accv[4];
#pragma unroll
    for (int u = 0; u < 4; u++) {
      float hj = hbuf[(size_t)(t0 + u) * 64 + j];
      float mu = wsum64(hj) * (1.f / 64.f);
      float d = hj - mu;
      float var = wsum64(d * d) * (1.f / 64.f);
      yv[u] = d * rsqrtf(var + 1e-5f) * gj + bj;
      acck[u] = bkj; accv[u] = bvj;
    }
    for (int i = 0; i < 64; i++) {
      float wki = wk_s[i * 64 + j], wvi = wv_s[i * 64 + j];
#pragma unroll
      for (int u = 0; u < 4; u++) {
        float yi = bcastf(yv[u], i);
        acck[u] += yi * wki;
        accv[u] += yi * wvi;
      }
    }
#pragma unroll
    for (int u = 0; u < 4; u++) {
      float kd = acck[u] * DN;
      kout[(size_t)(t0 + u) * 64 + j] = kd;   // store k*dn directly
      vout[(size_t)(t0 + u) * 64 + j] = accv[u];
      kd_s[w][u][j] = kd;
    }
    __syncthreads();
#pragma unroll
    for (int t2 = 0; t2 < 4; t2++) {
      int idx = j + 64 * t2;
      if (idx < 220) {
        int head = (idx >= 110);
        int f = idx - head * 110;
        const float* pr = &proj_s[f * 33];
        float dd0 = 0, dd1 = 0, dd2 = 0, dd3 = 0;
#pragma unroll
        for (int d = 0; d < 32; d++) {
          float p = pr[d];
          int a = head * 32 + d;
          dd0 += kd_s[w][0][a] * p;
          dd1 += kd_s[w][1][a] * p;
          dd2 += kd_s[w][2][a] * p;
          dd3 += kd_s[w][3][a] * p;
        }
        mymax = fmaxf(mymax, fmaxf(fmaxf(dd0, dd1), fmaxf(dd2, dd3)));
      }
    }
    __syncthreads();
  }
  mymax = wmax64(mymax);
  if (j == 0) wm_s[w] = mymax;
  __syncthreads();
  if (tid == 0) {
    float m = wm_s[0];
    for (int i = 1; i < 8; i++) m = fmaxf(m, wm_s[i]);
    unsigned u_ = __float_as_uint(m);
    unsigned mm = (u_ & 0x80000000u) ? ~u_ : (u_ | 0x80000000u);
    atomicMax(kmaxu, mm);
  }
}

// ---------------- kp features + ctx / ksum accumulation ----------------
__global__ __launch_bounds__(256) void k_kp_ctx(
    const float* __restrict__ kdbuf, const float* __restrict__ vbuf,
    const float* __restrict__ proj, const unsigned int* __restrict__ kmaxu,
    float* __restrict__ ksum_g, float* __restrict__ ctx_g) {
  __shared__ float proj_s[F_ * 33];
  __shared__ float k_s[16][65];
  __shared__ float v_s[16][64];
  __shared__ float kp_s[16][224];
  __shared__ float diag_s[16][2];
  const int tid = threadIdx.x;
  for (int i = tid; i < F_ * 32; i += 256) proj_s[(i >> 5) * 33 + (i & 31)] = proj[i];
  unsigned mu = *kmaxu;
  float M = (mu & 0x80000000u) ? __uint_as_float(mu ^ 0x80000000u) : __uint_as_float(~mu);
  float acc[28];
#pragma unroll
  for (int r = 0; r < 28; r++) acc[r] = 0.f;
  float ksacc = 0.f;
  const int tok0 = blockIdx.x * 128;
  const int b = tok0 >> 14;
  const int hd = tid & 63;
  const int head_o = hd >> 5;
  const int fbase = tid >> 6;      // 0..3
  const int ldt = tid >> 4;        // load: token
  const int ldc = (tid & 15) * 4;  // load: col group
  __syncthreads();
  for (int g8 = 0; g8 < 8; g8++) {
    const int t0 = tok0 + g8 * 16;
    float4 k4 = *(const float4*)(kdbuf + (size_t)(t0 + ldt) * 64 + ldc);
    float4 v4 = *(const float4*)(vbuf + (size_t)(t0 + ldt) * 64 + ldc);
    k_s[ldt][ldc + 0] = k4.x; k_s[ldt][ldc + 1] = k4.y;
    k_s[ldt][ldc + 2] = k4.z; k_s[ldt][ldc + 3] = k4.w;
    *(float4*)(&v_s[ldt][ldc]) = v4;
    __syncthreads();
    if (tid < 32) {
      int tk = tid >> 1, hh = tid & 1;
      const float* kk = &k_s[tk][hh * 32];
      float s = 0.f;
      for (int d = 0; d < 32; d++) { float t = kk[d]; s += t * t; }
      diag_s[tk][hh] = 0.5f * s;
    }
    __syncthreads();
#pragma unroll
    for (int r = 0; r < 14; r++) {
      int o = tid + (r << 8);
      int tk = o / 224;
      int rest = o - tk * 224;
      int hh = rest / 112;
      int f = rest - hh * 112;
      float val = 0.f;
      if (f < F_) {
        const float* pr = &proj_s[f * 33];
        const float* kk = &k_s[tk][hh * 32];
        float dd = 0.f;
#pragma unroll
        for (int d = 0; d < 32; d++) dd += kk[d] * pr[d];
        val = RATIO * (__expf(dd - diag_s[tk][hh] - M) + KEPS);
      }
      kp_s[tk][rest] = val;
    }
    __syncthreads();
    if (tid < 224) {
#pragma unroll
      for (int tk = 0; tk < 16; tk++) ksacc += kp_s[tk][tid];
    }
#pragma unroll
    for (int tk = 0; tk < 16; tk++) {
      float vv = v_s[tk][hd];
      const float* kpt = &kp_s[tk][head_o * 112 + fbase];
#pragma unroll
      for (int r = 0; r < 28; r++) acc[r] += kpt[4 * r] * vv;
    }
    __syncthreads();
  }
  if (tid < 224) {
    int hh = tid / 112, f = tid - hh * 112;
    if (f < F_) atomicAdd(&ksum_g[(b * 2 + hh) * F_ + f], ksacc);
  }
  const int dcol = hd & 31;
#pragma unroll
  for (int r = 0; r < 28; r++) {
    int f = fbase + 4 * r;
    if (f < F_) atomicAdd(&ctx_g[((size_t)(b * 2 + head_o) * F_ + f) * 32 + dcol], acc[r]);
  }
}

// ---------------- Q path + o = qp@ctx + out-proj + residual ----------------
__global__ __launch_bounds__(512) void k_attn_out(
    float* __restrict__ hbuf, const float* __restrict__ lng, const float* __restrict__ lnb,
    const float* __restrict__ wq, const float* __restrict__ bq,
    const float* __restrict__ wo, const float* __restrict__ bo,
    const float* __restrict__ proj, const float* __restrict__ ksum_g,
    const float* __restrict__ ctx_g) {
  __shared__ float wq_s[64 * 64];
  __shared__ float wo_s[64 * 64];
  __shared__ float proj_s[F_ * 33];
  __shared__ float ctx_s[F_ * 64];
  __shared__ float ksum_s[224];
  __shared__ float q_s[8][4][64];
  __shared__ float qp_s[8][224];
  const int tid = threadIdx.x, w = tid >> 6, j = tid & 63;
  const int b = (blockIdx.x * 128) >> 14;
  for (int i = tid; i < 64 * 64; i += 512) { wq_s[i] = wq[i]; wo_s[i] = wo[i]; }
  for (int i = tid; i < F_ * 32; i += 512) proj_s[(i >> 5) * 33 + (i & 31)] = proj[i];
  for (int i = tid; i < F_ * 64; i += 512) {
    int f = i >> 6, c = i & 63, hh = c >> 5, d = c & 31;
    ctx_s[i] = ctx_g[((size_t)(b * 2 + hh) * F_ + f) * 32 + d];
  }
  if (tid < 224) {
    int hh = tid / 112, f = tid - hh * 112;
    ksum_s[tid] = (f < F_) ? ksum_g[(b * 2 + hh) * F_ + f] : 0.f;
  }
  const float gj = lng[j], bj = lnb[j], bqj = bq[j], boj = bo[j];
  __syncthreads();
  const int tokbase = blockIdx.x * 128 + w * 16;
  for (int q4 = 0; q4 < 4; q4++) {
    const int t0 = tokbase + q4 * 4;
    float yv[4], horig[4], accq[4], oreg[4];
#pragma unroll
    for (int u = 0; u < 4; u++) {
      float hj = hbuf[(size_t)(t0 + u) * 64 + j];
      horig[u] = hj;
      float mu = wsum64(hj) * (1.f / 64.f);
      float d = hj - mu;
      float var = wsum64(d * d) * (1.f / 64.f);
      yv[u] = d * rsqrtf(var + 1e-5f) * gj + bj;
      accq[u] = bqj;
    }
    for (int i = 0; i < 64; i++) {
      float wqi = wq_s[i * 64 + j];
#pragma unroll
      for (int u = 0; u < 4; u++) accq[u] += bcastf(yv[u], i) * wqi;
    }
#pragma unroll
    for (int u = 0; u < 4; u++) {
      float qd = accq[u] * DN;
      q_s[w][u][j] = qd;
      accq[u] = qd;
    }
    __syncthreads();
#pragma unroll
    for (int u = 0; u < 4; u++) {
      float qd = accq[u];
      float ds_ = wsum32(qd * qd) * 0.5f;          // per-half (per-head) diag
      float diag0 = bcastf(ds_, 0), diag1 = bcastf(ds_, 32);
      float dd[4];
      float m0 = -3e38f, m1 = -3e38f;
#pragma unroll
      for (int t2 = 0; t2 < 4; t2++) {
        int idx = j + 64 * t2;
        float v = 0.f;
        if (idx < 220) {
          int head = idx >= 110;
          int f = idx - head * 110;
          const float* pr = &proj_s[f * 33];
          const float* qs = &q_s[w][u][head * 32];
#pragma unroll
          for (int d = 0; d < 32; d++) v += qs[d] * pr[d];
          if (head) m1 = fmaxf(m1, v); else m0 = fmaxf(m0, v);
        }
        dd[t2] = v;
      }
      m0 = wmax64(m0); m1 = wmax64(m1);
      float s0 = 0.f, s1 = 0.f;
#pragma unroll
      for (int t2 = 0; t2 < 4; t2++) {
        int idx = j + 64 * t2;
        if (idx < 220) {
          int head = idx >= 110;
          int f = idx - head * 110;
          float e = RATIO * (__expf(dd[t2] - (head ? diag1 : diag0) - (head ? m1 : m0)) + KEPS);
          qp_s[w][head * 112 + f] = e;
          float kss = ksum_s[head * 112 + f];
          if (head) s1 += e * kss; else s0 += e * kss;
        }
      }
      float dinv0 = 1.f / wsum64(s0);
      float dinv1 = 1.f / wsum64(s1);
      __syncthreads();
      const int hj_ = j >> 5;
      const float* qp = &qp_s[w][hj_ * 112];
      const float* cx = &ctx_s[j];
      float o = 0.f;
      for (int f = 0; f < F_; f++) o += qp[f] * cx[f * 64];
      oreg[u] = o * (hj_ ? dinv1 : dinv0);
    }
    float accA[4];
#pragma unroll
    for (int u = 0; u < 4; u++) accA[u] = boj;
    for (int i = 0; i < 64; i++) {
      float woi = wo_s[i * 64 + j];
#pragma unroll
      for (int u = 0; u < 4; u++) accA[u] += bcastf(oreg[u], i) * woi;
    }
#pragma unroll
    for (int u = 0; u < 4; u++)
      hbuf[(size_t)(t0 + u) * 64 + j] = horig[u] + accA[u];
    __syncthreads();
  }
}

// ---------------- feed-forward: h += gelu(LN(h)@w1+b1)@w2+b2 ----------------
__global__ __launch_bounds__(512) void k_ff(
    float* __restrict__ hbuf, const float* __restrict__ lng, const float* __restrict__ lnb,
    const float* __restrict__ w1, const float* __restrict__ b1,
    const float* __restrict__ w2, const float* __restrict__ b2) {
  __shared__ float wbuf[64 * 256];
  const int tid = threadIdx.x, w = tid >> 6, j = tid & 63;
  for (int i = tid; i < 64 * 256; i += 512) wbuf[i] = w1[i];
  const float gj = lng[j], bj = lnb[j], b2j = b2[j];
  float b1j[4];
#pragma unroll
  for (int cs = 0; cs < 4; cs++) b1j[cs] = b1[j + 64 * cs];
  __syncthreads();
  const int tokbase = blockIdx.x * 64 + w * 8;
  float t1r[2][4][4];   // [quad][col-slot][token]
  float horig[2][4];
#pragma unroll
  for (int qd = 0; qd < 2; qd++) {
    const int t0 = tokbase + qd * 4;
    float yv[4];
#pragma unroll
    for (int u = 0; u < 4; u++) {
      float hj = hbuf[(size_t)(t0 + u) * 64 + j];
      horig[qd][u] = hj;
      float mu = wsum64(hj) * (1.f / 64.f);
      float d = hj - mu;
      float var = wsum64(d * d) * (1.f / 64.f);
      yv[u] = d * rsqrtf(var + 1e-5f) * gj + bj;
    }
    float acc1[4][4];
#pragma unroll
    for (int cs = 0; cs < 4; cs++)
#pragma unroll
      for (int u = 0; u < 4; u++) acc1[cs][u] = b1j[cs];
    for (int i = 0; i < 64; i++) {
      float y0 = bcastf(yv[0], i), y1 = bcastf(yv[1], i);
      float y2 = bcastf(yv[2], i), y3 = bcastf(yv[3], i);
#pragma unroll
      for (int cs = 0; cs < 4; cs++) {
        float wv_ = wbuf[i * 256 + j + 64 * cs];
        acc1[cs][0] += y0 * wv_; acc1[cs][1] += y1 * wv_;
        acc1[cs][2] += y2 * wv_; acc1[cs][3] += y3 * wv_;
      }
    }
#pragma unroll
    for (int cs = 0; cs < 4; cs++)
#pragma unroll
      for (int u = 0; u < 4; u++) {
        float t = acc1[cs][u];
        t1r[qd][cs][u] = 0.5f * t * (1.f + erff(t * 0.70710678118654752f));
      }
  }
  __syncthreads();
  for (int i = tid; i < 256 * 64; i += 512) wbuf[i] = w2[i];
  __syncthreads();
#pragma unroll
  for (int qd = 0; qd < 2; qd++) {
    const int t0 = tokbase + qd * 4;
    float acc2[4];
#pragma unroll
    for (int u = 0; u < 4; u++) acc2[u] = b2j;
#pragma unroll
    for (int cs = 0; cs < 4; cs++) {
      for (int sl = 0; sl < 64; sl++) {
        float wv_ = wbuf[(cs * 64 + sl) * 64 + j];
        acc2[0] += bcastf(t1r[qd][cs][0], sl) * wv_;
        acc2[1] += bcastf(t1r[qd][cs][1], sl) * wv_;
        acc2[2] += bcastf(t1r[qd][cs][2], sl) * wv_;
        acc2[3] += bcastf(t1r[qd][cs][3], sl) * wv_;
      }
    }
#pragma unroll
    for (int u = 0; u < 4; u++)
      hbuf[(size_t)(t0 + u) * 64 + j] = horig[qd][u] + acc2[u];
  }
}

// ---------------- mean over N (partial) ----------------
__global__ __launch_bounds__(256) void k_colsum(const float* __restrict__ hbuf,
                                                float* __restrict__ colsum) {
  __shared__ float red[256];
  int bb = blockIdx.x >> 3, chunk = blockIdx.x & 7;
  int t = threadIdx.x;
  int c = t & 63, r0 = t >> 6;
  size_t base = ((size_t)bb * N_ + chunk * 2048 + r0) * 64 + c;
  float acc = 0.f;
  for (int s = 0; s < 512; s++) acc += hbuf[base + (size_t)s * 256];
  red[t] = acc;
  __syncthreads();
  if (t < 64) {
    float tot = red[t] + red[t + 64] + red[t + 128] + red[t + 192];
    atomicAdd(&colsum[bb * 64 + t], tot);
  }
}

// ---------------- classifier ----------------
__global__ __launch_bounds__(128) void k_logits(const float* __restrict__ colsum,
                                                const float* __restrict__ cw,
                                                const float* __restrict__ cb,
                                                float* __restrict__ out) {
  int t = threadIdx.x;
  if (t < 80) {
    int b = t / 10, kk = t - b * 10;
    float acc = 0.f;
    for (int c = 0; c < 64; c++) acc += colsum[b * 64 + c] * cw[c * 10 + kk];
    out[t] = acc * (1.f / 16384.f) + cb[kk];
  }
}

extern "C" void kernel_launch(void* const* d_in, const int* in_sizes, int n_in,
                              void* d_out, int out_size, void* d_ws, size_t ws_size,
                              hipStream_t stream) {
  const float* x    = (const float*)d_in[0];
  const float* emb  = (const float*)d_in[1];
  const float* ln1g = (const float*)d_in[2];
  const float* ln1b = (const float*)d_in[3];
  const float* wq   = (const float*)d_in[4];
  const float* bq   = (const float*)d_in[5];
  const float* wk   = (const float*)d_in[6];
  const float* bk   = (const float*)d_in[7];
  const float* wv   = (const float*)d_in[8];
  const float* bv   = (const float*)d_in[9];
  const float* wo   = (const float*)d_in[10];
  const float* bo   = (const float*)d_in[11];
  const float* proj = (const float*)d_in[12];
  const float* ln2g = (const float*)d_in[13];
  const float* ln2b = (const float*)d_in[14];
  const float* w1   = (const float*)d_in[15];
  const float* b1   = (const float*)d_in[16];
  const float* w2   = (const float*)d_in[17];
  const float* b2   = (const float*)d_in[18];
  const float* cw   = (const float*)d_in[19];
  const float* cb   = (const float*)d_in[20];

  float* h      = (float*)d_ws;                   // NTOK*64
  float* kb     = h + (size_t)NTOK * 64;          // NTOK*64 (stores k*dn)
  float* vb     = kb + (size_t)NTOK * 64;         // NTOK*64
  float* ctx    = vb + (size_t)NTOK * 64;         // 16*110*32
  float* ksum   = ctx + 16 * F_ * 32;             // 16*110
  unsigned* kmaxu = (unsigned*)(ksum + 16 * F_);  // 1
  float* colsum = (float*)(kmaxu + 1);            // 512

  // zero ctx + ksum + kmax + colsum (0 bits == 0.0f; kmax mapped-uint init 0 is < any real)
  hipMemsetAsync(ctx, 0, (size_t)(16 * F_ * 32 + 16 * F_ + 1 + 512) * sizeof(float), stream);
  k_embed<<<NTOK * 64 / 256, 256, 0, stream>>>(x, emb, h);
  for (int l = 0; l < 4; l++) {
    if (l) hipMemsetAsync(ctx, 0, (size_t)(16 * F_ * 32 + 16 * F_ + 1) * sizeof(float), stream);
    k_ln_kv<<<NTOK / 128, 512, 0, stream>>>(h, ln1g + 64 * l, ln1b + 64 * l,
                                            wk + 4096 * l, bk + 64 * l,
                                            wv + 4096 * l, bv + 64 * l,
                                            proj + 3520 * l, kb, vb, kmaxu);
    k_kp_ctx<<<NTOK / 128, 256, 0, stream>>>(kb, vb, proj + 3520 * l, kmaxu, ksum, ctx);
    k_attn_out<<<NTOK / 128, 512, 0, stream>>>(h, ln1g + 64 * l, ln1b + 64 * l,
                                               wq + 4096 * l, bq + 64 * l,
                                               wo + 4096 * l, bo + 64 * l,
                                               proj + 3520 * l, ksum, ctx);
    k_ff<<<NTOK / 64, 512, 0, stream>>>(h, ln2g + 64 * l, ln2b + 64 * l,
                                        w1 + 16384 * l, b1 + 256 * l,
                                        w2 + 16384 * l, b2 + 64 * l);
  }
  k_colsum<<<64, 256, 0, stream>>>(h, colsum);
  k_logits<<<1, 128, 0, stream>>>(colsum, cw, cb, (float*)d_out);
}

// Round 3
// 5753.527 us; speedup vs baseline: 2.6670x; 2.6670x over previous
//
#include <hip/hip_runtime.h>
#include <hip/hip_bf16.h>

// Performer (FAVOR+) classifier forward, f32, round 2 resubmit (round-1 infra fail).
// DEPTH=4, HEADS=2, DH=32, DE=64, N=16384, B=8, F=110, DFF=256, K=10

constexpr int B_   = 8;
constexpr int N_   = 16384;
constexpr int F_   = 110;
constexpr int NTOK = B_ * N_;          // 131072
constexpr float DN    = 0.42044820762685725f;   // 32^-0.25
constexpr float RATIO = 0.09534625892455922f;   // 110^-0.5
constexpr float KEPS  = 1e-4f;

__device__ __forceinline__ float wsum64(float v) {
#pragma unroll
  for (int m = 32; m > 0; m >>= 1) v += __shfl_xor(v, m);
  return v;
}
__device__ __forceinline__ float wsum32(float v) {
#pragma unroll
  for (int m = 16; m > 0; m >>= 1) v += __shfl_xor(v, m);
  return v;
}
__device__ __forceinline__ float wmax64(float v) {
#pragma unroll
  for (int m = 32; m > 0; m >>= 1) v = fmaxf(v, __shfl_xor(v, m));
  return v;
}
__device__ __forceinline__ float bcastf(float v, int lane) {
  return __uint_as_float((unsigned)__builtin_amdgcn_readlane((int)__float_as_uint(v), lane));
}

// ---------------- h = concat(emb_w, x) ----------------
__global__ __launch_bounds__(256) void k_embed(const float* __restrict__ x,
                                               const float* __restrict__ emb,
                                               float* __restrict__ hbuf) {
  int gidx = blockIdx.x * 256 + threadIdx.x;
  int tok = gidx >> 6, c = gidx & 63;
  float v;
  if (c < 63) v = emb[(size_t)(tok & (N_ - 1)) * 63 + c];
  else        v = x[tok];
  hbuf[gidx] = v;
}

// ---------------- LN + K,V projection + global max of dd_k ----------------
__global__ __launch_bounds__(512) void k_ln_kv(
    const float* __restrict__ hbuf, const float* __restrict__ lng, const float* __restrict__ lnb,
    const float* __restrict__ wk, const float* __restrict__ bk,
    const float* __restrict__ wv, const float* __restrict__ bv,
    const float* __restrict__ proj,
    float* __restrict__ kout, float* __restrict__ vout, unsigned int* __restrict__ kmaxu) {
  __shared__ float wk_s[64 * 64];
  __shared__ float wv_s[64 * 64];
  __shared__ float proj_s[F_ * 33];
  __shared__ float kd_s[8][4][64];
  __shared__ float wm_s[8];
  const int tid = threadIdx.x, w = tid >> 6, j = tid & 63;
  for (int i = tid; i < 64 * 64; i += 512) { wk_s[i] = wk[i]; wv_s[i] = wv[i]; }
  for (int i = tid; i < F_ * 32; i += 512) proj_s[(i >> 5) * 33 + (i & 31)] = proj[i];
  const float gj = lng[j], bj = lnb[j], bkj = bk[j], bvj = bv[j];
  __syncthreads();
  const int tokbase = blockIdx.x * 128 + w * 16;
  float mymax = -3.0e38f;
  for (int q4 = 0; q4 < 4; q4++) {
    const int t0 = tokbase + q4 * 4;
    float yv[4], acck[4], accv[4];
#pragma unroll
    for (int u = 0; u < 4; u++) {
      float hj = hbuf[(size_t)(t0 + u) * 64 + j];
      float mu = wsum64(hj) * (1.f / 64.f);
      float d = hj - mu;
      float var = wsum64(d * d) * (1.f / 64.f);
      yv[u] = d * rsqrtf(var + 1e-5f) * gj + bj;
      acck[u] = bkj; accv[u] = bvj;
    }
    for (int i = 0; i < 64; i++) {
      float wki = wk_s[i * 64 + j], wvi = wv_s[i * 64 + j];
#pragma unroll
      for (int u = 0; u < 4; u++) {
        float yi = bcastf(yv[u], i);
        acck[u] += yi * wki;
        accv[u] += yi * wvi;
      }
    }
#pragma unroll
    for (int u = 0; u < 4; u++) {
      float kd = acck[u] * DN;
      kout[(size_t)(t0 + u) * 64 + j] = kd;   // store k*dn directly
      vout[(size_t)(t0 + u) * 64 + j] = accv[u];
      kd_s[w][u][j] = kd;                     // wave-private: lockstep, no barrier
    }
#pragma unroll
    for (int t2 = 0; t2 < 4; t2++) {
      int idx = j + 64 * t2;
      if (idx < 220) {
        int head = (idx >= 110);
        int f = idx - head * 110;
        const float* pr = &proj_s[f * 33];
        const float* kk = &kd_s[w][0][head * 32];
        float dd0 = 0, dd1 = 0, dd2 = 0, dd3 = 0;
#pragma unroll 8
        for (int d = 0; d < 32; d++) {
          float p = pr[d];
          dd0 += kk[d]       * p;
          dd1 += kk[d + 64]  * p;
          dd2 += kk[d + 128] * p;
          dd3 += kk[d + 192] * p;
        }
        mymax = fmaxf(mymax, fmaxf(fmaxf(dd0, dd1), fmaxf(dd2, dd3)));
      }
    }
  }
  mymax = wmax64(mymax);
  if (j == 0) wm_s[w] = mymax;
  __syncthreads();
  if (tid == 0) {
    float m = wm_s[0];
    for (int i = 1; i < 8; i++) m = fmaxf(m, wm_s[i]);
    unsigned u_ = __float_as_uint(m);
    unsigned mm = (u_ & 0x80000000u) ? ~u_ : (u_ | 0x80000000u);
    atomicMax(kmaxu, mm);
  }
}

// ---------------- kp features + ctx / ksum accumulation ----------------
__global__ __launch_bounds__(256) void k_kp_ctx(
    const float* __restrict__ kdbuf, const float* __restrict__ vbuf,
    const float* __restrict__ proj, const unsigned int* __restrict__ kmaxu,
    float* __restrict__ ksum_g, float* __restrict__ ctx_g) {
  __shared__ float proj_s[F_ * 33];
  __shared__ float k_s[16][65];
  __shared__ float v_s[16][64];
  __shared__ float kp_s[16][224];
  __shared__ float diag_s[16][2];
  const int tid = threadIdx.x;
  for (int i = tid; i < F_ * 32; i += 256) proj_s[(i >> 5) * 33 + (i & 31)] = proj[i];
  unsigned mu = *kmaxu;
  float M = (mu & 0x80000000u) ? __uint_as_float(mu ^ 0x80000000u) : __uint_as_float(~mu);
  float acc[28];
#pragma unroll
  for (int r = 0; r < 28; r++) acc[r] = 0.f;
  float ksacc = 0.f;
  const int tok0 = blockIdx.x * 128;
  const int b = tok0 >> 14;
  const int hd = tid & 63;
  const int head_o = hd >> 5;
  const int fbase = tid >> 6;      // 0..3
  const int ldt = tid >> 4;        // load: token
  const int ldc = (tid & 15) * 4;  // load: col group
  const int kp_hh = (tid < 112) ? 0 : 1;
  const int kp_f  = tid - kp_hh * 112;
  const bool kp_act = (tid < 224) && (kp_f < F_);
  __syncthreads();
  for (int g8 = 0; g8 < 8; g8++) {
    const int t0 = tok0 + g8 * 16;
    float4 k4 = *(const float4*)(kdbuf + (size_t)(t0 + ldt) * 64 + ldc);
    float4 v4 = *(const float4*)(vbuf + (size_t)(t0 + ldt) * 64 + ldc);
    k_s[ldt][ldc + 0] = k4.x; k_s[ldt][ldc + 1] = k4.y;
    k_s[ldt][ldc + 2] = k4.z; k_s[ldt][ldc + 3] = k4.w;
    *(float4*)(&v_s[ldt][ldc]) = v4;
    __syncthreads();
    if (tid < 32) {
      int tk = tid >> 1, hh = tid & 1;
      const float* kk = &k_s[tk][hh * 32];
      float s = 0.f;
#pragma unroll 8
      for (int d = 0; d < 32; d++) { float t = kk[d]; s += t * t; }
      diag_s[tk][hh] = 0.5f * s;
    }
    __syncthreads();
    if (tid < 224) {
      const float* pr = &proj_s[kp_f * 33];
      for (int tk = 0; tk < 16; tk++) {
        float val = 0.f;
        if (kp_act) {
          const float* kk = &k_s[tk][kp_hh * 32];
          float dd = 0.f;
#pragma unroll 8
          for (int d = 0; d < 32; d++) dd += kk[d] * pr[d];
          val = RATIO * (__expf(dd - diag_s[tk][kp_hh] - M) + KEPS);
        }
        kp_s[tk][tid] = val;
      }
    }
    __syncthreads();
    if (tid < 224) {
#pragma unroll
      for (int tk = 0; tk < 16; tk++) ksacc += kp_s[tk][tid];
    }
#pragma unroll
    for (int tk = 0; tk < 16; tk++) {
      float vv = v_s[tk][hd];
      const float* kpt = &kp_s[tk][head_o * 112 + fbase];
#pragma unroll
      for (int r = 0; r < 28; r++) acc[r] += kpt[4 * r] * vv;
    }
    __syncthreads();
  }
  if (tid < 224) {
    int hh = tid / 112, f = tid - hh * 112;
    if (f < F_) atomicAdd(&ksum_g[(b * 2 + hh) * F_ + f], ksacc);
  }
  const int dcol = hd & 31;
#pragma unroll
  for (int r = 0; r < 28; r++) {
    int f = fbase + 4 * r;
    if (f < F_) atomicAdd(&ctx_g[((size_t)(b * 2 + head_o) * F_ + f) * 32 + dcol], acc[r]);
  }
}

// ---------------- Q path: o = (qp @ ctx) * d_inv  (pre-out-proj) ----------------
__global__ __launch_bounds__(512) void k_qo(
    const float* __restrict__ hbuf, const float* __restrict__ lng, const float* __restrict__ lnb,
    const float* __restrict__ wq, const float* __restrict__ bq,
    const float* __restrict__ proj, const float* __restrict__ ksum_g,
    const float* __restrict__ ctx_g, float* __restrict__ ob) {
  __shared__ float wq_s[64 * 64];      // 16 KB
  __shared__ float proj_s[F_ * 33];    // 14.5 KB
  __shared__ float ctx_s[F_ * 64];     // 28 KB
  __shared__ float ksum_s[224];
  __shared__ float q_s[8][4][64];      // 8 KB, wave-private rows
  __shared__ float qp_s[8][224];       // 7 KB, wave-private rows
  const int tid = threadIdx.x, w = tid >> 6, j = tid & 63;
  const int b = (blockIdx.x * 128) >> 14;
  for (int i = tid; i < 64 * 64; i += 512) wq_s[i] = wq[i];
  for (int i = tid; i < F_ * 32; i += 512) proj_s[(i >> 5) * 33 + (i & 31)] = proj[i];
  for (int i = tid; i < F_ * 64; i += 512) {
    int f = i >> 6, c = i & 63, hh = c >> 5, d = c & 31;
    ctx_s[i] = ctx_g[((size_t)(b * 2 + hh) * F_ + f) * 32 + d];
  }
  if (tid < 224) {
    int hh = tid / 112, f = tid - hh * 112;
    ksum_s[tid] = (f < F_) ? ksum_g[(b * 2 + hh) * F_ + f] : 0.f;
  }
  const float gj = lng[j], bj = lnb[j], bqj = bq[j];
  __syncthreads();   // staging only; everything below is wave-private
  const int tokbase = blockIdx.x * 128 + w * 16;
  const int hj_ = j >> 5;
  for (int q4 = 0; q4 < 4; q4++) {
    const int t0 = tokbase + q4 * 4;
    float yv[4], accq[4];
#pragma unroll
    for (int u = 0; u < 4; u++) {
      float hj = hbuf[(size_t)(t0 + u) * 64 + j];
      float mu = wsum64(hj) * (1.f / 64.f);
      float d = hj - mu;
      float var = wsum64(d * d) * (1.f / 64.f);
      yv[u] = d * rsqrtf(var + 1e-5f) * gj + bj;
      accq[u] = bqj;
    }
    for (int i = 0; i < 64; i++) {
      float wqi = wq_s[i * 64 + j];
#pragma unroll
      for (int u = 0; u < 4; u++) accq[u] += bcastf(yv[u], i) * wqi;
    }
#pragma unroll
    for (int u = 0; u < 4; u++) {
      accq[u] *= DN;
      q_s[w][u][j] = accq[u];
    }
#pragma unroll
    for (int u = 0; u < 4; u++) {
      float qd = accq[u];
      float ds_ = wsum32(qd * qd) * 0.5f;          // per-head diag
      float diag0 = bcastf(ds_, 0), diag1 = bcastf(ds_, 32);
      float dd[4];
      float m0 = -3e38f, m1 = -3e38f;
#pragma unroll
      for (int t2 = 0; t2 < 4; t2++) {
        int idx = j + 64 * t2;
        float v = 0.f;
        if (idx < 220) {
          int head = idx >= 110;
          int f = idx - head * 110;
          const float* pr = &proj_s[f * 33];
          const float* qs = &q_s[w][u][head * 32];
#pragma unroll 8
          for (int d = 0; d < 32; d++) v += qs[d] * pr[d];
          if (head) m1 = fmaxf(m1, v); else m0 = fmaxf(m0, v);
        }
        dd[t2] = v;
      }
      m0 = wmax64(m0); m1 = wmax64(m1);
      float s0 = 0.f, s1 = 0.f;
#pragma unroll
      for (int t2 = 0; t2 < 4; t2++) {
        int idx = j + 64 * t2;
        if (idx < 220) {
          int head = idx >= 110;
          int f = idx - head * 110;
          float e = RATIO * (__expf(dd[t2] - (head ? diag1 : diag0) - (head ? m1 : m0)) + KEPS);
          qp_s[w][head * 112 + f] = e;
          float kss = ksum_s[head * 112 + f];
          if (head) s1 += e * kss; else s0 += e * kss;
        }
      }
      float dinv0 = 1.f / wsum64(s0);
      float dinv1 = 1.f / wsum64(s1);
      const float* qp = &qp_s[w][hj_ * 112];
      const float* cx = &ctx_s[j];
      float o = 0.f;
#pragma unroll 11
      for (int f = 0; f < F_; f++) o += qp[f] * cx[f * 64];
      ob[(size_t)(t0 + u) * 64 + j] = o * (hj_ ? dinv1 : dinv0);
    }
  }
}

// -------- fused: h += o@wo+bo;  y=LN2(h);  h += gelu(y@w1+b1)@w2+b2 --------
__global__ __launch_bounds__(512) void k_wo_ff(
    float* __restrict__ hbuf, const float* __restrict__ ob,
    const float* __restrict__ wo, const float* __restrict__ bo,
    const float* __restrict__ lng, const float* __restrict__ lnb,
    const float* __restrict__ w1, const float* __restrict__ b1,
    const float* __restrict__ w2, const float* __restrict__ b2) {
  __shared__ float wbuf[64 * 256];  // 64 KB, reused for wo -> w1 -> w2
  const int tid = threadIdx.x, w = tid >> 6, j = tid & 63;
  const int tokbase = blockIdx.x * 64 + w * 8;
  const float gj = lng[j], bj = lnb[j], boj = bo[j], b2j = b2[j];
  float b1j[4];
#pragma unroll
  for (int cs = 0; cs < 4; cs++) b1j[cs] = b1[j + 64 * cs];
  // ---- phase A: out-projection + residual + LN2 ----
  for (int i = tid; i < 64 * 64; i += 512) wbuf[i] = wo[i];
  float hA[2][4], ov[2][4], yv[2][4];
#pragma unroll
  for (int qd = 0; qd < 2; qd++)
#pragma unroll
    for (int u = 0; u < 4; u++) {
      size_t idx = (size_t)(tokbase + qd * 4 + u) * 64 + j;
      hA[qd][u] = hbuf[idx];
      ov[qd][u] = ob[idx];
    }
  __syncthreads();
#pragma unroll
  for (int qd = 0; qd < 2; qd++) {
    float acc[4];
#pragma unroll
    for (int u = 0; u < 4; u++) acc[u] = boj;
    for (int i = 0; i < 64; i++) {
      float w_ = wbuf[i * 64 + j];
#pragma unroll
      for (int u = 0; u < 4; u++) acc[u] += bcastf(ov[qd][u], i) * w_;
    }
#pragma unroll
    for (int u = 0; u < 4; u++) {
      hA[qd][u] += acc[u];
      float hj = hA[qd][u];
      float mu = wsum64(hj) * (1.f / 64.f);
      float d = hj - mu;
      float var = wsum64(d * d) * (1.f / 64.f);
      yv[qd][u] = d * rsqrtf(var + 1e-5f) * gj + bj;
    }
  }
  __syncthreads();
  // ---- phase B: t1 = gelu(y @ w1 + b1) ----
  for (int i = tid; i < 64 * 256; i += 512) wbuf[i] = w1[i];
  __syncthreads();
  float t1r[2][4][4];   // [quad][col-slot][token]
#pragma unroll
  for (int qd = 0; qd < 2; qd++) {
    float acc1[4][4];
#pragma unroll
    for (int cs = 0; cs < 4; cs++)
#pragma unroll
      for (int u = 0; u < 4; u++) acc1[cs][u] = b1j[cs];
    for (int i = 0; i < 64; i++) {
      float y0 = bcastf(yv[qd][0], i), y1 = bcastf(yv[qd][1], i);
      float y2 = bcastf(yv[qd][2], i), y3 = bcastf(yv[qd][3], i);
#pragma unroll
      for (int cs = 0; cs < 4; cs++) {
        float wv_ = wbuf[i * 256 + j + 64 * cs];
        acc1[cs][0] += y0 * wv_; acc1[cs][1] += y1 * wv_;
        acc1[cs][2] += y2 * wv_; acc1[cs][3] += y3 * wv_;
      }
    }
#pragma unroll
    for (int cs = 0; cs < 4; cs++)
#pragma unroll
      for (int u = 0; u < 4; u++) {
        float t = acc1[cs][u];
        t1r[qd][cs][u] = 0.5f * t * (1.f + erff(t * 0.70710678118654752f));
      }
  }
  __syncthreads();
  // ---- phase C: h = hA + t1 @ w2 + b2 ----
  for (int i = tid; i < 256 * 64; i += 512) wbuf[i] = w2[i];
  __syncthreads();
#pragma unroll
  for (int qd = 0; qd < 2; qd++) {
    float acc2[4];
#pragma unroll
    for (int u = 0; u < 4; u++) acc2[u] = b2j;
#pragma unroll
    for (int cs = 0; cs < 4; cs++) {
      for (int sl = 0; sl < 64; sl++) {
        float wv_ = wbuf[(cs * 64 + sl) * 64 + j];
        acc2[0] += bcastf(t1r[qd][cs][0], sl) * wv_;
        acc2[1] += bcastf(t1r[qd][cs][1], sl) * wv_;
        acc2[2] += bcastf(t1r[qd][cs][2], sl) * wv_;
        acc2[3] += bcastf(t1r[qd][cs][3], sl) * wv_;
      }
    }
#pragma unroll
    for (int u = 0; u < 4; u++)
      hbuf[(size_t)(tokbase + qd * 4 + u) * 64 + j] = hA[qd][u] + acc2[u];
  }
}

// ---------------- mean over N (partial) ----------------
__global__ __launch_bounds__(256) void k_colsum(const float* __restrict__ hbuf,
                                                float* __restrict__ colsum) {
  __shared__ float red[256];
  int bb = blockIdx.x >> 3, chunk = blockIdx.x & 7;
  int t = threadIdx.x;
  int c = t & 63, r0 = t >> 6;
  size_t base = ((size_t)bb * N_ + chunk * 2048 + r0) * 64 + c;
  float acc = 0.f;
  for (int s = 0; s < 512; s++) acc += hbuf[base + (size_t)s * 256];
  red[t] = acc;
  __syncthreads();
  if (t < 64) {
    float tot = red[t] + red[t + 64] + red[t + 128] + red[t + 192];
    atomicAdd(&colsum[bb * 64 + t], tot);
  }
}

// ---------------- classifier ----------------
__global__ __launch_bounds__(128) void k_logits(const float* __restrict__ colsum,
                                                const float* __restrict__ cw,
                                                const float* __restrict__ cb,
                                                float* __restrict__ out) {
  int t = threadIdx.x;
  if (t < 80) {
    int b = t / 10, kk = t - b * 10;
    float acc = 0.f;
    for (int c = 0; c < 64; c++) acc += colsum[b * 64 + c] * cw[c * 10 + kk];
    out[t] = acc * (1.f / 16384.f) + cb[kk];
  }
}

extern "C" void kernel_launch(void* const* d_in, const int* in_sizes, int n_in,
                              void* d_out, int out_size, void* d_ws, size_t ws_size,
                              hipStream_t stream) {
  const float* x    = (const float*)d_in[0];
  const float* emb  = (const float*)d_in[1];
  const float* ln1g = (const float*)d_in[2];
  const float* ln1b = (const float*)d_in[3];
  const float* wq   = (const float*)d_in[4];
  const float* bq   = (const float*)d_in[5];
  const float* wk   = (const float*)d_in[6];
  const float* bk   = (const float*)d_in[7];
  const float* wv   = (const float*)d_in[8];
  const float* bv   = (const float*)d_in[9];
  const float* wo   = (const float*)d_in[10];
  const float* bo   = (const float*)d_in[11];
  const float* proj = (const float*)d_in[12];
  const float* ln2g = (const float*)d_in[13];
  const float* ln2b = (const float*)d_in[14];
  const float* w1   = (const float*)d_in[15];
  const float* b1   = (const float*)d_in[16];
  const float* w2   = (const float*)d_in[17];
  const float* b2   = (const float*)d_in[18];
  const float* cw   = (const float*)d_in[19];
  const float* cb   = (const float*)d_in[20];

  float* h      = (float*)d_ws;                   // NTOK*64
  float* kb     = h + (size_t)NTOK * 64;          // NTOK*64 (k*dn, later reused as ob)
  float* vb     = kb + (size_t)NTOK * 64;         // NTOK*64
  float* ctx    = vb + (size_t)NTOK * 64;         // 16*110*32
  float* ksum   = ctx + 16 * F_ * 32;             // 16*110
  unsigned* kmaxu = (unsigned*)(ksum + 16 * F_);  // 1
  float* colsum = (float*)(kmaxu + 1);            // 512

  hipMemsetAsync(ctx, 0, (size_t)(16 * F_ * 32 + 16 * F_ + 1 + 512) * sizeof(float), stream);
  k_embed<<<NTOK * 64 / 256, 256, 0, stream>>>(x, emb, h);
  for (int l = 0; l < 4; l++) {
    if (l) hipMemsetAsync(ctx, 0, (size_t)(16 * F_ * 32 + 16 * F_ + 1) * sizeof(float), stream);
    k_ln_kv<<<NTOK / 128, 512, 0, stream>>>(h, ln1g + 64 * l, ln1b + 64 * l,
                                            wk + 4096 * l, bk + 64 * l,
                                            wv + 4096 * l, bv + 64 * l,
                                            proj + 3520 * l, kb, vb, kmaxu);
    k_kp_ctx<<<NTOK / 128, 256, 0, stream>>>(kb, vb, proj + 3520 * l, kmaxu, ksum, ctx);
    k_qo<<<NTOK / 128, 512, 0, stream>>>(h, ln1g + 64 * l, ln1b + 64 * l,
                                         wq + 4096 * l, bq + 64 * l,
                                         proj + 3520 * l, ksum, ctx, kb);
    k_wo_ff<<<NTOK / 64, 512, 0, stream>>>(h, kb, wo + 4096 * l, bo + 64 * l,
                                           ln2g + 64 * l, ln2b + 64 * l,
                                           w1 + 16384 * l, b1 + 256 * l,
                                           w2 + 16384 * l, b2 + 64 * l);
  }
  k_colsum<<<64, 256, 0, stream>>>(h, colsum);
  k_logits<<<1, 128, 0, stream>>>(colsum, cw, cb, (float*)d_out);
}

// Round 4
// 4101.162 us; speedup vs baseline: 3.7415x; 1.4029x over previous
//
#include <hip/hip_runtime.h>
#include <hip/hip_bf16.h>

// Performer (FAVOR+) classifier forward, f32, round 3: spill-free fused wo+FF.
// DEPTH=4, HEADS=2, DH=32, DE=64, N=16384, B=8, F=110, DFF=256, K=10

constexpr int B_   = 8;
constexpr int N_   = 16384;
constexpr int F_   = 110;
constexpr int NTOK = B_ * N_;          // 131072
constexpr float DN    = 0.42044820762685725f;   // 32^-0.25
constexpr float RATIO = 0.09534625892455922f;   // 110^-0.5
constexpr float KEPS  = 1e-4f;

__device__ __forceinline__ float wsum64(float v) {
#pragma unroll
  for (int m = 32; m > 0; m >>= 1) v += __shfl_xor(v, m);
  return v;
}
__device__ __forceinline__ float wsum32(float v) {
#pragma unroll
  for (int m = 16; m > 0; m >>= 1) v += __shfl_xor(v, m);
  return v;
}
__device__ __forceinline__ float wmax64(float v) {
#pragma unroll
  for (int m = 32; m > 0; m >>= 1) v = fmaxf(v, __shfl_xor(v, m));
  return v;
}
__device__ __forceinline__ float bcastf(float v, int lane) {
  return __uint_as_float((unsigned)__builtin_amdgcn_readlane((int)__float_as_uint(v), lane));
}

// ---------------- h = concat(emb_w, x) ----------------
__global__ __launch_bounds__(256) void k_embed(const float* __restrict__ x,
                                               const float* __restrict__ emb,
                                               float* __restrict__ hbuf) {
  int gidx = blockIdx.x * 256 + threadIdx.x;
  int tok = gidx >> 6, c = gidx & 63;
  float v;
  if (c < 63) v = emb[(size_t)(tok & (N_ - 1)) * 63 + c];
  else        v = x[tok];
  hbuf[gidx] = v;
}

// ---------------- LN + K,V projection + global max of dd_k ----------------
__global__ __launch_bounds__(512) void k_ln_kv(
    const float* __restrict__ hbuf, const float* __restrict__ lng, const float* __restrict__ lnb,
    const float* __restrict__ wk, const float* __restrict__ bk,
    const float* __restrict__ wv, const float* __restrict__ bv,
    const float* __restrict__ proj,
    float* __restrict__ kout, float* __restrict__ vout, unsigned int* __restrict__ kmaxu) {
  __shared__ float wk_s[64 * 64];
  __shared__ float wv_s[64 * 64];
  __shared__ float proj_s[F_ * 33];
  __shared__ float kd_s[8][4][64];
  __shared__ float wm_s[8];
  const int tid = threadIdx.x, w = tid >> 6, j = tid & 63;
  for (int i = tid; i < 64 * 64; i += 512) { wk_s[i] = wk[i]; wv_s[i] = wv[i]; }
  for (int i = tid; i < F_ * 32; i += 512) proj_s[(i >> 5) * 33 + (i & 31)] = proj[i];
  const float gj = lng[j], bj = lnb[j], bkj = bk[j], bvj = bv[j];
  __syncthreads();
  const int tokbase = blockIdx.x * 128 + w * 16;
  float mymax = -3.0e38f;
  for (int q4 = 0; q4 < 4; q4++) {
    const int t0 = tokbase + q4 * 4;
    float yv[4], acck[4], accv[4];
#pragma unroll
    for (int u = 0; u < 4; u++) {
      float hj = hbuf[(size_t)(t0 + u) * 64 + j];
      float mu = wsum64(hj) * (1.f / 64.f);
      float d = hj - mu;
      float var = wsum64(d * d) * (1.f / 64.f);
      yv[u] = d * rsqrtf(var + 1e-5f) * gj + bj;
      acck[u] = bkj; accv[u] = bvj;
    }
    for (int i = 0; i < 64; i++) {
      float wki = wk_s[i * 64 + j], wvi = wv_s[i * 64 + j];
#pragma unroll
      for (int u = 0; u < 4; u++) {
        float yi = bcastf(yv[u], i);
        acck[u] += yi * wki;
        accv[u] += yi * wvi;
      }
    }
#pragma unroll
    for (int u = 0; u < 4; u++) {
      float kd = acck[u] * DN;
      kout[(size_t)(t0 + u) * 64 + j] = kd;   // store k*dn directly
      vout[(size_t)(t0 + u) * 64 + j] = accv[u];
      kd_s[w][u][j] = kd;                     // wave-private: lockstep, no barrier
    }
#pragma unroll
    for (int t2 = 0; t2 < 4; t2++) {
      int idx = j + 64 * t2;
      if (idx < 220) {
        int head = (idx >= 110);
        int f = idx - head * 110;
        const float* pr = &proj_s[f * 33];
        const float* kk = &kd_s[w][0][head * 32];
        float dd0 = 0, dd1 = 0, dd2 = 0, dd3 = 0;
#pragma unroll 8
        for (int d = 0; d < 32; d++) {
          float p = pr[d];
          dd0 += kk[d]       * p;
          dd1 += kk[d + 64]  * p;
          dd2 += kk[d + 128] * p;
          dd3 += kk[d + 192] * p;
        }
        mymax = fmaxf(mymax, fmaxf(fmaxf(dd0, dd1), fmaxf(dd2, dd3)));
      }
    }
  }
  mymax = wmax64(mymax);
  if (j == 0) wm_s[w] = mymax;
  __syncthreads();
  if (tid == 0) {
    float m = wm_s[0];
    for (int i = 1; i < 8; i++) m = fmaxf(m, wm_s[i]);
    unsigned u_ = __float_as_uint(m);
    unsigned mm = (u_ & 0x80000000u) ? ~u_ : (u_ | 0x80000000u);
    atomicMax(kmaxu, mm);
  }
}

// ---------------- kp features + ctx / ksum accumulation ----------------
__global__ __launch_bounds__(256) void k_kp_ctx(
    const float* __restrict__ kdbuf, const float* __restrict__ vbuf,
    const float* __restrict__ proj, const unsigned int* __restrict__ kmaxu,
    float* __restrict__ ksum_g, float* __restrict__ ctx_g) {
  __shared__ float proj_s[F_ * 33];
  __shared__ float k_s[16][65];
  __shared__ float v_s[16][64];
  __shared__ float kp_s[16][224];
  __shared__ float diag_s[16][2];
  const int tid = threadIdx.x;
  for (int i = tid; i < F_ * 32; i += 256) proj_s[(i >> 5) * 33 + (i & 31)] = proj[i];
  unsigned mu = *kmaxu;
  float M = (mu & 0x80000000u) ? __uint_as_float(mu ^ 0x80000000u) : __uint_as_float(~mu);
  float acc[28];
#pragma unroll
  for (int r = 0; r < 28; r++) acc[r] = 0.f;
  float ksacc = 0.f;
  const int tok0 = blockIdx.x * 128;
  const int b = tok0 >> 14;
  const int hd = tid & 63;
  const int head_o = hd >> 5;
  const int fbase = tid >> 6;      // 0..3
  const int ldt = tid >> 4;        // load: token
  const int ldc = (tid & 15) * 4;  // load: col group
  const int kp_hh = (tid < 112) ? 0 : 1;
  const int kp_f  = tid - kp_hh * 112;
  const bool kp_act = (tid < 224) && (kp_f < F_);
  __syncthreads();
  for (int g8 = 0; g8 < 8; g8++) {
    const int t0 = tok0 + g8 * 16;
    float4 k4 = *(const float4*)(kdbuf + (size_t)(t0 + ldt) * 64 + ldc);
    float4 v4 = *(const float4*)(vbuf + (size_t)(t0 + ldt) * 64 + ldc);
    k_s[ldt][ldc + 0] = k4.x; k_s[ldt][ldc + 1] = k4.y;
    k_s[ldt][ldc + 2] = k4.z; k_s[ldt][ldc + 3] = k4.w;
    *(float4*)(&v_s[ldt][ldc]) = v4;
    __syncthreads();
    if (tid < 32) {
      int tk = tid >> 1, hh = tid & 1;
      const float* kk = &k_s[tk][hh * 32];
      float s = 0.f;
#pragma unroll 8
      for (int d = 0; d < 32; d++) { float t = kk[d]; s += t * t; }
      diag_s[tk][hh] = 0.5f * s;
    }
    __syncthreads();
    if (tid < 224) {
      const float* pr = &proj_s[kp_f * 33];
      for (int tk = 0; tk < 16; tk++) {
        float val = 0.f;
        if (kp_act) {
          const float* kk = &k_s[tk][kp_hh * 32];
          float dd = 0.f;
#pragma unroll 8
          for (int d = 0; d < 32; d++) dd += kk[d] * pr[d];
          val = RATIO * (__expf(dd - diag_s[tk][kp_hh] - M) + KEPS);
        }
        kp_s[tk][tid] = val;
      }
    }
    __syncthreads();
    if (tid < 224) {
#pragma unroll
      for (int tk = 0; tk < 16; tk++) ksacc += kp_s[tk][tid];
    }
#pragma unroll
    for (int tk = 0; tk < 16; tk++) {
      float vv = v_s[tk][hd];
      const float* kpt = &kp_s[tk][head_o * 112 + fbase];
#pragma unroll
      for (int r = 0; r < 28; r++) acc[r] += kpt[4 * r] * vv;
    }
    __syncthreads();
  }
  if (tid < 224) {
    int hh = tid / 112, f = tid - hh * 112;
    if (f < F_) atomicAdd(&ksum_g[(b * 2 + hh) * F_ + f], ksacc);
  }
  const int dcol = hd & 31;
#pragma unroll
  for (int r = 0; r < 28; r++) {
    int f = fbase + 4 * r;
    if (f < F_) atomicAdd(&ctx_g[((size_t)(b * 2 + head_o) * F_ + f) * 32 + dcol], acc[r]);
  }
}

// ---------------- Q path: o = (qp @ ctx) * d_inv  (pre-out-proj) ----------------
__global__ __launch_bounds__(512) void k_qo(
    const float* __restrict__ hbuf, const float* __restrict__ lng, const float* __restrict__ lnb,
    const float* __restrict__ wq, const float* __restrict__ bq,
    const float* __restrict__ proj, const float* __restrict__ ksum_g,
    const float* __restrict__ ctx_g, float* __restrict__ ob) {
  __shared__ float wq_s[64 * 64];      // 16 KB
  __shared__ float proj_s[F_ * 33];    // 14.5 KB
  __shared__ float ctx_s[F_ * 64];     // 28 KB
  __shared__ float ksum_s[224];
  __shared__ float q_s[8][4][64];      // 8 KB, wave-private rows
  __shared__ float qp_s[8][224];       // 7 KB, wave-private rows
  const int tid = threadIdx.x, w = tid >> 6, j = tid & 63;
  const int b = (blockIdx.x * 128) >> 14;
  for (int i = tid; i < 64 * 64; i += 512) wq_s[i] = wq[i];
  for (int i = tid; i < F_ * 32; i += 512) proj_s[(i >> 5) * 33 + (i & 31)] = proj[i];
  for (int i = tid; i < F_ * 64; i += 512) {
    int f = i >> 6, c = i & 63, hh = c >> 5, d = c & 31;
    ctx_s[i] = ctx_g[((size_t)(b * 2 + hh) * F_ + f) * 32 + d];
  }
  if (tid < 224) {
    int hh = tid / 112, f = tid - hh * 112;
    ksum_s[tid] = (f < F_) ? ksum_g[(b * 2 + hh) * F_ + f] : 0.f;
  }
  const float gj = lng[j], bj = lnb[j], bqj = bq[j];
  __syncthreads();   // staging only; everything below is wave-private
  const int tokbase = blockIdx.x * 128 + w * 16;
  const int hj_ = j >> 5;
  for (int q4 = 0; q4 < 4; q4++) {
    const int t0 = tokbase + q4 * 4;
    float yv[4], accq[4];
#pragma unroll
    for (int u = 0; u < 4; u++) {
      float hj = hbuf[(size_t)(t0 + u) * 64 + j];
      float mu = wsum64(hj) * (1.f / 64.f);
      float d = hj - mu;
      float var = wsum64(d * d) * (1.f / 64.f);
      yv[u] = d * rsqrtf(var + 1e-5f) * gj + bj;
      accq[u] = bqj;
    }
    for (int i = 0; i < 64; i++) {
      float wqi = wq_s[i * 64 + j];
#pragma unroll
      for (int u = 0; u < 4; u++) accq[u] += bcastf(yv[u], i) * wqi;
    }
#pragma unroll
    for (int u = 0; u < 4; u++) {
      accq[u] *= DN;
      q_s[w][u][j] = accq[u];
    }
#pragma unroll
    for (int u = 0; u < 4; u++) {
      float qd = accq[u];
      float ds_ = wsum32(qd * qd) * 0.5f;          // per-head diag
      float diag0 = bcastf(ds_, 0), diag1 = bcastf(ds_, 32);
      float dd[4];
      float m0 = -3e38f, m1 = -3e38f;
#pragma unroll
      for (int t2 = 0; t2 < 4; t2++) {
        int idx = j + 64 * t2;
        float v = 0.f;
        if (idx < 220) {
          int head = idx >= 110;
          int f = idx - head * 110;
          const float* pr = &proj_s[f * 33];
          const float* qs = &q_s[w][u][head * 32];
#pragma unroll 8
          for (int d = 0; d < 32; d++) v += qs[d] * pr[d];
          if (head) m1 = fmaxf(m1, v); else m0 = fmaxf(m0, v);
        }
        dd[t2] = v;
      }
      m0 = wmax64(m0); m1 = wmax64(m1);
      float s0 = 0.f, s1 = 0.f;
#pragma unroll
      for (int t2 = 0; t2 < 4; t2++) {
        int idx = j + 64 * t2;
        if (idx < 220) {
          int head = idx >= 110;
          int f = idx - head * 110;
          float e = RATIO * (__expf(dd[t2] - (head ? diag1 : diag0) - (head ? m1 : m0)) + KEPS);
          qp_s[w][head * 112 + f] = e;
          float kss = ksum_s[head * 112 + f];
          if (head) s1 += e * kss; else s0 += e * kss;
        }
      }
      float dinv0 = 1.f / wsum64(s0);
      float dinv1 = 1.f / wsum64(s1);
      const float* qp = &qp_s[w][hj_ * 112];
      const float* cx = &ctx_s[j];
      float o = 0.f;
#pragma unroll 11
      for (int f = 0; f < F_; f++) o += qp[f] * cx[f * 64];
      ob[(size_t)(t0 + u) * 64 + j] = o * (hj_ ? dinv1 : dinv0);
    }
  }
}

// -------- fused, spill-free: h += o@wo+bo;  y=LN2(h);  h += gelu(y@w1+b1)@w2+b2 --------
// FF processed in 4 column-slots of 64: w1-slot + w2-slot staged together (48 KB LDS
// total), t1 consumed into acc2 before any barrier -> persistent state = 48 VGPRs.
__global__ __launch_bounds__(512, 4) void k_wo_ff(
    float* __restrict__ hbuf, const float* __restrict__ ob,
    const float* __restrict__ wo, const float* __restrict__ bo,
    const float* __restrict__ lng, const float* __restrict__ lnb,
    const float* __restrict__ w1, const float* __restrict__ b1,
    const float* __restrict__ w2, const float* __restrict__ b2) {
  __shared__ float wo_s[64 * 64];   // 16 KB, persistent
  __shared__ float w1_s[64 * 64];   // 16 KB, current column-slot of w1
  __shared__ float w2_s[64 * 64];   // 16 KB, current row-slot of w2
  const int tid = threadIdx.x, w = tid >> 6, j = tid & 63;
  const int tokbase = blockIdx.x * 128 + w * 16;   // 16 tokens per wave
  const float gj = lng[j], bj = lnb[j], boj = bo[j], b2j = b2[j];
  for (int i = tid; i < 4096; i += 512) wo_s[i] = wo[i];
  float hA[16], yv[16], acc2[16];
  __syncthreads();
  // ---- phase A: out-projection + residual + LN2 ----
#pragma unroll
  for (int q = 0; q < 4; q++) {
    const int t0 = tokbase + q * 4;
    float ovq[4], acc[4];
#pragma unroll
    for (int u = 0; u < 4; u++) {
      size_t idx = (size_t)(t0 + u) * 64 + j;
      hA[q * 4 + u] = hbuf[idx];
      ovq[u] = ob[idx];
      acc[u] = boj;
    }
#pragma unroll 8
    for (int i = 0; i < 64; i++) {
      float w_ = wo_s[i * 64 + j];
#pragma unroll
      for (int u = 0; u < 4; u++) acc[u] += bcastf(ovq[u], i) * w_;
    }
#pragma unroll
    for (int u = 0; u < 4; u++) {
      float hj = hA[q * 4 + u] + acc[u];
      hA[q * 4 + u] = hj;
      float mu = wsum64(hj) * (1.f / 64.f);
      float d = hj - mu;
      float var = wsum64(d * d) * (1.f / 64.f);
      yv[q * 4 + u] = d * rsqrtf(var + 1e-5f) * gj + bj;
      acc2[q * 4 + u] = b2j;
    }
  }
  // ---- FF: 4 column-slots of 64, t1 consumed immediately (no spill) ----
  for (int cs = 0; cs < 4; cs++) {
    __syncthreads();  // previous slot fully consumed
    for (int i = tid; i < 4096; i += 512) {
      w1_s[i] = w1[(i >> 6) * 256 + cs * 64 + (i & 63)];
      w2_s[i] = w2[cs * 4096 + i];
    }
    const float b1v = b1[cs * 64 + j];
    __syncthreads();  // slot ready
#pragma unroll
    for (int q = 0; q < 4; q++) {
      float acc1[4], t1[4];
#pragma unroll
      for (int u = 0; u < 4; u++) acc1[u] = b1v;
#pragma unroll 8
      for (int i = 0; i < 64; i++) {
        float wv_ = w1_s[i * 64 + j];
#pragma unroll
        for (int u = 0; u < 4; u++) acc1[u] += bcastf(yv[q * 4 + u], i) * wv_;
      }
#pragma unroll
      for (int u = 0; u < 4; u++) {
        float t = acc1[u];
        t1[u] = 0.5f * t * (1.f + erff(t * 0.70710678118654752f));
      }
#pragma unroll 8
      for (int sl = 0; sl < 64; sl++) {
        float wv_ = w2_s[sl * 64 + j];
#pragma unroll
        for (int u = 0; u < 4; u++) acc2[q * 4 + u] += bcastf(t1[u], sl) * wv_;
      }
    }
  }
#pragma unroll
  for (int q = 0; q < 4; q++)
#pragma unroll
    for (int u = 0; u < 4; u++)
      hbuf[(size_t)(tokbase + q * 4 + u) * 64 + j] = hA[q * 4 + u] + acc2[q * 4 + u];
}

// ---------------- mean over N (partial) ----------------
__global__ __launch_bounds__(256) void k_colsum(const float* __restrict__ hbuf,
                                                float* __restrict__ colsum) {
  __shared__ float red[256];
  int bb = blockIdx.x >> 3, chunk = blockIdx.x & 7;
  int t = threadIdx.x;
  int c = t & 63, r0 = t >> 6;
  size_t base = ((size_t)bb * N_ + chunk * 2048 + r0) * 64 + c;
  float acc = 0.f;
  for (int s = 0; s < 512; s++) acc += hbuf[base + (size_t)s * 256];
  red[t] = acc;
  __syncthreads();
  if (t < 64) {
    float tot = red[t] + red[t + 64] + red[t + 128] + red[t + 192];
    atomicAdd(&colsum[bb * 64 + t], tot);
  }
}

// ---------------- classifier ----------------
__global__ __launch_bounds__(128) void k_logits(const float* __restrict__ colsum,
                                                const float* __restrict__ cw,
                                                const float* __restrict__ cb,
                                                float* __restrict__ out) {
  int t = threadIdx.x;
  if (t < 80) {
    int b = t / 10, kk = t - b * 10;
    float acc = 0.f;
    for (int c = 0; c < 64; c++) acc += colsum[b * 64 + c] * cw[c * 10 + kk];
    out[t] = acc * (1.f / 16384.f) + cb[kk];
  }
}

extern "C" void kernel_launch(void* const* d_in, const int* in_sizes, int n_in,
                              void* d_out, int out_size, void* d_ws, size_t ws_size,
                              hipStream_t stream) {
  const float* x    = (const float*)d_in[0];
  const float* emb  = (const float*)d_in[1];
  const float* ln1g = (const float*)d_in[2];
  const float* ln1b = (const float*)d_in[3];
  const float* wq   = (const float*)d_in[4];
  const float* bq   = (const float*)d_in[5];
  const float* wk   = (const float*)d_in[6];
  const float* bk   = (const float*)d_in[7];
  const float* wv   = (const float*)d_in[8];
  const float* bv   = (const float*)d_in[9];
  const float* wo   = (const float*)d_in[10];
  const float* bo   = (const float*)d_in[11];
  const float* proj = (const float*)d_in[12];
  const float* ln2g = (const float*)d_in[13];
  const float* ln2b = (const float*)d_in[14];
  const float* w1   = (const float*)d_in[15];
  const float* b1   = (const float*)d_in[16];
  const float* w2   = (const float*)d_in[17];
  const float* b2   = (const float*)d_in[18];
  const float* cw   = (const float*)d_in[19];
  const float* cb   = (const float*)d_in[20];

  float* h      = (float*)d_ws;                   // NTOK*64
  float* kb     = h + (size_t)NTOK * 64;          // NTOK*64 (k*dn, later reused as ob)
  float* vb     = kb + (size_t)NTOK * 64;         // NTOK*64
  float* ctx    = vb + (size_t)NTOK * 64;         // 16*110*32
  float* ksum   = ctx + 16 * F_ * 32;             // 16*110
  unsigned* kmaxu = (unsigned*)(ksum + 16 * F_);  // 1
  float* colsum = (float*)(kmaxu + 1);            // 512

  hipMemsetAsync(ctx, 0, (size_t)(16 * F_ * 32 + 16 * F_ + 1 + 512) * sizeof(float), stream);
  k_embed<<<NTOK * 64 / 256, 256, 0, stream>>>(x, emb, h);
  for (int l = 0; l < 4; l++) {
    if (l) hipMemsetAsync(ctx, 0, (size_t)(16 * F_ * 32 + 16 * F_ + 1) * sizeof(float), stream);
    k_ln_kv<<<NTOK / 128, 512, 0, stream>>>(h, ln1g + 64 * l, ln1b + 64 * l,
                                            wk + 4096 * l, bk + 64 * l,
                                            wv + 4096 * l, bv + 64 * l,
                                            proj + 3520 * l, kb, vb, kmaxu);
    k_kp_ctx<<<NTOK / 128, 256, 0, stream>>>(kb, vb, proj + 3520 * l, kmaxu, ksum, ctx);
    k_qo<<<NTOK / 128, 512, 0, stream>>>(h, ln1g + 64 * l, ln1b + 64 * l,
                                         wq + 4096 * l, bq + 64 * l,
                                         proj + 3520 * l, ksum, ctx, kb);
    k_wo_ff<<<NTOK / 128, 512, 0, stream>>>(h, kb, wo + 4096 * l, bo + 64 * l,
                                            ln2g + 64 * l, ln2b + 64 * l,
                                            w1 + 16384 * l, b1 + 256 * l,
                                            w2 + 16384 * l, b2 + 64 * l);
  }
  k_colsum<<<64, 256, 0, stream>>>(h, colsum);
  k_logits<<<1, 128, 0, stream>>>(colsum, cw, cb, (float*)d_out);
}

// Round 8
// 2869.064 us; speedup vs baseline: 5.3483x; 1.4294x over previous
//
#include <hip/hip_runtime.h>
#include <hip/hip_bf16.h>

// Performer (FAVOR+) classifier forward, round 7 resubmit (rounds 4-6 infra fails).
// MFMA f16 hi/lo for wo+FF. DEPTH=4, HEADS=2, DH=32, DE=64, N=16384, B=8, F=110

constexpr int B_   = 8;
constexpr int N_   = 16384;
constexpr int F_   = 110;
constexpr int NTOK = B_ * N_;          // 131072
constexpr float DN    = 0.42044820762685725f;   // 32^-0.25
constexpr float RATIO = 0.09534625892455922f;   // 110^-0.5
constexpr float KEPS  = 1e-4f;

typedef _Float16 f16x8 __attribute__((ext_vector_type(8)));
typedef float    f32x4 __attribute__((ext_vector_type(4)));

__device__ __forceinline__ float wsum64(float v) {
#pragma unroll
  for (int m = 32; m > 0; m >>= 1) v += __shfl_xor(v, m);
  return v;
}
__device__ __forceinline__ float wsum32(float v) {
#pragma unroll
  for (int m = 16; m > 0; m >>= 1) v += __shfl_xor(v, m);
  return v;
}
__device__ __forceinline__ float wmax64(float v) {
#pragma unroll
  for (int m = 32; m > 0; m >>= 1) v = fmaxf(v, __shfl_xor(v, m));
  return v;
}
__device__ __forceinline__ float bcastf(float v, int lane) {
  return __uint_as_float((unsigned)__builtin_amdgcn_readlane((int)__float_as_uint(v), lane));
}

// ---------------- h = concat(emb_w, x) ----------------
__global__ __launch_bounds__(256) void k_embed(const float* __restrict__ x,
                                               const float* __restrict__ emb,
                                               float* __restrict__ hbuf) {
  int gidx = blockIdx.x * 256 + threadIdx.x;
  int tok = gidx >> 6, c = gidx & 63;
  float v;
  if (c < 63) v = emb[(size_t)(tok & (N_ - 1)) * 63 + c];
  else        v = x[tok];
  hbuf[gidx] = v;
}

// ------ weight prep: wo/w1/w2 -> hi/lo f16 planes, B-fragment-major layout ------
// B-fragment (K x N, mfma_16x16x32): frag f = (k>>5)*(N/16) + (n>>4);
// lane = ((k>>3)&3)*16 + (n&15); e = k&7; elem offset = (f*64+lane)*8+e.
__global__ __launch_bounds__(256) void k_prep(
    const float* __restrict__ wo, const float* __restrict__ w1, const float* __restrict__ w2,
    _Float16* __restrict__ whi, _Float16* __restrict__ wlo) {
  int t = blockIdx.x * 256 + threadIdx.x;
  if (t >= 4 * 36864) return;
  int l = t / 36864, r = t % 36864;
  const float* src; int N, base;
  if (r < 4096)       { src = wo + l * 4096;  N = 64;  base = 0; }
  else if (r < 20480) { src = w1 + l * 16384; N = 256; base = 4096;  r -= 4096; }
  else                { src = w2 + l * 16384; N = 64;  base = 20480; r -= 20480; }
  int f = r >> 9, lane = (r >> 3) & 63, e = r & 7;
  int NB = N >> 4;
  int k = (f / NB) * 32 + ((lane >> 4) & 3) * 8 + e;
  int n = (f % NB) * 16 + (lane & 15);
  float v = src[k * N + n];
  _Float16 hi = (_Float16)v;
  _Float16 lo = (_Float16)(v - (float)hi);
  size_t off = (size_t)l * 36864 + base + r;
  whi[off] = hi; wlo[off] = lo;
}

// ---------------- LN + K,V projection + global max of dd_k ----------------
__global__ __launch_bounds__(512) void k_ln_kv(
    const float* __restrict__ hbuf, const float* __restrict__ lng, const float* __restrict__ lnb,
    const float* __restrict__ wk, const float* __restrict__ bk,
    const float* __restrict__ wv, const float* __restrict__ bv,
    const float* __restrict__ proj,
    float* __restrict__ kout, float* __restrict__ vout, unsigned int* __restrict__ kmaxu) {
  __shared__ float wk_s[64 * 64];
  __shared__ float wv_s[64 * 64];
  __shared__ float proj_s[F_ * 33];
  __shared__ float kd_s[8][4][64];
  __shared__ float wm_s[8];
  const int tid = threadIdx.x, w = tid >> 6, j = tid & 63;
  for (int i = tid; i < 64 * 64; i += 512) { wk_s[i] = wk[i]; wv_s[i] = wv[i]; }
  for (int i = tid; i < F_ * 32; i += 512) proj_s[(i >> 5) * 33 + (i & 31)] = proj[i];
  const float gj = lng[j], bj = lnb[j], bkj = bk[j], bvj = bv[j];
  __syncthreads();
  const int tokbase = blockIdx.x * 128 + w * 16;
  float mymax = -3.0e38f;
  for (int q4 = 0; q4 < 4; q4++) {
    const int t0 = tokbase + q4 * 4;
    float yv[4], acck[4], accv[4];
#pragma unroll
    for (int u = 0; u < 4; u++) {
      float hj = hbuf[(size_t)(t0 + u) * 64 + j];
      float mu = wsum64(hj) * (1.f / 64.f);
      float d = hj - mu;
      float var = wsum64(d * d) * (1.f / 64.f);
      yv[u] = d * rsqrtf(var + 1e-5f) * gj + bj;
      acck[u] = bkj; accv[u] = bvj;
    }
    for (int i = 0; i < 64; i++) {
      float wki = wk_s[i * 64 + j], wvi = wv_s[i * 64 + j];
#pragma unroll
      for (int u = 0; u < 4; u++) {
        float yi = bcastf(yv[u], i);
        acck[u] += yi * wki;
        accv[u] += yi * wvi;
      }
    }
#pragma unroll
    for (int u = 0; u < 4; u++) {
      float kd = acck[u] * DN;
      kout[(size_t)(t0 + u) * 64 + j] = kd;   // store k*dn directly
      vout[(size_t)(t0 + u) * 64 + j] = accv[u];
      kd_s[w][u][j] = kd;                     // wave-private: lockstep, no barrier
    }
#pragma unroll
    for (int t2 = 0; t2 < 4; t2++) {
      int idx = j + 64 * t2;
      if (idx < 220) {
        int head = (idx >= 110);
        int f = idx - head * 110;
        const float* pr = &proj_s[f * 33];
        const float* kk = &kd_s[w][0][head * 32];
        float dd0 = 0, dd1 = 0, dd2 = 0, dd3 = 0;
#pragma unroll 8
        for (int d = 0; d < 32; d++) {
          float p = pr[d];
          dd0 += kk[d]       * p;
          dd1 += kk[d + 64]  * p;
          dd2 += kk[d + 128] * p;
          dd3 += kk[d + 192] * p;
        }
        mymax = fmaxf(mymax, fmaxf(fmaxf(dd0, dd1), fmaxf(dd2, dd3)));
      }
    }
  }
  mymax = wmax64(mymax);
  if (j == 0) wm_s[w] = mymax;
  __syncthreads();
  if (tid == 0) {
    float m = wm_s[0];
    for (int i = 1; i < 8; i++) m = fmaxf(m, wm_s[i]);
    unsigned u_ = __float_as_uint(m);
    unsigned mm = (u_ & 0x80000000u) ? ~u_ : (u_ | 0x80000000u);
    atomicMax(kmaxu, mm);
  }
}

// ---------------- kp features + ctx / ksum accumulation ----------------
__global__ __launch_bounds__(256) void k_kp_ctx(
    const float* __restrict__ kdbuf, const float* __restrict__ vbuf,
    const float* __restrict__ proj, const unsigned int* __restrict__ kmaxu,
    float* __restrict__ ksum_g, float* __restrict__ ctx_g) {
  __shared__ float proj_s[F_ * 33];
  __shared__ float k_s[16][65];
  __shared__ float v_s[16][64];
  __shared__ float kp_s[16][224];
  __shared__ float diag_s[16][2];
  const int tid = threadIdx.x;
  for (int i = tid; i < F_ * 32; i += 256) proj_s[(i >> 5) * 33 + (i & 31)] = proj[i];
  unsigned mu = *kmaxu;
  float M = (mu & 0x80000000u) ? __uint_as_float(mu ^ 0x80000000u) : __uint_as_float(~mu);
  float acc[28];
#pragma unroll
  for (int r = 0; r < 28; r++) acc[r] = 0.f;
  float ksacc = 0.f;
  const int tok0 = blockIdx.x * 128;
  const int b = tok0 >> 14;
  const int hd = tid & 63;
  const int head_o = hd >> 5;
  const int fbase = tid >> 6;      // 0..3
  const int ldt = tid >> 4;        // load: token
  const int ldc = (tid & 15) * 4;  // load: col group
  const int kp_hh = (tid < 112) ? 0 : 1;
  const int kp_f  = tid - kp_hh * 112;
  const bool kp_act = (tid < 224) && (kp_f < F_);
  __syncthreads();
  for (int g8 = 0; g8 < 8; g8++) {
    const int t0 = tok0 + g8 * 16;
    float4 k4 = *(const float4*)(kdbuf + (size_t)(t0 + ldt) * 64 + ldc);
    float4 v4 = *(const float4*)(vbuf + (size_t)(t0 + ldt) * 64 + ldc);
    k_s[ldt][ldc + 0] = k4.x; k_s[ldt][ldc + 1] = k4.y;
    k_s[ldt][ldc + 2] = k4.z; k_s[ldt][ldc + 3] = k4.w;
    *(float4*)(&v_s[ldt][ldc]) = v4;
    __syncthreads();
    if (tid < 32) {
      int tk = tid >> 1, hh = tid & 1;
      const float* kk = &k_s[tk][hh * 32];
      float s = 0.f;
#pragma unroll 8
      for (int d = 0; d < 32; d++) { float t = kk[d]; s += t * t; }
      diag_s[tk][hh] = 0.5f * s;
    }
    __syncthreads();
    if (tid < 224) {
      const float* pr = &proj_s[kp_f * 33];
      for (int tk = 0; tk < 16; tk++) {
        float val = 0.f;
        if (kp_act) {
          const float* kk = &k_s[tk][kp_hh * 32];
          float dd = 0.f;
#pragma unroll 8
          for (int d = 0; d < 32; d++) dd += kk[d] * pr[d];
          val = RATIO * (__expf(dd - diag_s[tk][kp_hh] - M) + KEPS);
        }
        kp_s[tk][tid] = val;
      }
    }
    __syncthreads();
    if (tid < 224) {
#pragma unroll
      for (int tk = 0; tk < 16; tk++) ksacc += kp_s[tk][tid];
    }
#pragma unroll
    for (int tk = 0; tk < 16; tk++) {
      float vv = v_s[tk][hd];
      const float* kpt = &kp_s[tk][head_o * 112 + fbase];
#pragma unroll
      for (int r = 0; r < 28; r++) acc[r] += kpt[4 * r] * vv;
    }
    __syncthreads();
  }
  if (tid < 224) {
    int hh = tid / 112, f = tid - hh * 112;
    if (f < F_) atomicAdd(&ksum_g[(b * 2 + hh) * F_ + f], ksacc);
  }
  const int dcol = hd & 31;
#pragma unroll
  for (int r = 0; r < 28; r++) {
    int f = fbase + 4 * r;
    if (f < F_) atomicAdd(&ctx_g[((size_t)(b * 2 + head_o) * F_ + f) * 32 + dcol], acc[r]);
  }
}

// ------ Q path: o = (qp @ ctx) * d_inv -> hi/lo f16 (A-fragment-friendly row-major) ------
__global__ __launch_bounds__(512) void k_qo(
    const float* __restrict__ hbuf, const float* __restrict__ lng, const float* __restrict__ lnb,
    const float* __restrict__ wq, const float* __restrict__ bq,
    const float* __restrict__ proj, const float* __restrict__ ksum_g,
    const float* __restrict__ ctx_g,
    _Float16* __restrict__ obh, _Float16* __restrict__ obl) {
  __shared__ float wq_s[64 * 64];      // 16 KB
  __shared__ float proj_s[F_ * 33];    // 14.5 KB
  __shared__ float ctx_s[F_ * 64];     // 28 KB
  __shared__ float ksum_s[224];
  __shared__ float q_s[8][4][64];      // wave-private rows
  __shared__ float qp_s[8][224];       // wave-private rows
  const int tid = threadIdx.x, w = tid >> 6, j = tid & 63;
  const int b = (blockIdx.x * 128) >> 14;
  for (int i = tid; i < 64 * 64; i += 512) wq_s[i] = wq[i];
  for (int i = tid; i < F_ * 32; i += 512) proj_s[(i >> 5) * 33 + (i & 31)] = proj[i];
  for (int i = tid; i < F_ * 64; i += 512) {
    int f = i >> 6, c = i & 63, hh = c >> 5, d = c & 31;
    ctx_s[i] = ctx_g[((size_t)(b * 2 + hh) * F_ + f) * 32 + d];
  }
  if (tid < 224) {
    int hh = tid / 112, f = tid - hh * 112;
    ksum_s[tid] = (f < F_) ? ksum_g[(b * 2 + hh) * F_ + f] : 0.f;
  }
  const float gj = lng[j], bj = lnb[j], bqj = bq[j];
  __syncthreads();   // staging only; everything below is wave-private
  const int tokbase = blockIdx.x * 128 + w * 16;
  const int hj_ = j >> 5;
  for (int q4 = 0; q4 < 4; q4++) {
    const int t0 = tokbase + q4 * 4;
    float yv[4], accq[4];
#pragma unroll
    for (int u = 0; u < 4; u++) {
      float hj = hbuf[(size_t)(t0 + u) * 64 + j];
      float mu = wsum64(hj) * (1.f / 64.f);
      float d = hj - mu;
      float var = wsum64(d * d) * (1.f / 64.f);
      yv[u] = d * rsqrtf(var + 1e-5f) * gj + bj;
      accq[u] = bqj;
    }
    for (int i = 0; i < 64; i++) {
      float wqi = wq_s[i * 64 + j];
#pragma unroll
      for (int u = 0; u < 4; u++) accq[u] += bcastf(yv[u], i) * wqi;
    }
#pragma unroll
    for (int u = 0; u < 4; u++) {
      accq[u] *= DN;
      q_s[w][u][j] = accq[u];
    }
#pragma unroll
    for (int u = 0; u < 4; u++) {
      float qd = accq[u];
      float ds_ = wsum32(qd * qd) * 0.5f;          // per-head diag
      float diag0 = bcastf(ds_, 0), diag1 = bcastf(ds_, 32);
      float dd[4];
      float m0 = -3e38f, m1 = -3e38f;
#pragma unroll
      for (int t2 = 0; t2 < 4; t2++) {
        int idx = j + 64 * t2;
        float v = 0.f;
        if (idx < 220) {
          int head = idx >= 110;
          int f = idx - head * 110;
          const float* pr = &proj_s[f * 33];
          const float* qs = &q_s[w][u][head * 32];
#pragma unroll 8
          for (int d = 0; d < 32; d++) v += qs[d] * pr[d];
          if (head) m1 = fmaxf(m1, v); else m0 = fmaxf(m0, v);
        }
        dd[t2] = v;
      }
      m0 = wmax64(m0); m1 = wmax64(m1);
      float s0 = 0.f, s1 = 0.f;
#pragma unroll
      for (int t2 = 0; t2 < 4; t2++) {
        int idx = j + 64 * t2;
        if (idx < 220) {
          int head = idx >= 110;
          int f = idx - head * 110;
          float e = RATIO * (__expf(dd[t2] - (head ? diag1 : diag0) - (head ? m1 : m0)) + KEPS);
          qp_s[w][head * 112 + f] = e;
          float kss = ksum_s[head * 112 + f];
          if (head) s1 += e * kss; else s0 += e * kss;
        }
      }
      float dinv0 = 1.f / wsum64(s0);
      float dinv1 = 1.f / wsum64(s1);
      const float* qp = &qp_s[w][hj_ * 112];
      const float* cx = &ctx_s[j];
      float o = 0.f;
#pragma unroll 11
      for (int f = 0; f < F_; f++) o += qp[f] * cx[f * 64];
      float oval = o * (hj_ ? dinv1 : dinv0);
      _Float16 hi = (_Float16)oval;
      _Float16 lo = (_Float16)(oval - (float)hi);
      obh[(size_t)(t0 + u) * 64 + j] = hi;
      obl[(size_t)(t0 + u) * 64 + j] = lo;
    }
  }
}

// ------ MFMA fused: h += o@wo+bo; y=LN2(h); h += gelu(y@w1+b1)@w2+b2 ------
// 256 threads = 4 waves; 64 tokens/block, wave w owns rows 16w..16w+15.
// hi/lo split: D = Ah*Bh + Ah*Bl + Al*Bh (rel err ~2^-22).
__global__ __launch_bounds__(256) void k_wo_ff(
    float* __restrict__ hbuf,
    const _Float16* __restrict__ obh, const _Float16* __restrict__ obl,
    const _Float16* __restrict__ whi, const _Float16* __restrict__ wlo,
    const float* __restrict__ bo, const float* __restrict__ lng, const float* __restrict__ lnb,
    const float* __restrict__ b1, const float* __restrict__ b2) {
  __shared__ _Float16 y_lds[4][2][16][72];     // [wave][hi/lo][row][ch]
  __shared__ _Float16 t1_lds[4][2][16][136];   // [wave][hi/lo][row][col-half]
  const int tid = threadIdx.x, w = tid >> 6, l = tid & 63;
  const int lr = l & 15, lg = l >> 4;
  const int row0 = blockIdx.x * 64 + w * 16;

  // ---- G1: D1 = ov @ wo (+bo) ----
  f32x4 acc[4];
#pragma unroll
  for (int nt = 0; nt < 4; nt++) {
    float bb = bo[nt * 16 + lr];
    acc[nt] = f32x4{bb, bb, bb, bb};
  }
#pragma unroll
  for (int kb = 0; kb < 2; kb++) {
    f16x8 ah = *(const f16x8*)(obh + (size_t)(row0 + lr) * 64 + kb * 32 + lg * 8);
    f16x8 al = *(const f16x8*)(obl + (size_t)(row0 + lr) * 64 + kb * 32 + lg * 8);
#pragma unroll
    for (int nt = 0; nt < 4; nt++) {
      int f = kb * 4 + nt;
      f16x8 bh = *(const f16x8*)(whi + ((f * 64 + l) << 3));
      f16x8 bl = *(const f16x8*)(wlo + ((f * 64 + l) << 3));
      acc[nt] = __builtin_amdgcn_mfma_f32_16x16x32_f16(ah, bh, acc[nt], 0, 0, 0);
      acc[nt] = __builtin_amdgcn_mfma_f32_16x16x32_f16(ah, bl, acc[nt], 0, 0, 0);
      acc[nt] = __builtin_amdgcn_mfma_f32_16x16x32_f16(al, bh, acc[nt], 0, 0, 0);
    }
  }
  // ---- residual + LN2 (D-layout: row=lg*4+r, col=nt*16+lr) ----
  float hA[4][4];
#pragma unroll
  for (int nt = 0; nt < 4; nt++)
#pragma unroll
    for (int r = 0; r < 4; r++)
      hA[nt][r] = hbuf[(size_t)(row0 + lg * 4 + r) * 64 + nt * 16 + lr] + acc[nt][r];
  float mu[4], rs[4];
#pragma unroll
  for (int r = 0; r < 4; r++) {
    float s = hA[0][r] + hA[1][r] + hA[2][r] + hA[3][r];
    s += __shfl_xor(s, 1); s += __shfl_xor(s, 2);
    s += __shfl_xor(s, 4); s += __shfl_xor(s, 8);
    mu[r] = s * (1.f / 64.f);
  }
#pragma unroll
  for (int r = 0; r < 4; r++) {
    float sq = 0.f;
#pragma unroll
    for (int nt = 0; nt < 4; nt++) { float d = hA[nt][r] - mu[r]; sq += d * d; }
    sq += __shfl_xor(sq, 1); sq += __shfl_xor(sq, 2);
    sq += __shfl_xor(sq, 4); sq += __shfl_xor(sq, 8);
    rs[r] = rsqrtf(sq * (1.f / 64.f) + 1e-5f);
  }
#pragma unroll
  for (int nt = 0; nt < 4; nt++) {
    float gc = lng[nt * 16 + lr], bc = lnb[nt * 16 + lr];
#pragma unroll
    for (int r = 0; r < 4; r++) {
      float yv = (hA[nt][r] - mu[r]) * rs[r] * gc + bc;
      _Float16 hi = (_Float16)yv;
      _Float16 lo = (_Float16)(yv - (float)hi);
      y_lds[w][0][lg * 4 + r][nt * 16 + lr] = hi;
      y_lds[w][1][lg * 4 + r][nt * 16 + lr] = lo;
    }
  }
  // ---- FF in two N-halves of 128 ----
  const _Float16* w1h = whi + 4096;  const _Float16* w1l = wlo + 4096;
  const _Float16* w2h = whi + 20480; const _Float16* w2l = wlo + 20480;
  f32x4 acc3[4];
#pragma unroll
  for (int nt = 0; nt < 4; nt++) {
    float bb = b2[nt * 16 + lr];
    acc3[nt] = f32x4{bb, bb, bb, bb};
  }
  for (int half = 0; half < 2; half++) {
    // G2: t1_half = y @ w1[:, half*128 : half*128+128] (+b1)
    f32x4 acc2[8];
#pragma unroll
    for (int nt = 0; nt < 8; nt++) {
      float bb = b1[half * 128 + nt * 16 + lr];
      acc2[nt] = f32x4{bb, bb, bb, bb};
    }
#pragma unroll
    for (int kb = 0; kb < 2; kb++) {
      f16x8 ah = *(const f16x8*)(&y_lds[w][0][lr][kb * 32 + lg * 8]);
      f16x8 al = *(const f16x8*)(&y_lds[w][1][lr][kb * 32 + lg * 8]);
#pragma unroll
      for (int nt = 0; nt < 8; nt++) {
        int f = kb * 16 + half * 8 + nt;
        f16x8 bh = *(const f16x8*)(w1h + ((f * 64 + l) << 3));
        f16x8 bl = *(const f16x8*)(w1l + ((f * 64 + l) << 3));
        acc2[nt] = __builtin_amdgcn_mfma_f32_16x16x32_f16(ah, bh, acc2[nt], 0, 0, 0);
        acc2[nt] = __builtin_amdgcn_mfma_f32_16x16x32_f16(ah, bl, acc2[nt], 0, 0, 0);
        acc2[nt] = __builtin_amdgcn_mfma_f32_16x16x32_f16(al, bh, acc2[nt], 0, 0, 0);
      }
    }
    // GELU + split + stage t1 half
#pragma unroll
    for (int nt = 0; nt < 8; nt++)
#pragma unroll
      for (int r = 0; r < 4; r++) {
        float t = acc2[nt][r];
        float gl = 0.5f * t * (1.f + erff(t * 0.70710678118654752f));
        _Float16 hi = (_Float16)gl;
        _Float16 lo = (_Float16)(gl - (float)hi);
        t1_lds[w][0][lg * 4 + r][nt * 16 + lr] = hi;
        t1_lds[w][1][lg * 4 + r][nt * 16 + lr] = lo;
      }
    // G3 partial: acc3 += t1_half @ w2[half*128 : half*128+128, :]
#pragma unroll
    for (int kb2 = 0; kb2 < 4; kb2++) {
      f16x8 ah = *(const f16x8*)(&t1_lds[w][0][lr][kb2 * 32 + lg * 8]);
      f16x8 al = *(const f16x8*)(&t1_lds[w][1][lr][kb2 * 32 + lg * 8]);
#pragma unroll
      for (int nt = 0; nt < 4; nt++) {
        int f = (half * 4 + kb2) * 4 + nt;
        f16x8 bh = *(const f16x8*)(w2h + ((f * 64 + l) << 3));
        f16x8 bl = *(const f16x8*)(w2l + ((f * 64 + l) << 3));
        acc3[nt] = __builtin_amdgcn_mfma_f32_16x16x32_f16(ah, bh, acc3[nt], 0, 0, 0);
        acc3[nt] = __builtin_amdgcn_mfma_f32_16x16x32_f16(ah, bl, acc3[nt], 0, 0, 0);
        acc3[nt] = __builtin_amdgcn_mfma_f32_16x16x32_f16(al, bh, acc3[nt], 0, 0, 0);
      }
    }
  }
  // ---- store h = hA + FF ----
#pragma unroll
  for (int nt = 0; nt < 4; nt++)
#pragma unroll
    for (int r = 0; r < 4; r++)
      hbuf[(size_t)(row0 + lg * 4 + r) * 64 + nt * 16 + lr] = hA[nt][r] + acc3[nt][r];
}

// ---------------- mean over N (partial) ----------------
__global__ __launch_bounds__(256) void k_colsum(const float* __restrict__ hbuf,
                                                float* __restrict__ colsum) {
  __shared__ float red[256];
  int bb = blockIdx.x >> 3, chunk = blockIdx.x & 7;
  int t = threadIdx.x;
  int c = t & 63, r0 = t >> 6;
  size_t base = ((size_t)bb * N_ + chunk * 2048 + r0) * 64 + c;
  float acc = 0.f;
  for (int s = 0; s < 512; s++) acc += hbuf[base + (size_t)s * 256];
  red[t] = acc;
  __syncthreads();
  if (t < 64) {
    float tot = red[t] + red[t + 64] + red[t + 128] + red[t + 192];
    atomicAdd(&colsum[bb * 64 + t], tot);
  }
}

// ---------------- classifier ----------------
__global__ __launch_bounds__(128) void k_logits(const float* __restrict__ colsum,
                                                const float* __restrict__ cw,
                                                const float* __restrict__ cb,
                                                float* __restrict__ out) {
  int t = threadIdx.x;
  if (t < 80) {
    int b = t / 10, kk = t - b * 10;
    float acc = 0.f;
    for (int c = 0; c < 64; c++) acc += colsum[b * 64 + c] * cw[c * 10 + kk];
    out[t] = acc * (1.f / 16384.f) + cb[kk];
  }
}

extern "C" void kernel_launch(void* const* d_in, const int* in_sizes, int n_in,
                              void* d_out, int out_size, void* d_ws, size_t ws_size,
                              hipStream_t stream) {
  const float* x    = (const float*)d_in[0];
  const float* emb  = (const float*)d_in[1];
  const float* ln1g = (const float*)d_in[2];
  const float* ln1b = (const float*)d_in[3];
  const float* wq   = (const float*)d_in[4];
  const float* bq   = (const float*)d_in[5];
  const float* wk   = (const float*)d_in[6];
  const float* bk   = (const float*)d_in[7];
  const float* wv   = (const float*)d_in[8];
  const float* bv   = (const float*)d_in[9];
  const float* wo   = (const float*)d_in[10];
  const float* bo   = (const float*)d_in[11];
  const float* proj = (const float*)d_in[12];
  const float* ln2g = (const float*)d_in[13];
  const float* ln2b = (const float*)d_in[14];
  const float* w1   = (const float*)d_in[15];
  const float* b1   = (const float*)d_in[16];
  const float* w2   = (const float*)d_in[17];
  const float* b2   = (const float*)d_in[18];
  const float* cw   = (const float*)d_in[19];
  const float* cb   = (const float*)d_in[20];

  float* h      = (float*)d_ws;                   // NTOK*64
  float* kb     = h + (size_t)NTOK * 64;          // NTOK*64 (k*dn, later reused as ob hi/lo f16)
  float* vb     = kb + (size_t)NTOK * 64;         // NTOK*64
  float* ctx    = vb + (size_t)NTOK * 64;         // 16*110*32
  float* ksum   = ctx + 16 * F_ * 32;             // 16*110
  unsigned* kmaxu = (unsigned*)(ksum + 16 * F_);  // 1
  float* colsum = (float*)(kmaxu + 1);            // 512
  // f16 weight planes, 64B-aligned
  uintptr_t wp = (uintptr_t)(colsum + 512);
  wp = (wp + 63) & ~(uintptr_t)63;
  _Float16* whi = (_Float16*)wp;                  // 4*36864
  _Float16* wlo = whi + 4 * 36864;                // 4*36864
  _Float16* obh = (_Float16*)kb;                  // NTOK*64 f16
  _Float16* obl = obh + (size_t)NTOK * 64;        // NTOK*64 f16

  hipMemsetAsync(ctx, 0, (size_t)(16 * F_ * 32 + 16 * F_ + 1 + 512) * sizeof(float), stream);
  k_prep<<<576, 256, 0, stream>>>(wo, w1, w2, whi, wlo);
  k_embed<<<NTOK * 64 / 256, 256, 0, stream>>>(x, emb, h);
  for (int l = 0; l < 4; l++) {
    if (l) hipMemsetAsync(ctx, 0, (size_t)(16 * F_ * 32 + 16 * F_ + 1) * sizeof(float), stream);
    k_ln_kv<<<NTOK / 128, 512, 0, stream>>>(h, ln1g + 64 * l, ln1b + 64 * l,
                                            wk + 4096 * l, bk + 64 * l,
                                            wv + 4096 * l, bv + 64 * l,
                                            proj + 3520 * l, kb, vb, kmaxu);
    k_kp_ctx<<<NTOK / 128, 256, 0, stream>>>(kb, vb, proj + 3520 * l, kmaxu, ksum, ctx);
    k_qo<<<NTOK / 128, 512, 0, stream>>>(h, ln1g + 64 * l, ln1b + 64 * l,
                                         wq + 4096 * l, bq + 64 * l,
                                         proj + 3520 * l, ksum, ctx, obh, obl);
    k_wo_ff<<<NTOK / 64, 256, 0, stream>>>(h, obh, obl,
                                           whi + (size_t)l * 36864, wlo + (size_t)l * 36864,
                                           bo + 64 * l, ln2g + 64 * l, ln2b + 64 * l,
                                           b1 + 256 * l, b2 + 64 * l);
  }
  k_colsum<<<64, 256, 0, stream>>>(h, colsum);
  k_logits<<<1, 128, 0, stream>>>(colsum, cw, cb, (float*)d_out);
}

// Round 10
// 1822.974 us; speedup vs baseline: 8.4174x; 1.5738x over previous
//
#include <hip/hip_runtime.h>
#include <hip/hip_bf16.h>

// Performer (FAVOR+) classifier, round 9 resubmit (round-8 infra fail).
// MFMA mega-kernel for Q-path+wo+FF. DEPTH=4, HEADS=2, DH=32, DE=64, N=16384, B=8, F=110

constexpr int B_   = 8;
constexpr int N_   = 16384;
constexpr int F_   = 110;
constexpr int NTOK = B_ * N_;          // 131072
constexpr int WSEG = 44544;            // per-layer f16 weight-plane elems
constexpr float DN    = 0.42044820762685725f;   // 32^-0.25
constexpr float RATIO = 0.09534625892455922f;   // 110^-0.5
constexpr float KEPS  = 1e-4f;

typedef _Float16 f16x8 __attribute__((ext_vector_type(8)));
typedef float    f32x4 __attribute__((ext_vector_type(4)));

__device__ __forceinline__ float wsum64(float v) {
#pragma unroll
  for (int m = 32; m > 0; m >>= 1) v += __shfl_xor(v, m);
  return v;
}
__device__ __forceinline__ float wmax64(float v) {
#pragma unroll
  for (int m = 32; m > 0; m >>= 1) v = fmaxf(v, __shfl_xor(v, m));
  return v;
}
__device__ __forceinline__ float bcastf(float v, int lane) {
  return __uint_as_float((unsigned)__builtin_amdgcn_readlane((int)__float_as_uint(v), lane));
}
// reduce over the 16-lane (lr) group: masks 1,2,4,8
__device__ __forceinline__ float rsum16(float v) {
  v += __shfl_xor(v, 1); v += __shfl_xor(v, 2);
  v += __shfl_xor(v, 4); v += __shfl_xor(v, 8);
  return v;
}
__device__ __forceinline__ float rmax16(float v) {
  v = fmaxf(v, __shfl_xor(v, 1)); v = fmaxf(v, __shfl_xor(v, 2));
  v = fmaxf(v, __shfl_xor(v, 4)); v = fmaxf(v, __shfl_xor(v, 8));
  return v;
}

// ---------------- h = concat(emb_w, x) ----------------
__global__ __launch_bounds__(256) void k_embed(const float* __restrict__ x,
                                               const float* __restrict__ emb,
                                               float* __restrict__ hbuf) {
  int gidx = blockIdx.x * 256 + threadIdx.x;
  int tok = gidx >> 6, c = gidx & 63;
  float v;
  if (c < 63) v = emb[(size_t)(tok & (N_ - 1)) * 63 + c];
  else        v = x[tok];
  hbuf[gidx] = v;
}

// ------ weight prep: wo/w1/w2/wq/proj^T -> hi/lo f16 B-frag planes ------
// B-frag (K x N, mfma_16x16x32): frag f=(k>>5)*(N/16)+(n>>4);
// lane=((k>>3)&3)*16+(n&15); e=k&7.
__global__ __launch_bounds__(256) void k_prep(
    const float* __restrict__ wo, const float* __restrict__ w1, const float* __restrict__ w2,
    const float* __restrict__ wq, const float* __restrict__ proj,
    _Float16* __restrict__ whi, _Float16* __restrict__ wlo) {
  int t = blockIdx.x * 256 + threadIdx.x;
  if (t >= 4 * WSEG) return;
  int l = t / WSEG, r = t % WSEG;
  int rr = r; const float* src; int N; bool tr = false;
  if (rr < 4096)       { src = wo + l * 4096;  N = 64; }
  else if (rr < 20480) { src = w1 + l * 16384; N = 256; rr -= 4096; }
  else if (rr < 36864) { src = w2 + l * 16384; N = 64;  rr -= 20480; }
  else if (rr < 40960) { src = wq + l * 4096;  N = 64;  rr -= 36864; }
  else                 { src = proj + l * 3520; N = 112; tr = true; rr -= 40960; }
  int f = rr >> 9, lane = (rr >> 3) & 63, e = rr & 7;
  int NB = N >> 4;
  int k = (f / NB) * 32 + ((lane >> 4) & 3) * 8 + e;
  int n = (f % NB) * 16 + (lane & 15);
  float v;
  if (tr) v = (n < F_) ? src[n * 32 + k] : 0.f;   // B[k][n] = proj[n][k], zero-pad n>=110
  else    v = src[k * N + n];
  _Float16 hi = (_Float16)v;
  _Float16 lo = (_Float16)(v - (float)hi);
  size_t off = (size_t)l * WSEG + r;
  whi[off] = hi; wlo[off] = lo;
}

// ------ ctx -> B-frag hi/lo planes (K=128 zero-padded, N=32) per (b,head) ------
__global__ __launch_bounds__(256) void k_ctxprep(const float* __restrict__ ctx_g,
                                                 _Float16* __restrict__ ctxBh,
                                                 _Float16* __restrict__ ctxBl) {
  int t = blockIdx.x * 256 + threadIdx.x;        // 65536 = 16 bh * 8 frag * 64 lane * 8 e
  int e = t & 7, lane = (t >> 3) & 63, frag = (t >> 9) & 7, bh = t >> 12;
  int k = (frag >> 1) * 32 + ((lane >> 4) & 3) * 8 + e;
  int n = (frag & 1) * 16 + (lane & 15);
  float v = (k < F_) ? ctx_g[((size_t)bh * F_ + k) * 32 + n] : 0.f;
  _Float16 hi = (_Float16)v;
  ctxBh[t] = hi; ctxBl[t] = (_Float16)(v - (float)hi);
}

// ---------------- LN + K,V projection + global max of dd_k ----------------
__global__ __launch_bounds__(512) void k_ln_kv(
    const float* __restrict__ hbuf, const float* __restrict__ lng, const float* __restrict__ lnb,
    const float* __restrict__ wk, const float* __restrict__ bk,
    const float* __restrict__ wv, const float* __restrict__ bv,
    const float* __restrict__ proj,
    float* __restrict__ kout, float* __restrict__ vout, unsigned int* __restrict__ kmaxu) {
  __shared__ float wk_s[64 * 64];
  __shared__ float wv_s[64 * 64];
  __shared__ float proj_s[F_ * 33];
  __shared__ float kd_s[8][4][64];
  __shared__ float wm_s[8];
  const int tid = threadIdx.x, w = tid >> 6, j = tid & 63;
  for (int i = tid; i < 64 * 64; i += 512) { wk_s[i] = wk[i]; wv_s[i] = wv[i]; }
  for (int i = tid; i < F_ * 32; i += 512) proj_s[(i >> 5) * 33 + (i & 31)] = proj[i];
  const float gj = lng[j], bj = lnb[j], bkj = bk[j], bvj = bv[j];
  __syncthreads();
  const int tokbase = blockIdx.x * 128 + w * 16;
  float mymax = -3.0e38f;
  for (int q4 = 0; q4 < 4; q4++) {
    const int t0 = tokbase + q4 * 4;
    float yv[4], acck[4], accv[4];
#pragma unroll
    for (int u = 0; u < 4; u++) {
      float hj = hbuf[(size_t)(t0 + u) * 64 + j];
      float mu = wsum64(hj) * (1.f / 64.f);
      float d = hj - mu;
      float var = wsum64(d * d) * (1.f / 64.f);
      yv[u] = d * rsqrtf(var + 1e-5f) * gj + bj;
      acck[u] = bkj; accv[u] = bvj;
    }
    for (int i = 0; i < 64; i++) {
      float wki = wk_s[i * 64 + j], wvi = wv_s[i * 64 + j];
#pragma unroll
      for (int u = 0; u < 4; u++) {
        float yi = bcastf(yv[u], i);
        acck[u] += yi * wki;
        accv[u] += yi * wvi;
      }
    }
#pragma unroll
    for (int u = 0; u < 4; u++) {
      float kd = acck[u] * DN;
      kout[(size_t)(t0 + u) * 64 + j] = kd;
      vout[(size_t)(t0 + u) * 64 + j] = accv[u];
      kd_s[w][u][j] = kd;                     // wave-private
    }
#pragma unroll
    for (int t2 = 0; t2 < 4; t2++) {
      int idx = j + 64 * t2;
      if (idx < 220) {
        int head = (idx >= 110);
        int f = idx - head * 110;
        const float* pr = &proj_s[f * 33];
        const float* kk = &kd_s[w][0][head * 32];
        float dd0 = 0, dd1 = 0, dd2 = 0, dd3 = 0;
#pragma unroll 8
        for (int d = 0; d < 32; d++) {
          float p = pr[d];
          dd0 += kk[d]       * p;
          dd1 += kk[d + 64]  * p;
          dd2 += kk[d + 128] * p;
          dd3 += kk[d + 192] * p;
        }
        mymax = fmaxf(mymax, fmaxf(fmaxf(dd0, dd1), fmaxf(dd2, dd3)));
      }
    }
  }
  mymax = wmax64(mymax);
  if (j == 0) wm_s[w] = mymax;
  __syncthreads();
  if (tid == 0) {
    float m = wm_s[0];
    for (int i = 1; i < 8; i++) m = fmaxf(m, wm_s[i]);
    unsigned u_ = __float_as_uint(m);
    unsigned mm = (u_ & 0x80000000u) ? ~u_ : (u_ | 0x80000000u);
    atomicMax(kmaxu, mm);
  }
}

// ---------------- kp features + ctx / ksum accumulation ----------------
__global__ __launch_bounds__(256) void k_kp_ctx(
    const float* __restrict__ kdbuf, const float* __restrict__ vbuf,
    const float* __restrict__ proj, const unsigned int* __restrict__ kmaxu,
    float* __restrict__ ksum_g, float* __restrict__ ctx_g) {
  __shared__ float proj_s[F_ * 33];
  __shared__ float k_s[16][65];
  __shared__ float v_s[16][64];
  __shared__ float kp_s[16][224];
  __shared__ float diag_s[16][2];
  const int tid = threadIdx.x;
  for (int i = tid; i < F_ * 32; i += 256) proj_s[(i >> 5) * 33 + (i & 31)] = proj[i];
  unsigned mu = *kmaxu;
  float M = (mu & 0x80000000u) ? __uint_as_float(mu ^ 0x80000000u) : __uint_as_float(~mu);
  float acc[28];
#pragma unroll
  for (int r = 0; r < 28; r++) acc[r] = 0.f;
  float ksacc = 0.f;
  const int tok0 = blockIdx.x * 128;
  const int b = tok0 >> 14;
  const int hd = tid & 63;
  const int head_o = hd >> 5;
  const int fbase = tid >> 6;
  const int ldt = tid >> 4;
  const int ldc = (tid & 15) * 4;
  const int kp_hh = (tid < 112) ? 0 : 1;
  const int kp_f  = tid - kp_hh * 112;
  const bool kp_act = (tid < 224) && (kp_f < F_);
  __syncthreads();
  for (int g8 = 0; g8 < 8; g8++) {
    const int t0 = tok0 + g8 * 16;
    float4 k4 = *(const float4*)(kdbuf + (size_t)(t0 + ldt) * 64 + ldc);
    float4 v4 = *(const float4*)(vbuf + (size_t)(t0 + ldt) * 64 + ldc);
    k_s[ldt][ldc + 0] = k4.x; k_s[ldt][ldc + 1] = k4.y;
    k_s[ldt][ldc + 2] = k4.z; k_s[ldt][ldc + 3] = k4.w;
    *(float4*)(&v_s[ldt][ldc]) = v4;
    __syncthreads();
    if (tid < 32) {
      int tk = tid >> 1, hh = tid & 1;
      const float* kk = &k_s[tk][hh * 32];
      float s = 0.f;
#pragma unroll 8
      for (int d = 0; d < 32; d++) { float t = kk[d]; s += t * t; }
      diag_s[tk][hh] = 0.5f * s;
    }
    __syncthreads();
    if (tid < 224) {
      const float* pr = &proj_s[kp_f * 33];
      for (int tk = 0; tk < 16; tk++) {
        float val = 0.f;
        if (kp_act) {
          const float* kk = &k_s[tk][kp_hh * 32];
          float dd = 0.f;
#pragma unroll 8
          for (int d = 0; d < 32; d++) dd += kk[d] * pr[d];
          val = RATIO * (__expf(dd - diag_s[tk][kp_hh] - M) + KEPS);
        }
        kp_s[tk][tid] = val;
      }
    }
    __syncthreads();
    if (tid < 224) {
#pragma unroll
      for (int tk = 0; tk < 16; tk++) ksacc += kp_s[tk][tid];
    }
#pragma unroll
    for (int tk = 0; tk < 16; tk++) {
      float vv = v_s[tk][hd];
      const float* kpt = &kp_s[tk][head_o * 112 + fbase];
#pragma unroll
      for (int r = 0; r < 28; r++) acc[r] += kpt[4 * r] * vv;
    }
    __syncthreads();
  }
  if (tid < 224) {
    int hh = tid / 112, f = tid - hh * 112;
    if (f < F_) atomicAdd(&ksum_g[(b * 2 + hh) * F_ + f], ksacc);
  }
  const int dcol = hd & 31;
#pragma unroll
  for (int r = 0; r < 28; r++) {
    int f = fbase + 4 * r;
    if (f < F_) atomicAdd(&ctx_g[((size_t)(b * 2 + head_o) * F_ + f) * 32 + dcol], acc[r]);
  }
}

// ====== merged MFMA attention: LN1+Qproj+features+o, then wo+LN2+FF ======
// 256 threads = 4 waves; 64 tokens/block; wave w owns rows 16w..16w+15.
// All GEMMs via mfma_16x16x32_f16 hi/lo (D = Ah*Bh + Ah*Bl + Al*Bh).
__global__ __launch_bounds__(256) void k_attn(
    float* __restrict__ hbuf,
    const _Float16* __restrict__ whi, const _Float16* __restrict__ wlo,  // layer base
    const _Float16* __restrict__ ctxBh, const _Float16* __restrict__ ctxBl,
    const float* __restrict__ ksum_g,
    const float* __restrict__ ln1g, const float* __restrict__ ln1b,
    const float* __restrict__ bq,  const float* __restrict__ bo,
    const float* __restrict__ ln2g, const float* __restrict__ ln2b,
    const float* __restrict__ b1,  const float* __restrict__ b2) {
  // per-wave scratch, aliased across sequential phases (wave-private: no barriers)
  __shared__ __align__(16) unsigned char scrA_[4][5632];  // q h/l [16][88] -> o f32 [16][76] -> y h/l [16][88]
  __shared__ __align__(16) unsigned char scrB_[4][8704];  // qp h/l [16][136] -> t1 h/l [16][136]
  const int tid = threadIdx.x, w = tid >> 6, l = tid & 63;
  const int lr = l & 15, lg = l >> 4;
  const int row0 = blockIdx.x * 64 + w * 16;
  const int b = (blockIdx.x * 64) >> 14;
  _Float16* qh = (_Float16*)scrA_[w];
  _Float16* ql = qh + 16 * 88;
  float*    oS = (float*)scrA_[w];
  _Float16* yh = (_Float16*)scrA_[w];
  _Float16* yl = yh + 16 * 88;
  _Float16* ph = (_Float16*)scrB_[w];
  _Float16* pl = ph + 16 * 136;

  // ---- LN1, distributed: lane (lr,lg) holds 16 ch of row row0+lr ----
  float hv[16];
#pragma unroll
  for (int kb = 0; kb < 2; kb++) {
    const float* hp = hbuf + (size_t)(row0 + lr) * 64 + kb * 32 + lg * 8;
    float4 p0 = *(const float4*)hp;
    float4 p1 = *(const float4*)(hp + 4);
    hv[kb * 8 + 0] = p0.x; hv[kb * 8 + 1] = p0.y; hv[kb * 8 + 2] = p0.z; hv[kb * 8 + 3] = p0.w;
    hv[kb * 8 + 4] = p1.x; hv[kb * 8 + 5] = p1.y; hv[kb * 8 + 6] = p1.z; hv[kb * 8 + 7] = p1.w;
  }
  float s = 0.f;
#pragma unroll
  for (int i = 0; i < 16; i++) s += hv[i];
  s += __shfl_xor(s, 16); s += __shfl_xor(s, 32);
  float mu1 = s * (1.f / 64.f);
  float sq = 0.f;
#pragma unroll
  for (int i = 0; i < 16; i++) { float d = hv[i] - mu1; sq += d * d; }
  sq += __shfl_xor(sq, 16); sq += __shfl_xor(sq, 32);
  float rs1 = rsqrtf(sq * (1.f / 64.f) + 1e-5f);
  // y1 A-frags in regs
  f16x8 ah1[2], al1[2];
#pragma unroll
  for (int kb = 0; kb < 2; kb++) {
    const float* gp = ln1g + kb * 32 + lg * 8;
    const float* bp = ln1b + kb * 32 + lg * 8;
    float4 g0 = *(const float4*)gp, g1 = *(const float4*)(gp + 4);
    float4 b0 = *(const float4*)bp, b1v_ = *(const float4*)(bp + 4);
    float gv[8] = {g0.x, g0.y, g0.z, g0.w, g1.x, g1.y, g1.z, g1.w};
    float bv[8] = {b0.x, b0.y, b0.z, b0.w, b1v_.x, b1v_.y, b1v_.z, b1v_.w};
#pragma unroll
    for (int e = 0; e < 8; e++) {
      float yv = (hv[kb * 8 + e] - mu1) * rs1 * gv[e] + bv[e];
      _Float16 hi = (_Float16)yv;
      ah1[kb][e] = hi;
      al1[kb][e] = (_Float16)(yv - (float)hi);
    }
  }
  // ---- q = y1 @ wq + bq, *DN (D-layout) ----
  const _Float16* wqh = whi + 36864; const _Float16* wql = wlo + 36864;
  f32x4 q[4];
#pragma unroll
  for (int nt = 0; nt < 4; nt++) {
    float bb = bq[nt * 16 + lr];
    q[nt] = f32x4{bb, bb, bb, bb};
  }
#pragma unroll
  for (int kb = 0; kb < 2; kb++)
#pragma unroll
    for (int nt = 0; nt < 4; nt++) {
      int f = kb * 4 + nt;
      f16x8 bh = *(const f16x8*)(wqh + ((f * 64 + l) << 3));
      f16x8 bl = *(const f16x8*)(wql + ((f * 64 + l) << 3));
      q[nt] = __builtin_amdgcn_mfma_f32_16x16x32_f16(ah1[kb], bh, q[nt], 0, 0, 0);
      q[nt] = __builtin_amdgcn_mfma_f32_16x16x32_f16(ah1[kb], bl, q[nt], 0, 0, 0);
      q[nt] = __builtin_amdgcn_mfma_f32_16x16x32_f16(al1[kb], bh, q[nt], 0, 0, 0);
    }
#pragma unroll
  for (int nt = 0; nt < 4; nt++)
#pragma unroll
    for (int r = 0; r < 4; r++) q[nt][r] *= DN;
  // diag per head per row
  float diag[2][4];
#pragma unroll
  for (int hh = 0; hh < 2; hh++)
#pragma unroll
    for (int r = 0; r < 4; r++) {
      float t = q[hh * 2][r] * q[hh * 2][r] + q[hh * 2 + 1][r] * q[hh * 2 + 1][r];
      diag[hh][r] = 0.5f * rsum16(t);
    }
  // q D-layout -> LDS hi/lo (rows lg*4+r, cols nt*16+lr)
#pragma unroll
  for (int nt = 0; nt < 4; nt++)
#pragma unroll
    for (int r = 0; r < 4; r++) {
      float v = q[nt][r];
      _Float16 hi = (_Float16)v;
      qh[(lg * 4 + r) * 88 + nt * 16 + lr] = hi;
      ql[(lg * 4 + r) * 88 + nt * 16 + lr] = (_Float16)(v - (float)hi);
    }
  // ---- per head: dd = q@proj^T, max, qp, d_inv, o = qp@ctx ----
  const _Float16* pjh = whi + 40960; const _Float16* pjl = wlo + 40960;
  float dinv[2][4];
  f32x4 oreg[2][2];
#pragma unroll
  for (int hh = 0; hh < 2; hh++) {
    f16x8 aqh = *(const f16x8*)(qh + lr * 88 + hh * 32 + lg * 8);
    f16x8 aql = *(const f16x8*)(ql + lr * 88 + hh * 32 + lg * 8);
    f32x4 dd[7];
#pragma unroll
    for (int nt = 0; nt < 7; nt++) {
      dd[nt] = f32x4{0.f, 0.f, 0.f, 0.f};
      f16x8 bh = *(const f16x8*)(pjh + ((nt * 64 + l) << 3));
      f16x8 bl = *(const f16x8*)(pjl + ((nt * 64 + l) << 3));
      dd[nt] = __builtin_amdgcn_mfma_f32_16x16x32_f16(aqh, bh, dd[nt], 0, 0, 0);
      dd[nt] = __builtin_amdgcn_mfma_f32_16x16x32_f16(aqh, bl, dd[nt], 0, 0, 0);
      dd[nt] = __builtin_amdgcn_mfma_f32_16x16x32_f16(aql, bh, dd[nt], 0, 0, 0);
    }
    // row max (mask padding cols f>=110 in nt=6)
    float mrow[4];
#pragma unroll
    for (int r = 0; r < 4; r++) {
      float m = dd[0][r];
#pragma unroll
      for (int nt = 1; nt < 6; nt++) m = fmaxf(m, dd[nt][r]);
      float v6 = (lr < 14) ? dd[6][r] : -3.0e38f;
      mrow[r] = rmax16(fmaxf(m, v6));
    }
    // ksum per col
    float ks[7];
#pragma unroll
    for (int nt = 0; nt < 7; nt++) {
      int f = nt * 16 + lr;
      ks[nt] = (f < F_) ? ksum_g[(b * 2 + hh) * F_ + f] : 0.f;
    }
    // qp + denominator + LDS stage (D-layout, K padded to 128)
    float sp[4] = {0.f, 0.f, 0.f, 0.f};
#pragma unroll
    for (int nt = 0; nt < 7; nt++)
#pragma unroll
      for (int r = 0; r < 4; r++) {
        float e = 0.f;
        if (nt < 6 || lr < 14)
          e = RATIO * (__expf(dd[nt][r] - diag[hh][r] - mrow[r]) + KEPS);
        sp[r] += e * ks[nt];
        _Float16 hi = (_Float16)e;
        ph[(lg * 4 + r) * 136 + nt * 16 + lr] = hi;
        pl[(lg * 4 + r) * 136 + nt * 16 + lr] = (_Float16)(e - (float)hi);
      }
#pragma unroll
    for (int r = 0; r < 4; r++) {           // zero pad cols 112..127
      ph[(lg * 4 + r) * 136 + 112 + lr] = (_Float16)0.f;
      pl[(lg * 4 + r) * 136 + 112 + lr] = (_Float16)0.f;
    }
#pragma unroll
    for (int r = 0; r < 4; r++) dinv[hh][r] = 1.f / rsum16(sp[r]);
    // o = qp @ ctx  (K=128, N=32)
#pragma unroll
    for (int nt = 0; nt < 2; nt++) oreg[hh][nt] = f32x4{0.f, 0.f, 0.f, 0.f};
#pragma unroll
    for (int kb = 0; kb < 4; kb++) {
      f16x8 aph = *(const f16x8*)(ph + lr * 136 + kb * 32 + lg * 8);
      f16x8 apl = *(const f16x8*)(pl + lr * 136 + kb * 32 + lg * 8);
#pragma unroll
      for (int nt = 0; nt < 2; nt++) {
        size_t fi = (size_t)(((b * 2 + hh) * 8 + kb * 2 + nt) * 64 + l) * 8;
        f16x8 bh = *(const f16x8*)(ctxBh + fi);
        f16x8 bl = *(const f16x8*)(ctxBl + fi);
        oreg[hh][nt] = __builtin_amdgcn_mfma_f32_16x16x32_f16(aph, bh, oreg[hh][nt], 0, 0, 0);
        oreg[hh][nt] = __builtin_amdgcn_mfma_f32_16x16x32_f16(aph, bl, oreg[hh][nt], 0, 0, 0);
        oreg[hh][nt] = __builtin_amdgcn_mfma_f32_16x16x32_f16(apl, bh, oreg[hh][nt], 0, 0, 0);
      }
    }
  }
  // ---- o*dinv -> scratch f32 [16][76] (q area now dead) ----
#pragma unroll
  for (int hh = 0; hh < 2; hh++)
#pragma unroll
    for (int nt = 0; nt < 2; nt++)
#pragma unroll
      for (int r = 0; r < 4; r++)
        oS[(lg * 4 + r) * 76 + hh * 32 + nt * 16 + lr] = oreg[hh][nt][r] * dinv[hh][r];
  // ---- G1: D1 = o @ wo (+bo) ----
  f32x4 acc1[4];
#pragma unroll
  for (int nt = 0; nt < 4; nt++) {
    float bb = bo[nt * 16 + lr];
    acc1[nt] = f32x4{bb, bb, bb, bb};
  }
#pragma unroll
  for (int kb = 0; kb < 2; kb++) {
    float4 o0 = *(const float4*)(oS + lr * 76 + kb * 32 + lg * 8);
    float4 o1 = *(const float4*)(oS + lr * 76 + kb * 32 + lg * 8 + 4);
    float ov[8] = {o0.x, o0.y, o0.z, o0.w, o1.x, o1.y, o1.z, o1.w};
    f16x8 aoh, aol;
#pragma unroll
    for (int e = 0; e < 8; e++) {
      _Float16 hi = (_Float16)ov[e];
      aoh[e] = hi; aol[e] = (_Float16)(ov[e] - (float)hi);
    }
#pragma unroll
    for (int nt = 0; nt < 4; nt++) {
      int f = kb * 4 + nt;
      f16x8 bh = *(const f16x8*)(whi + ((f * 64 + l) << 3));
      f16x8 bl = *(const f16x8*)(wlo + ((f * 64 + l) << 3));
      acc1[nt] = __builtin_amdgcn_mfma_f32_16x16x32_f16(aoh, bh, acc1[nt], 0, 0, 0);
      acc1[nt] = __builtin_amdgcn_mfma_f32_16x16x32_f16(aoh, bl, acc1[nt], 0, 0, 0);
      acc1[nt] = __builtin_amdgcn_mfma_f32_16x16x32_f16(aol, bh, acc1[nt], 0, 0, 0);
    }
  }
  // ---- residual + LN2 (D-layout) ----
  float hA[4][4];
#pragma unroll
  for (int nt = 0; nt < 4; nt++)
#pragma unroll
    for (int r = 0; r < 4; r++)
      hA[nt][r] = hbuf[(size_t)(row0 + lg * 4 + r) * 64 + nt * 16 + lr] + acc1[nt][r];
  float mu2[4], rs2[4];
#pragma unroll
  for (int r = 0; r < 4; r++) {
    float t = hA[0][r] + hA[1][r] + hA[2][r] + hA[3][r];
    mu2[r] = rsum16(t) * (1.f / 64.f);
  }
#pragma unroll
  for (int r = 0; r < 4; r++) {
    float t = 0.f;
#pragma unroll
    for (int nt = 0; nt < 4; nt++) { float d = hA[nt][r] - mu2[r]; t += d * d; }
    rs2[r] = rsqrtf(rsum16(t) * (1.f / 64.f) + 1e-5f);
  }
#pragma unroll
  for (int nt = 0; nt < 4; nt++) {
    float gc = ln2g[nt * 16 + lr], bc = ln2b[nt * 16 + lr];
#pragma unroll
    for (int r = 0; r < 4; r++) {
      float yv = (hA[nt][r] - mu2[r]) * rs2[r] * gc + bc;
      _Float16 hi = (_Float16)yv;
      yh[(lg * 4 + r) * 88 + nt * 16 + lr] = hi;
      yl[(lg * 4 + r) * 88 + nt * 16 + lr] = (_Float16)(yv - (float)hi);
    }
  }
  // ---- FF in two N-halves of 128 ----
  const _Float16* w1h = whi + 4096;  const _Float16* w1l = wlo + 4096;
  const _Float16* w2h = whi + 20480; const _Float16* w2l = wlo + 20480;
  f32x4 acc3[4];
#pragma unroll
  for (int nt = 0; nt < 4; nt++) {
    float bb = b2[nt * 16 + lr];
    acc3[nt] = f32x4{bb, bb, bb, bb};
  }
  for (int half = 0; half < 2; half++) {
    f32x4 acc2[8];
#pragma unroll
    for (int nt = 0; nt < 8; nt++) {
      float bb = b1[half * 128 + nt * 16 + lr];
      acc2[nt] = f32x4{bb, bb, bb, bb};
    }
#pragma unroll
    for (int kb = 0; kb < 2; kb++) {
      f16x8 ayh = *(const f16x8*)(yh + lr * 88 + kb * 32 + lg * 8);
      f16x8 ayl = *(const f16x8*)(yl + lr * 88 + kb * 32 + lg * 8);
#pragma unroll
      for (int nt = 0; nt < 8; nt++) {
        int f = kb * 16 + half * 8 + nt;
        f16x8 bh = *(const f16x8*)(w1h + ((f * 64 + l) << 3));
        f16x8 bl = *(const f16x8*)(w1l + ((f * 64 + l) << 3));
        acc2[nt] = __builtin_amdgcn_mfma_f32_16x16x32_f16(ayh, bh, acc2[nt], 0, 0, 0);
        acc2[nt] = __builtin_amdgcn_mfma_f32_16x16x32_f16(ayh, bl, acc2[nt], 0, 0, 0);
        acc2[nt] = __builtin_amdgcn_mfma_f32_16x16x32_f16(ayl, bh, acc2[nt], 0, 0, 0);
      }
    }
#pragma unroll
    for (int nt = 0; nt < 8; nt++)
#pragma unroll
      for (int r = 0; r < 4; r++) {
        float t = acc2[nt][r];
        float gl = 0.5f * t * (1.f + erff(t * 0.70710678118654752f));
        _Float16 hi = (_Float16)gl;
        ph[(lg * 4 + r) * 136 + nt * 16 + lr] = hi;
        pl[(lg * 4 + r) * 136 + nt * 16 + lr] = (_Float16)(gl - (float)hi);
      }
#pragma unroll
    for (int kb2 = 0; kb2 < 4; kb2++) {
      f16x8 ath = *(const f16x8*)(ph + lr * 136 + kb2 * 32 + lg * 8);
      f16x8 atl = *(const f16x8*)(pl + lr * 136 + kb2 * 32 + lg * 8);
#pragma unroll
      for (int nt = 0; nt < 4; nt++) {
        int f = (half * 4 + kb2) * 4 + nt;
        f16x8 bh = *(const f16x8*)(w2h + ((f * 64 + l) << 3));
        f16x8 bl = *(const f16x8*)(w2l + ((f * 64 + l) << 3));
        acc3[nt] = __builtin_amdgcn_mfma_f32_16x16x32_f16(ath, bh, acc3[nt], 0, 0, 0);
        acc3[nt] = __builtin_amdgcn_mfma_f32_16x16x32_f16(ath, bl, acc3[nt], 0, 0, 0);
        acc3[nt] = __builtin_amdgcn_mfma_f32_16x16x32_f16(atl, bh, acc3[nt], 0, 0, 0);
      }
    }
  }
#pragma unroll
  for (int nt = 0; nt < 4; nt++)
#pragma unroll
    for (int r = 0; r < 4; r++)
      hbuf[(size_t)(row0 + lg * 4 + r) * 64 + nt * 16 + lr] = hA[nt][r] + acc3[nt][r];
}

// ---------------- mean over N (partial) ----------------
__global__ __launch_bounds__(256) void k_colsum(const float* __restrict__ hbuf,
                                                float* __restrict__ colsum) {
  __shared__ float red[256];
  int bb = blockIdx.x >> 3, chunk = blockIdx.x & 7;
  int t = threadIdx.x;
  int c = t & 63, r0 = t >> 6;
  size_t base = ((size_t)bb * N_ + chunk * 2048 + r0) * 64 + c;
  float acc = 0.f;
  for (int s = 0; s < 512; s++) acc += hbuf[base + (size_t)s * 256];
  red[t] = acc;
  __syncthreads();
  if (t < 64) {
    float tot = red[t] + red[t + 64] + red[t + 128] + red[t + 192];
    atomicAdd(&colsum[bb * 64 + t], tot);
  }
}

// ---------------- classifier ----------------
__global__ __launch_bounds__(128) void k_logits(const float* __restrict__ colsum,
                                                const float* __restrict__ cw,
                                                const float* __restrict__ cb,
                                                float* __restrict__ out) {
  int t = threadIdx.x;
  if (t < 80) {
    int b = t / 10, kk = t - b * 10;
    float acc = 0.f;
    for (int c = 0; c < 64; c++) acc += colsum[b * 64 + c] * cw[c * 10 + kk];
    out[t] = acc * (1.f / 16384.f) + cb[kk];
  }
}

extern "C" void kernel_launch(void* const* d_in, const int* in_sizes, int n_in,
                              void* d_out, int out_size, void* d_ws, size_t ws_size,
                              hipStream_t stream) {
  const float* x    = (const float*)d_in[0];
  const float* emb  = (const float*)d_in[1];
  const float* ln1g = (const float*)d_in[2];
  const float* ln1b = (const float*)d_in[3];
  const float* wq   = (const float*)d_in[4];
  const float* bq   = (const float*)d_in[5];
  const float* wk   = (const float*)d_in[6];
  const float* bk   = (const float*)d_in[7];
  const float* wv   = (const float*)d_in[8];
  const float* bv   = (const float*)d_in[9];
  const float* wo   = (const float*)d_in[10];
  const float* bo   = (const float*)d_in[11];
  const float* proj = (const float*)d_in[12];
  const float* ln2g = (const float*)d_in[13];
  const float* ln2b = (const float*)d_in[14];
  const float* w1   = (const float*)d_in[15];
  const float* b1   = (const float*)d_in[16];
  const float* w2   = (const float*)d_in[17];
  const float* b2   = (const float*)d_in[18];
  const float* cw   = (const float*)d_in[19];
  const float* cb   = (const float*)d_in[20];

  float* h      = (float*)d_ws;                   // NTOK*64
  float* kb     = h + (size_t)NTOK * 64;          // NTOK*64 (k*dn)
  float* vb     = kb + (size_t)NTOK * 64;         // NTOK*64
  float* ctx    = vb + (size_t)NTOK * 64;         // 16*110*32
  float* ksum   = ctx + 16 * F_ * 32;             // 16*110
  unsigned* kmaxu = (unsigned*)(ksum + 16 * F_);  // 1
  float* colsum = (float*)(kmaxu + 1);            // 512
  uintptr_t wp = (uintptr_t)(colsum + 512);
  wp = (wp + 63) & ~(uintptr_t)63;
  _Float16* whi   = (_Float16*)wp;                // 4*WSEG
  _Float16* wlo   = whi + 4 * WSEG;               // 4*WSEG
  _Float16* ctxBh = wlo + 4 * WSEG;               // 65536
  _Float16* ctxBl = ctxBh + 65536;                // 65536

  hipMemsetAsync(ctx, 0, (size_t)(16 * F_ * 32 + 16 * F_ + 1 + 512) * sizeof(float), stream);
  k_prep<<<(4 * WSEG) / 256, 256, 0, stream>>>(wo, w1, w2, wq, proj, whi, wlo);
  k_embed<<<NTOK * 64 / 256, 256, 0, stream>>>(x, emb, h);
  for (int l = 0; l < 4; l++) {
    if (l) hipMemsetAsync(ctx, 0, (size_t)(16 * F_ * 32 + 16 * F_ + 1) * sizeof(float), stream);
    k_ln_kv<<<NTOK / 128, 512, 0, stream>>>(h, ln1g + 64 * l, ln1b + 64 * l,
                                            wk + 4096 * l, bk + 64 * l,
                                            wv + 4096 * l, bv + 64 * l,
                                            proj + 3520 * l, kb, vb, kmaxu);
    k_kp_ctx<<<NTOK / 128, 256, 0, stream>>>(kb, vb, proj + 3520 * l, kmaxu, ksum, ctx);
    k_ctxprep<<<256, 256, 0, stream>>>(ctx, ctxBh, ctxBl);
    k_attn<<<NTOK / 64, 256, 0, stream>>>(h, whi + (size_t)l * WSEG, wlo + (size_t)l * WSEG,
                                          ctxBh, ctxBl, ksum,
                                          ln1g + 64 * l, ln1b + 64 * l, bq + 64 * l,
                                          bo + 64 * l, ln2g + 64 * l, ln2b + 64 * l,
                                          b1 + 256 * l, b2 + 64 * l);
  }
  k_colsum<<<64, 256, 0, stream>>>(h, colsum);
  k_logits<<<1, 128, 0, stream>>>(colsum, cw, cb, (float*)d_out);
}

// Round 11
// 1272.928 us; speedup vs baseline: 12.0546x; 1.4321x over previous
//
#include <hip/hip_runtime.h>
#include <hip/hip_bf16.h>

// Performer (FAVOR+) classifier, round 10: MFMA k_kp_ctx (dd + ctx^T GEMMs).
// DEPTH=4, HEADS=2, DH=32, DE=64, N=16384, B=8, F=110

constexpr int B_   = 8;
constexpr int N_   = 16384;
constexpr int F_   = 110;
constexpr int NTOK = B_ * N_;          // 131072
constexpr int WSEG = 44544;            // per-layer f16 weight-plane elems
constexpr int CTXE = 16 * 32 * 112;    // ctxT elems (f padded to 112)
constexpr float DN    = 0.42044820762685725f;   // 32^-0.25
constexpr float RATIO = 0.09534625892455922f;   // 110^-0.5
constexpr float KEPS  = 1e-4f;

typedef _Float16 f16x8 __attribute__((ext_vector_type(8)));
typedef float    f32x4 __attribute__((ext_vector_type(4)));

__device__ __forceinline__ float wsum64(float v) {
#pragma unroll
  for (int m = 32; m > 0; m >>= 1) v += __shfl_xor(v, m);
  return v;
}
__device__ __forceinline__ float wmax64(float v) {
#pragma unroll
  for (int m = 32; m > 0; m >>= 1) v = fmaxf(v, __shfl_xor(v, m));
  return v;
}
__device__ __forceinline__ float bcastf(float v, int lane) {
  return __uint_as_float((unsigned)__builtin_amdgcn_readlane((int)__float_as_uint(v), lane));
}
__device__ __forceinline__ float rsum16(float v) {
  v += __shfl_xor(v, 1); v += __shfl_xor(v, 2);
  v += __shfl_xor(v, 4); v += __shfl_xor(v, 8);
  return v;
}
__device__ __forceinline__ float rmax16(float v) {
  v = fmaxf(v, __shfl_xor(v, 1)); v = fmaxf(v, __shfl_xor(v, 2));
  v = fmaxf(v, __shfl_xor(v, 4)); v = fmaxf(v, __shfl_xor(v, 8));
  return v;
}

// ---------------- h = concat(emb_w, x) ----------------
__global__ __launch_bounds__(256) void k_embed(const float* __restrict__ x,
                                               const float* __restrict__ emb,
                                               float* __restrict__ hbuf) {
  int gidx = blockIdx.x * 256 + threadIdx.x;
  int tok = gidx >> 6, c = gidx & 63;
  float v;
  if (c < 63) v = emb[(size_t)(tok & (N_ - 1)) * 63 + c];
  else        v = x[tok];
  hbuf[gidx] = v;
}

// ------ weight prep: wo/w1/w2/wq/proj^T -> hi/lo f16 B-frag planes ------
__global__ __launch_bounds__(256) void k_prep(
    const float* __restrict__ wo, const float* __restrict__ w1, const float* __restrict__ w2,
    const float* __restrict__ wq, const float* __restrict__ proj,
    _Float16* __restrict__ whi, _Float16* __restrict__ wlo) {
  int t = blockIdx.x * 256 + threadIdx.x;
  if (t >= 4 * WSEG) return;
  int l = t / WSEG, r = t % WSEG;
  int rr = r; const float* src; int N; bool tr = false;
  if (rr < 4096)       { src = wo + l * 4096;  N = 64; }
  else if (rr < 20480) { src = w1 + l * 16384; N = 256; rr -= 4096; }
  else if (rr < 36864) { src = w2 + l * 16384; N = 64;  rr -= 20480; }
  else if (rr < 40960) { src = wq + l * 4096;  N = 64;  rr -= 36864; }
  else                 { src = proj + l * 3520; N = 112; tr = true; rr -= 40960; }
  int f = rr >> 9, lane = (rr >> 3) & 63, e = rr & 7;
  int NB = N >> 4;
  int k = (f / NB) * 32 + ((lane >> 4) & 3) * 8 + e;
  int n = (f % NB) * 16 + (lane & 15);
  float v;
  if (tr) v = (n < F_) ? src[n * 32 + k] : 0.f;
  else    v = src[k * N + n];
  _Float16 hi = (_Float16)v;
  _Float16 lo = (_Float16)(v - (float)hi);
  size_t off = (size_t)l * WSEG + r;
  whi[off] = hi; wlo[off] = lo;
}

// ------ ctxT[d][f] -> B-frag hi/lo planes (K=f padded to 128, N=d 32) per (b,head) ------
__global__ __launch_bounds__(256) void k_ctxprep(const float* __restrict__ ctxT_g,
                                                 _Float16* __restrict__ ctxBh,
                                                 _Float16* __restrict__ ctxBl) {
  int t = blockIdx.x * 256 + threadIdx.x;        // 65536 = 16 bh * 8 frag * 64 lane * 8 e
  int e = t & 7, lane = (t >> 3) & 63, frag = (t >> 9) & 7, bh = t >> 12;
  int k = (frag >> 1) * 32 + ((lane >> 4) & 3) * 8 + e;   // f dim
  int n = (frag & 1) * 16 + (lane & 15);                  // d dim
  float v = (k < 112) ? ctxT_g[((size_t)bh * 32 + n) * 112 + k] : 0.f;
  _Float16 hi = (_Float16)v;
  ctxBh[t] = hi; ctxBl[t] = (_Float16)(v - (float)hi);
}

// ---------------- LN + K,V projection + global max of dd_k ----------------
__global__ __launch_bounds__(512) void k_ln_kv(
    const float* __restrict__ hbuf, const float* __restrict__ lng, const float* __restrict__ lnb,
    const float* __restrict__ wk, const float* __restrict__ bk,
    const float* __restrict__ wv, const float* __restrict__ bv,
    const float* __restrict__ proj,
    float* __restrict__ kout, float* __restrict__ vout, unsigned int* __restrict__ kmaxu) {
  __shared__ float wk_s[64 * 64];
  __shared__ float wv_s[64 * 64];
  __shared__ float proj_s[F_ * 33];
  __shared__ float kd_s[8][4][64];
  __shared__ float wm_s[8];
  const int tid = threadIdx.x, w = tid >> 6, j = tid & 63;
  for (int i = tid; i < 64 * 64; i += 512) { wk_s[i] = wk[i]; wv_s[i] = wv[i]; }
  for (int i = tid; i < F_ * 32; i += 512) proj_s[(i >> 5) * 33 + (i & 31)] = proj[i];
  const float gj = lng[j], bj = lnb[j], bkj = bk[j], bvj = bv[j];
  __syncthreads();
  const int tokbase = blockIdx.x * 128 + w * 16;
  float mymax = -3.0e38f;
  for (int q4 = 0; q4 < 4; q4++) {
    const int t0 = tokbase + q4 * 4;
    float yv[4], acck[4], accv[4];
#pragma unroll
    for (int u = 0; u < 4; u++) {
      float hj = hbuf[(size_t)(t0 + u) * 64 + j];
      float mu = wsum64(hj) * (1.f / 64.f);
      float d = hj - mu;
      float var = wsum64(d * d) * (1.f / 64.f);
      yv[u] = d * rsqrtf(var + 1e-5f) * gj + bj;
      acck[u] = bkj; accv[u] = bvj;
    }
    for (int i = 0; i < 64; i++) {
      float wki = wk_s[i * 64 + j], wvi = wv_s[i * 64 + j];
#pragma unroll
      for (int u = 0; u < 4; u++) {
        float yi = bcastf(yv[u], i);
        acck[u] += yi * wki;
        accv[u] += yi * wvi;
      }
    }
#pragma unroll
    for (int u = 0; u < 4; u++) {
      float kd = acck[u] * DN;
      kout[(size_t)(t0 + u) * 64 + j] = kd;
      vout[(size_t)(t0 + u) * 64 + j] = accv[u];
      kd_s[w][u][j] = kd;                     // wave-private
    }
#pragma unroll
    for (int t2 = 0; t2 < 4; t2++) {
      int idx = j + 64 * t2;
      if (idx < 220) {
        int head = (idx >= 110);
        int f = idx - head * 110;
        const float* pr = &proj_s[f * 33];
        const float* kk = &kd_s[w][0][head * 32];
        float dd0 = 0, dd1 = 0, dd2 = 0, dd3 = 0;
#pragma unroll 8
        for (int d = 0; d < 32; d++) {
          float p = pr[d];
          dd0 += kk[d]       * p;
          dd1 += kk[d + 64]  * p;
          dd2 += kk[d + 128] * p;
          dd3 += kk[d + 192] * p;
        }
        mymax = fmaxf(mymax, fmaxf(fmaxf(dd0, dd1), fmaxf(dd2, dd3)));
      }
    }
  }
  mymax = wmax64(mymax);
  if (j == 0) wm_s[w] = mymax;
  __syncthreads();
  if (tid == 0) {
    float m = wm_s[0];
    for (int i = 1; i < 8; i++) m = fmaxf(m, wm_s[i]);
    unsigned u_ = __float_as_uint(m);
    unsigned mm = (u_ & 0x80000000u) ? ~u_ : (u_ | 0x80000000u);
    atomicMax(kmaxu, mm);
  }
}

// ====== MFMA kp features + ctx^T / ksum accumulation ======
// 256 threads = 4 waves; block covers 512 tokens; wave handles 4 tiles of 32.
// dd = k@proj^T (reuses pjh/pjl planes); ctxT[d][f] += v^T @ kp via shfl-built B-frags.
__global__ __launch_bounds__(256) void k_kp_ctx(
    const float* __restrict__ kdbuf, const float* __restrict__ vbuf,
    const _Float16* __restrict__ pjh, const _Float16* __restrict__ pjl,
    const unsigned int* __restrict__ kmaxu,
    float* __restrict__ ksum_g, float* __restrict__ ctxT_g) {
  __shared__ float ctxred[32][113];
  const int tid = threadIdx.x, w = tid >> 6, l = tid & 63;
  const int lr = l & 15, lg = l >> 4;
  const int tok0 = blockIdx.x * 512;
  const int b = tok0 >> 14;
  unsigned mu = *kmaxu;
  float M = (mu & 0x80000000u) ? __uint_as_float(mu ^ 0x80000000u) : __uint_as_float(~mu);

  for (int hh = 0; hh < 2; hh++) {
    for (int i = tid; i < 32 * 113; i += 256) ((float*)ctxred)[i] = 0.f;
    float ksumacc[7];
#pragma unroll
    for (int nf = 0; nf < 7; nf++) ksumacc[nf] = 0.f;
    f32x4 ctxacc[2][7];
#pragma unroll
    for (int mtD = 0; mtD < 2; mtD++)
#pragma unroll
      for (int nf = 0; nf < 7; nf++) ctxacc[mtD][nf] = f32x4{0.f, 0.f, 0.f, 0.f};
    __syncthreads();

    for (int it = 0; it < 4; it++) {
      const int tb = tok0 + it * 128 + w * 32;
      // --- k A-frags (2 token-tiles of 16) + per-token diag ---
      f16x8 kAh[2], kAl[2];
      float diagv[2];
#pragma unroll
      for (int mtT = 0; mtT < 2; mtT++) {
        const float* kp_ = kdbuf + (size_t)(tb + mtT * 16 + lr) * 64 + hh * 32 + lg * 8;
        float4 a0 = *(const float4*)kp_;
        float4 a1 = *(const float4*)(kp_ + 4);
        float kv[8] = {a0.x, a0.y, a0.z, a0.w, a1.x, a1.y, a1.z, a1.w};
        float p = 0.f;
#pragma unroll
        for (int e = 0; e < 8; e++) {
          _Float16 hi = (_Float16)kv[e];
          kAh[mtT][e] = hi; kAl[mtT][e] = (_Float16)(kv[e] - (float)hi);
          p += kv[e] * kv[e];
        }
        p += __shfl_xor(p, 16); p += __shfl_xor(p, 32);   // sum over 32 k-dims
        diagv[mtT] = 0.5f * p;                            // diag for token lr (all lg)
      }
      float diagD[2][4];
#pragma unroll
      for (int mtT = 0; mtT < 2; mtT++)
#pragma unroll
        for (int r = 0; r < 4; r++)
          diagD[mtT][r] = __shfl(diagv[mtT], lg * 4 + r); // diag in D-layout rows
      // --- v^T A-frags for ctx GEMM (row=d, k=token) ---
      f16x8 vAh[2], vAl[2];
#pragma unroll
      for (int mtD = 0; mtD < 2; mtD++) {
        const float* vp_ = vbuf + (size_t)(tb + lg * 8) * 64 + hh * 32 + mtD * 16 + lr;
#pragma unroll
        for (int e = 0; e < 8; e++) {
          float vv = vp_[(size_t)e * 64];
          _Float16 hi = (_Float16)vv;
          vAh[mtD][e] = hi; vAl[mtD][e] = (_Float16)(vv - (float)hi);
        }
      }
      // --- per f-tile: dd -> exp -> ksum -> shfl-build kp B-frag -> ctx mfma ---
#pragma unroll
      for (int nf = 0; nf < 7; nf++) {
        f16x8 bh = *(const f16x8*)(pjh + ((nf * 64 + l) << 3));
        f16x8 bl = *(const f16x8*)(pjl + ((nf * 64 + l) << 3));
        float kpe[2][4];
#pragma unroll
        for (int mtT = 0; mtT < 2; mtT++) {
          f32x4 dd = f32x4{0.f, 0.f, 0.f, 0.f};
          dd = __builtin_amdgcn_mfma_f32_16x16x32_f16(kAh[mtT], bh, dd, 0, 0, 0);
          dd = __builtin_amdgcn_mfma_f32_16x16x32_f16(kAh[mtT], bl, dd, 0, 0, 0);
          dd = __builtin_amdgcn_mfma_f32_16x16x32_f16(kAl[mtT], bh, dd, 0, 0, 0);
#pragma unroll
          for (int r = 0; r < 4; r++) {
            float e_ = RATIO * (__expf(dd[r] - diagD[mtT][r] - M) + KEPS);
            if (nf == 6 && lr >= 14) e_ = 0.f;   // f >= 110 padding
            kpe[mtT][r] = e_;
            ksumacc[nf] += e_;
          }
        }
        // kp B-frag: element e of lane l = kp[token=8*lg+e][f=nf*16+lr]
        f16x8 pbh, pbl;
#pragma unroll
        for (int e = 0; e < 8; e++) {
          int srcl = lr + ((((lg << 1) + (e >> 2)) & 3) << 4);
          float v0 = __shfl(kpe[0][e & 3], srcl);
          float v1 = __shfl(kpe[1][e & 3], srcl);
          float val = (lg >= 2) ? v1 : v0;
          _Float16 hi = (_Float16)val;
          pbh[e] = hi; pbl[e] = (_Float16)(val - (float)hi);
        }
#pragma unroll
        for (int mtD = 0; mtD < 2; mtD++) {
          ctxacc[mtD][nf] = __builtin_amdgcn_mfma_f32_16x16x32_f16(vAh[mtD], pbh, ctxacc[mtD][nf], 0, 0, 0);
          ctxacc[mtD][nf] = __builtin_amdgcn_mfma_f32_16x16x32_f16(vAh[mtD], pbl, ctxacc[mtD][nf], 0, 0, 0);
          ctxacc[mtD][nf] = __builtin_amdgcn_mfma_f32_16x16x32_f16(vAl[mtD], pbh, ctxacc[mtD][nf], 0, 0, 0);
        }
      }
    }
    // --- ksum flush (reduce token-rows across lg groups) ---
#pragma unroll
    for (int nf = 0; nf < 7; nf++) {
      float s = ksumacc[nf];
      s += __shfl_xor(s, 16); s += __shfl_xor(s, 32);
      int f = nf * 16 + lr;
      if (lg == 0 && f < F_) atomicAdd(&ksum_g[(b * 2 + hh) * F_ + f], s);
    }
    // --- ctx block-reduce via LDS, then global flush ---
#pragma unroll
    for (int mtD = 0; mtD < 2; mtD++)
#pragma unroll
      for (int nf = 0; nf < 7; nf++)
#pragma unroll
        for (int r = 0; r < 4; r++)
          atomicAdd(&ctxred[mtD * 16 + lg * 4 + r][nf * 16 + lr], ctxacc[mtD][nf][r]);
    __syncthreads();
    for (int i = tid; i < 32 * 112; i += 256) {
      int d = i / 112, f = i - d * 112;
      atomicAdd(&ctxT_g[((size_t)(b * 2 + hh) * 32 + d) * 112 + f], ctxred[d][f]);
    }
    __syncthreads();
  }
}

// ====== merged MFMA attention: LN1+Qproj+features+o, then wo+LN2+FF ======
__global__ __launch_bounds__(256) void k_attn(
    float* __restrict__ hbuf,
    const _Float16* __restrict__ whi, const _Float16* __restrict__ wlo,  // layer base
    const _Float16* __restrict__ ctxBh, const _Float16* __restrict__ ctxBl,
    const float* __restrict__ ksum_g,
    const float* __restrict__ ln1g, const float* __restrict__ ln1b,
    const float* __restrict__ bq,  const float* __restrict__ bo,
    const float* __restrict__ ln2g, const float* __restrict__ ln2b,
    const float* __restrict__ b1,  const float* __restrict__ b2) {
  __shared__ __align__(16) unsigned char scrA_[4][5632];
  __shared__ __align__(16) unsigned char scrB_[4][8704];
  const int tid = threadIdx.x, w = tid >> 6, l = tid & 63;
  const int lr = l & 15, lg = l >> 4;
  const int row0 = blockIdx.x * 64 + w * 16;
  const int b = (blockIdx.x * 64) >> 14;
  _Float16* qh = (_Float16*)scrA_[w];
  _Float16* ql = qh + 16 * 88;
  float*    oS = (float*)scrA_[w];
  _Float16* yh = (_Float16*)scrA_[w];
  _Float16* yl = yh + 16 * 88;
  _Float16* ph = (_Float16*)scrB_[w];
  _Float16* pl = ph + 16 * 136;

  float hv[16];
#pragma unroll
  for (int kb = 0; kb < 2; kb++) {
    const float* hp = hbuf + (size_t)(row0 + lr) * 64 + kb * 32 + lg * 8;
    float4 p0 = *(const float4*)hp;
    float4 p1 = *(const float4*)(hp + 4);
    hv[kb * 8 + 0] = p0.x; hv[kb * 8 + 1] = p0.y; hv[kb * 8 + 2] = p0.z; hv[kb * 8 + 3] = p0.w;
    hv[kb * 8 + 4] = p1.x; hv[kb * 8 + 5] = p1.y; hv[kb * 8 + 6] = p1.z; hv[kb * 8 + 7] = p1.w;
  }
  float s = 0.f;
#pragma unroll
  for (int i = 0; i < 16; i++) s += hv[i];
  s += __shfl_xor(s, 16); s += __shfl_xor(s, 32);
  float mu1 = s * (1.f / 64.f);
  float sq = 0.f;
#pragma unroll
  for (int i = 0; i < 16; i++) { float d = hv[i] - mu1; sq += d * d; }
  sq += __shfl_xor(sq, 16); sq += __shfl_xor(sq, 32);
  float rs1 = rsqrtf(sq * (1.f / 64.f) + 1e-5f);
  f16x8 ah1[2], al1[2];
#pragma unroll
  for (int kb = 0; kb < 2; kb++) {
    const float* gp = ln1g + kb * 32 + lg * 8;
    const float* bp = ln1b + kb * 32 + lg * 8;
    float4 g0 = *(const float4*)gp, g1 = *(const float4*)(gp + 4);
    float4 b0 = *(const float4*)bp, b1v_ = *(const float4*)(bp + 4);
    float gv[8] = {g0.x, g0.y, g0.z, g0.w, g1.x, g1.y, g1.z, g1.w};
    float bv[8] = {b0.x, b0.y, b0.z, b0.w, b1v_.x, b1v_.y, b1v_.z, b1v_.w};
#pragma unroll
    for (int e = 0; e < 8; e++) {
      float yv = (hv[kb * 8 + e] - mu1) * rs1 * gv[e] + bv[e];
      _Float16 hi = (_Float16)yv;
      ah1[kb][e] = hi;
      al1[kb][e] = (_Float16)(yv - (float)hi);
    }
  }
  const _Float16* wqh = whi + 36864; const _Float16* wql = wlo + 36864;
  f32x4 q[4];
#pragma unroll
  for (int nt = 0; nt < 4; nt++) {
    float bb = bq[nt * 16 + lr];
    q[nt] = f32x4{bb, bb, bb, bb};
  }
#pragma unroll
  for (int kb = 0; kb < 2; kb++)
#pragma unroll
    for (int nt = 0; nt < 4; nt++) {
      int f = kb * 4 + nt;
      f16x8 bh = *(const f16x8*)(wqh + ((f * 64 + l) << 3));
      f16x8 bl = *(const f16x8*)(wql + ((f * 64 + l) << 3));
      q[nt] = __builtin_amdgcn_mfma_f32_16x16x32_f16(ah1[kb], bh, q[nt], 0, 0, 0);
      q[nt] = __builtin_amdgcn_mfma_f32_16x16x32_f16(ah1[kb], bl, q[nt], 0, 0, 0);
      q[nt] = __builtin_amdgcn_mfma_f32_16x16x32_f16(al1[kb], bh, q[nt], 0, 0, 0);
    }
#pragma unroll
  for (int nt = 0; nt < 4; nt++)
#pragma unroll
    for (int r = 0; r < 4; r++) q[nt][r] *= DN;
  float diag[2][4];
#pragma unroll
  for (int hh = 0; hh < 2; hh++)
#pragma unroll
    for (int r = 0; r < 4; r++) {
      float t = q[hh * 2][r] * q[hh * 2][r] + q[hh * 2 + 1][r] * q[hh * 2 + 1][r];
      diag[hh][r] = 0.5f * rsum16(t);
    }
#pragma unroll
  for (int nt = 0; nt < 4; nt++)
#pragma unroll
    for (int r = 0; r < 4; r++) {
      float v = q[nt][r];
      _Float16 hi = (_Float16)v;
      qh[(lg * 4 + r) * 88 + nt * 16 + lr] = hi;
      ql[(lg * 4 + r) * 88 + nt * 16 + lr] = (_Float16)(v - (float)hi);
    }
  const _Float16* pjh = whi + 40960; const _Float16* pjl = wlo + 40960;
  float dinv[2][4];
  f32x4 oreg[2][2];
#pragma unroll
  for (int hh = 0; hh < 2; hh++) {
    f16x8 aqh = *(const f16x8*)(qh + lr * 88 + hh * 32 + lg * 8);
    f16x8 aql = *(const f16x8*)(ql + lr * 88 + hh * 32 + lg * 8);
    f32x4 dd[7];
#pragma unroll
    for (int nt = 0; nt < 7; nt++) {
      dd[nt] = f32x4{0.f, 0.f, 0.f, 0.f};
      f16x8 bh = *(const f16x8*)(pjh + ((nt * 64 + l) << 3));
      f16x8 bl = *(const f16x8*)(pjl + ((nt * 64 + l) << 3));
      dd[nt] = __builtin_amdgcn_mfma_f32_16x16x32_f16(aqh, bh, dd[nt], 0, 0, 0);
      dd[nt] = __builtin_amdgcn_mfma_f32_16x16x32_f16(aqh, bl, dd[nt], 0, 0, 0);
      dd[nt] = __builtin_amdgcn_mfma_f32_16x16x32_f16(aql, bh, dd[nt], 0, 0, 0);
    }
    float mrow[4];
#pragma unroll
    for (int r = 0; r < 4; r++) {
      float m = dd[0][r];
#pragma unroll
      for (int nt = 1; nt < 6; nt++) m = fmaxf(m, dd[nt][r]);
      float v6 = (lr < 14) ? dd[6][r] : -3.0e38f;
      mrow[r] = rmax16(fmaxf(m, v6));
    }
    float ks[7];
#pragma unroll
    for (int nt = 0; nt < 7; nt++) {
      int f = nt * 16 + lr;
      ks[nt] = (f < F_) ? ksum_g[(b * 2 + hh) * F_ + f] : 0.f;
    }
    float sp[4] = {0.f, 0.f, 0.f, 0.f};
#pragma unroll
    for (int nt = 0; nt < 7; nt++)
#pragma unroll
      for (int r = 0; r < 4; r++) {
        float e = 0.f;
        if (nt < 6 || lr < 14)
          e = RATIO * (__expf(dd[nt][r] - diag[hh][r] - mrow[r]) + KEPS);
        sp[r] += e * ks[nt];
        _Float16 hi = (_Float16)e;
        ph[(lg * 4 + r) * 136 + nt * 16 + lr] = hi;
        pl[(lg * 4 + r) * 136 + nt * 16 + lr] = (_Float16)(e - (float)hi);
      }
#pragma unroll
    for (int r = 0; r < 4; r++) {
      ph[(lg * 4 + r) * 136 + 112 + lr] = (_Float16)0.f;
      pl[(lg * 4 + r) * 136 + 112 + lr] = (_Float16)0.f;
    }
#pragma unroll
    for (int r = 0; r < 4; r++) dinv[hh][r] = 1.f / rsum16(sp[r]);
#pragma unroll
    for (int nt = 0; nt < 2; nt++) oreg[hh][nt] = f32x4{0.f, 0.f, 0.f, 0.f};
#pragma unroll
    for (int kb = 0; kb < 4; kb++) {
      f16x8 aph = *(const f16x8*)(ph + lr * 136 + kb * 32 + lg * 8);
      f16x8 apl = *(const f16x8*)(pl + lr * 136 + kb * 32 + lg * 8);
#pragma unroll
      for (int nt = 0; nt < 2; nt++) {
        size_t fi = (size_t)(((b * 2 + hh) * 8 + kb * 2 + nt) * 64 + l) * 8;
        f16x8 bh = *(const f16x8*)(ctxBh + fi);
        f16x8 bl = *(const f16x8*)(ctxBl + fi);
        oreg[hh][nt] = __builtin_amdgcn_mfma_f32_16x16x32_f16(aph, bh, oreg[hh][nt], 0, 0, 0);
        oreg[hh][nt] = __builtin_amdgcn_mfma_f32_16x16x32_f16(aph, bl, oreg[hh][nt], 0, 0, 0);
        oreg[hh][nt] = __builtin_amdgcn_mfma_f32_16x16x32_f16(apl, bh, oreg[hh][nt], 0, 0, 0);
      }
    }
  }
#pragma unroll
  for (int hh = 0; hh < 2; hh++)
#pragma unroll
    for (int nt = 0; nt < 2; nt++)
#pragma unroll
      for (int r = 0; r < 4; r++)
        oS[(lg * 4 + r) * 76 + hh * 32 + nt * 16 + lr] = oreg[hh][nt][r] * dinv[hh][r];
  f32x4 acc1[4];
#pragma unroll
  for (int nt = 0; nt < 4; nt++) {
    float bb = bo[nt * 16 + lr];
    acc1[nt] = f32x4{bb, bb, bb, bb};
  }
#pragma unroll
  for (int kb = 0; kb < 2; kb++) {
    float4 o0 = *(const float4*)(oS + lr * 76 + kb * 32 + lg * 8);
    float4 o1 = *(const float4*)(oS + lr * 76 + kb * 32 + lg * 8 + 4);
    float ov[8] = {o0.x, o0.y, o0.z, o0.w, o1.x, o1.y, o1.z, o1.w};
    f16x8 aoh, aol;
#pragma unroll
    for (int e = 0; e < 8; e++) {
      _Float16 hi = (_Float16)ov[e];
      aoh[e] = hi; aol[e] = (_Float16)(ov[e] - (float)hi);
    }
#pragma unroll
    for (int nt = 0; nt < 4; nt++) {
      int f = kb * 4 + nt;
      f16x8 bh = *(const f16x8*)(whi + ((f * 64 + l) << 3));
      f16x8 bl = *(const f16x8*)(wlo + ((f * 64 + l) << 3));
      acc1[nt] = __builtin_amdgcn_mfma_f32_16x16x32_f16(aoh, bh, acc1[nt], 0, 0, 0);
      acc1[nt] = __builtin_amdgcn_mfma_f32_16x16x32_f16(aoh, bl, acc1[nt], 0, 0, 0);
      acc1[nt] = __builtin_amdgcn_mfma_f32_16x16x32_f16(aol, bh, acc1[nt], 0, 0, 0);
    }
  }
  float hA[4][4];
#pragma unroll
  for (int nt = 0; nt < 4; nt++)
#pragma unroll
    for (int r = 0; r < 4; r++)
      hA[nt][r] = hbuf[(size_t)(row0 + lg * 4 + r) * 64 + nt * 16 + lr] + acc1[nt][r];
  float mu2[4], rs2[4];
#pragma unroll
  for (int r = 0; r < 4; r++) {
    float t = hA[0][r] + hA[1][r] + hA[2][r] + hA[3][r];
    mu2[r] = rsum16(t) * (1.f / 64.f);
  }
#pragma unroll
  for (int r = 0; r < 4; r++) {
    float t = 0.f;
#pragma unroll
    for (int nt = 0; nt < 4; nt++) { float d = hA[nt][r] - mu2[r]; t += d * d; }
    rs2[r] = rsqrtf(rsum16(t) * (1.f / 64.f) + 1e-5f);
  }
#pragma unroll
  for (int nt = 0; nt < 4; nt++) {
    float gc = ln2g[nt * 16 + lr], bc = ln2b[nt * 16 + lr];
#pragma unroll
    for (int r = 0; r < 4; r++) {
      float yv = (hA[nt][r] - mu2[r]) * rs2[r] * gc + bc;
      _Float16 hi = (_Float16)yv;
      yh[(lg * 4 + r) * 88 + nt * 16 + lr] = hi;
      yl[(lg * 4 + r) * 88 + nt * 16 + lr] = (_Float16)(yv - (float)hi);
    }
  }
  const _Float16* w1h = whi + 4096;  const _Float16* w1l = wlo + 4096;
  const _Float16* w2h = whi + 20480; const _Float16* w2l = wlo + 20480;
  f32x4 acc3[4];
#pragma unroll
  for (int nt = 0; nt < 4; nt++) {
    float bb = b2[nt * 16 + lr];
    acc3[nt] = f32x4{bb, bb, bb, bb};
  }
  for (int half = 0; half < 2; half++) {
    f32x4 acc2[8];
#pragma unroll
    for (int nt = 0; nt < 8; nt++) {
      float bb = b1[half * 128 + nt * 16 + lr];
      acc2[nt] = f32x4{bb, bb, bb, bb};
    }
#pragma unroll
    for (int kb = 0; kb < 2; kb++) {
      f16x8 ayh = *(const f16x8*)(yh + lr * 88 + kb * 32 + lg * 8);
      f16x8 ayl = *(const f16x8*)(yl + lr * 88 + kb * 32 + lg * 8);
#pragma unroll
      for (int nt = 0; nt < 8; nt++) {
        int f = kb * 16 + half * 8 + nt;
        f16x8 bh = *(const f16x8*)(w1h + ((f * 64 + l) << 3));
        f16x8 bl = *(const f16x8*)(w1l + ((f * 64 + l) << 3));
        acc2[nt] = __builtin_amdgcn_mfma_f32_16x16x32_f16(ayh, bh, acc2[nt], 0, 0, 0);
        acc2[nt] = __builtin_amdgcn_mfma_f32_16x16x32_f16(ayh, bl, acc2[nt], 0, 0, 0);
        acc2[nt] = __builtin_amdgcn_mfma_f32_16x16x32_f16(ayl, bh, acc2[nt], 0, 0, 0);
      }
    }
#pragma unroll
    for (int nt = 0; nt < 8; nt++)
#pragma unroll
      for (int r = 0; r < 4; r++) {
        float t = acc2[nt][r];
        float gl = 0.5f * t * (1.f + erff(t * 0.70710678118654752f));
        _Float16 hi = (_Float16)gl;
        ph[(lg * 4 + r) * 136 + nt * 16 + lr] = hi;
        pl[(lg * 4 + r) * 136 + nt * 16 + lr] = (_Float16)(gl - (float)hi);
      }
#pragma unroll
    for (int kb2 = 0; kb2 < 4; kb2++) {
      f16x8 ath = *(const f16x8*)(ph + lr * 136 + kb2 * 32 + lg * 8);
      f16x8 atl = *(const f16x8*)(pl + lr * 136 + kb2 * 32 + lg * 8);
#pragma unroll
      for (int nt = 0; nt < 4; nt++) {
        int f = (half * 4 + kb2) * 4 + nt;
        f16x8 bh = *(const f16x8*)(w2h + ((f * 64 + l) << 3));
        f16x8 bl = *(const f16x8*)(w2l + ((f * 64 + l) << 3));
        acc3[nt] = __builtin_amdgcn_mfma_f32_16x16x32_f16(ath, bh, acc3[nt], 0, 0, 0);
        acc3[nt] = __builtin_amdgcn_mfma_f32_16x16x32_f16(ath, bl, acc3[nt], 0, 0, 0);
        acc3[nt] = __builtin_amdgcn_mfma_f32_16x16x32_f16(atl, bh, acc3[nt], 0, 0, 0);
      }
    }
  }
#pragma unroll
  for (int nt = 0; nt < 4; nt++)
#pragma unroll
    for (int r = 0; r < 4; r++)
      hbuf[(size_t)(row0 + lg * 4 + r) * 64 + nt * 16 + lr] = hA[nt][r] + acc3[nt][r];
}

// ---------------- mean over N (partial) ----------------
__global__ __launch_bounds__(256) void k_colsum(const float* __restrict__ hbuf,
                                                float* __restrict__ colsum) {
  __shared__ float red[256];
  int bb = blockIdx.x >> 3, chunk = blockIdx.x & 7;
  int t = threadIdx.x;
  int c = t & 63, r0 = t >> 6;
  size_t base = ((size_t)bb * N_ + chunk * 2048 + r0) * 64 + c;
  float acc = 0.f;
  for (int s = 0; s < 512; s++) acc += hbuf[base + (size_t)s * 256];
  red[t] = acc;
  __syncthreads();
  if (t < 64) {
    float tot = red[t] + red[t + 64] + red[t + 128] + red[t + 192];
    atomicAdd(&colsum[bb * 64 + t], tot);
  }
}

// ---------------- classifier ----------------
__global__ __launch_bounds__(128) void k_logits(const float* __restrict__ colsum,
                                                const float* __restrict__ cw,
                                                const float* __restrict__ cb,
                                                float* __restrict__ out) {
  int t = threadIdx.x;
  if (t < 80) {
    int b = t / 10, kk = t - b * 10;
    float acc = 0.f;
    for (int c = 0; c < 64; c++) acc += colsum[b * 64 + c] * cw[c * 10 + kk];
    out[t] = acc * (1.f / 16384.f) + cb[kk];
  }
}

extern "C" void kernel_launch(void* const* d_in, const int* in_sizes, int n_in,
                              void* d_out, int out_size, void* d_ws, size_t ws_size,
                              hipStream_t stream) {
  const float* x    = (const float*)d_in[0];
  const float* emb  = (const float*)d_in[1];
  const float* ln1g = (const float*)d_in[2];
  const float* ln1b = (const float*)d_in[3];
  const float* wq   = (const float*)d_in[4];
  const float* bq   = (const float*)d_in[5];
  const float* wk   = (const float*)d_in[6];
  const float* bk   = (const float*)d_in[7];
  const float* wv   = (const float*)d_in[8];
  const float* bv   = (const float*)d_in[9];
  const float* wo   = (const float*)d_in[10];
  const float* bo   = (const float*)d_in[11];
  const float* proj = (const float*)d_in[12];
  const float* ln2g = (const float*)d_in[13];
  const float* ln2b = (const float*)d_in[14];
  const float* w1   = (const float*)d_in[15];
  const float* b1   = (const float*)d_in[16];
  const float* w2   = (const float*)d_in[17];
  const float* b2   = (const float*)d_in[18];
  const float* cw   = (const float*)d_in[19];
  const float* cb   = (const float*)d_in[20];

  float* h      = (float*)d_ws;                   // NTOK*64
  float* kb     = h + (size_t)NTOK * 64;          // NTOK*64 (k*dn)
  float* vb     = kb + (size_t)NTOK * 64;         // NTOK*64
  float* ctx    = vb + (size_t)NTOK * 64;         // ctxT: 16*32*112
  float* ksum   = ctx + CTXE;                     // 16*110
  unsigned* kmaxu = (unsigned*)(ksum + 16 * F_);  // 1
  float* colsum = (float*)(kmaxu + 1);            // 512
  uintptr_t wp = (uintptr_t)(colsum + 512);
  wp = (wp + 63) & ~(uintptr_t)63;
  _Float16* whi   = (_Float16*)wp;                // 4*WSEG
  _Float16* wlo   = whi + 4 * WSEG;               // 4*WSEG
  _Float16* ctxBh = wlo + 4 * WSEG;               // 65536
  _Float16* ctxBl = ctxBh + 65536;                // 65536

  hipMemsetAsync(ctx, 0, (size_t)(CTXE + 16 * F_ + 1 + 512) * sizeof(float), stream);
  k_prep<<<(4 * WSEG) / 256, 256, 0, stream>>>(wo, w1, w2, wq, proj, whi, wlo);
  k_embed<<<NTOK * 64 / 256, 256, 0, stream>>>(x, emb, h);
  for (int l = 0; l < 4; l++) {
    if (l) hipMemsetAsync(ctx, 0, (size_t)(CTXE + 16 * F_ + 1) * sizeof(float), stream);
    k_ln_kv<<<NTOK / 128, 512, 0, stream>>>(h, ln1g + 64 * l, ln1b + 64 * l,
                                            wk + 4096 * l, bk + 64 * l,
                                            wv + 4096 * l, bv + 64 * l,
                                            proj + 3520 * l, kb, vb, kmaxu);
    k_kp_ctx<<<NTOK / 512, 256, 0, stream>>>(kb, vb,
                                             whi + (size_t)l * WSEG + 40960,
                                             wlo + (size_t)l * WSEG + 40960,
                                             kmaxu, ksum, ctx);
    k_ctxprep<<<256, 256, 0, stream>>>(ctx, ctxBh, ctxBl);
    k_attn<<<NTOK / 64, 256, 0, stream>>>(h, whi + (size_t)l * WSEG, wlo + (size_t)l * WSEG,
                                          ctxBh, ctxBl, ksum,
                                          ln1g + 64 * l, ln1b + 64 * l, bq + 64 * l,
                                          bo + 64 * l, ln2g + 64 * l, ln2b + 64 * l,
                                          b1 + 256 * l, b2 + 64 * l);
  }
  k_colsum<<<64, 256, 0, stream>>>(h, colsum);
  k_logits<<<1, 128, 0, stream>>>(colsum, cw, cb, (float*)d_out);
}

// Round 12
// 973.665 us; speedup vs baseline: 15.7596x; 1.3074x over previous
//
#include <hip/hip_runtime.h>
#include <hip/hip_bf16.h>

// Performer (FAVOR+) classifier, round 11: MFMA k_ln_kv (LN1 + K/V GEMMs + dd max).
// DEPTH=4, HEADS=2, DH=32, DE=64, N=16384, B=8, F=110

constexpr int B_   = 8;
constexpr int N_   = 16384;
constexpr int F_   = 110;
constexpr int NTOK = B_ * N_;          // 131072
constexpr int WSEG = 52736;            // per-layer f16 weight-plane elems
constexpr int CTXE = 16 * 32 * 112;    // ctxT elems (f padded to 112)
constexpr float DN    = 0.42044820762685725f;   // 32^-0.25
constexpr float RATIO = 0.09534625892455922f;   // 110^-0.5
constexpr float KEPS  = 1e-4f;

typedef _Float16 f16x8 __attribute__((ext_vector_type(8)));
typedef float    f32x4 __attribute__((ext_vector_type(4)));

__device__ __forceinline__ float wsum64(float v) {
#pragma unroll
  for (int m = 32; m > 0; m >>= 1) v += __shfl_xor(v, m);
  return v;
}
__device__ __forceinline__ float wmax64(float v) {
#pragma unroll
  for (int m = 32; m > 0; m >>= 1) v = fmaxf(v, __shfl_xor(v, m));
  return v;
}
__device__ __forceinline__ float rsum16(float v) {
  v += __shfl_xor(v, 1); v += __shfl_xor(v, 2);
  v += __shfl_xor(v, 4); v += __shfl_xor(v, 8);
  return v;
}
__device__ __forceinline__ float rmax16(float v) {
  v = fmaxf(v, __shfl_xor(v, 1)); v = fmaxf(v, __shfl_xor(v, 2));
  v = fmaxf(v, __shfl_xor(v, 4)); v = fmaxf(v, __shfl_xor(v, 8));
  return v;
}

// ---------------- h = concat(emb_w, x) ----------------
__global__ __launch_bounds__(256) void k_embed(const float* __restrict__ x,
                                               const float* __restrict__ emb,
                                               float* __restrict__ hbuf) {
  int gidx = blockIdx.x * 256 + threadIdx.x;
  int tok = gidx >> 6, c = gidx & 63;
  float v;
  if (c < 63) v = emb[(size_t)(tok & (N_ - 1)) * 63 + c];
  else        v = x[tok];
  hbuf[gidx] = v;
}

// ------ weight prep: wo/w1/w2/wq/proj^T/wk/wv -> hi/lo f16 B-frag planes ------
__global__ __launch_bounds__(256) void k_prep(
    const float* __restrict__ wo, const float* __restrict__ w1, const float* __restrict__ w2,
    const float* __restrict__ wq, const float* __restrict__ proj,
    const float* __restrict__ wk, const float* __restrict__ wv,
    _Float16* __restrict__ whi, _Float16* __restrict__ wlo) {
  int t = blockIdx.x * 256 + threadIdx.x;
  if (t >= 4 * WSEG) return;
  int l = t / WSEG, r = t % WSEG;
  int rr = r; const float* src; int N; bool tr = false;
  if (rr < 4096)       { src = wo + l * 4096;  N = 64; }
  else if (rr < 20480) { src = w1 + l * 16384; N = 256; rr -= 4096; }
  else if (rr < 36864) { src = w2 + l * 16384; N = 64;  rr -= 20480; }
  else if (rr < 40960) { src = wq + l * 4096;  N = 64;  rr -= 36864; }
  else if (rr < 44544) { src = proj + l * 3520; N = 112; tr = true; rr -= 40960; }
  else if (rr < 48640) { src = wk + l * 4096;  N = 64;  rr -= 44544; }
  else                 { src = wv + l * 4096;  N = 64;  rr -= 48640; }
  int f = rr >> 9, lane = (rr >> 3) & 63, e = rr & 7;
  int NB = N >> 4;
  int k = (f / NB) * 32 + ((lane >> 4) & 3) * 8 + e;
  int n = (f % NB) * 16 + (lane & 15);
  float v;
  if (tr) v = (n < F_) ? src[n * 32 + k] : 0.f;
  else    v = src[k * N + n];
  _Float16 hi = (_Float16)v;
  _Float16 lo = (_Float16)(v - (float)hi);
  size_t off = (size_t)l * WSEG + r;
  whi[off] = hi; wlo[off] = lo;
}

// ------ ctxT[d][f] -> B-frag hi/lo planes (K=f padded to 128, N=d 32) per (b,head) ------
__global__ __launch_bounds__(256) void k_ctxprep(const float* __restrict__ ctxT_g,
                                                 _Float16* __restrict__ ctxBh,
                                                 _Float16* __restrict__ ctxBl) {
  int t = blockIdx.x * 256 + threadIdx.x;        // 65536 = 16 bh * 8 frag * 64 lane * 8 e
  int e = t & 7, lane = (t >> 3) & 63, frag = (t >> 9) & 7, bh = t >> 12;
  int k = (frag >> 1) * 32 + ((lane >> 4) & 3) * 8 + e;   // f dim
  int n = (frag & 1) * 16 + (lane & 15);                  // d dim
  float v = (k < 112) ? ctxT_g[((size_t)bh * 32 + n) * 112 + k] : 0.f;
  _Float16 hi = (_Float16)v;
  ctxBh[t] = hi; ctxBl[t] = (_Float16)(v - (float)hi);
}

// ====== MFMA LN1 + K,V projection + global max of dd_k ======
// 256 threads = 4 waves; 64 tokens/block; wave w owns rows 16w..16w+15.
__global__ __launch_bounds__(256) void k_ln_kv(
    const float* __restrict__ hbuf, const float* __restrict__ lng, const float* __restrict__ lnb,
    const _Float16* __restrict__ whi, const _Float16* __restrict__ wlo,  // layer base
    const float* __restrict__ bk, const float* __restrict__ bv,
    float* __restrict__ kout, float* __restrict__ vout, unsigned int* __restrict__ kmaxu) {
  __shared__ __align__(16) _Float16 kscr[4][2][16][88];   // [wave][hi/lo][row][col]
  __shared__ float wm_s[4];
  const int tid = threadIdx.x, w = tid >> 6, l = tid & 63;
  const int lr = l & 15, lg = l >> 4;
  const int row0 = blockIdx.x * 64 + w * 16;

  // ---- LN1, distributed ----
  float hv[16];
#pragma unroll
  for (int kb = 0; kb < 2; kb++) {
    const float* hp = hbuf + (size_t)(row0 + lr) * 64 + kb * 32 + lg * 8;
    float4 p0 = *(const float4*)hp;
    float4 p1 = *(const float4*)(hp + 4);
    hv[kb * 8 + 0] = p0.x; hv[kb * 8 + 1] = p0.y; hv[kb * 8 + 2] = p0.z; hv[kb * 8 + 3] = p0.w;
    hv[kb * 8 + 4] = p1.x; hv[kb * 8 + 5] = p1.y; hv[kb * 8 + 6] = p1.z; hv[kb * 8 + 7] = p1.w;
  }
  float s = 0.f;
#pragma unroll
  for (int i = 0; i < 16; i++) s += hv[i];
  s += __shfl_xor(s, 16); s += __shfl_xor(s, 32);
  float mu1 = s * (1.f / 64.f);
  float sq = 0.f;
#pragma unroll
  for (int i = 0; i < 16; i++) { float d = hv[i] - mu1; sq += d * d; }
  sq += __shfl_xor(sq, 16); sq += __shfl_xor(sq, 32);
  float rs1 = rsqrtf(sq * (1.f / 64.f) + 1e-5f);
  f16x8 ah1[2], al1[2];
#pragma unroll
  for (int kb = 0; kb < 2; kb++) {
    const float* gp = lng + kb * 32 + lg * 8;
    const float* bp = lnb + kb * 32 + lg * 8;
    float4 g0 = *(const float4*)gp, g1 = *(const float4*)(gp + 4);
    float4 b0 = *(const float4*)bp, b1v_ = *(const float4*)(bp + 4);
    float gv[8] = {g0.x, g0.y, g0.z, g0.w, g1.x, g1.y, g1.z, g1.w};
    float bv_[8] = {b0.x, b0.y, b0.z, b0.w, b1v_.x, b1v_.y, b1v_.z, b1v_.w};
#pragma unroll
    for (int e = 0; e < 8; e++) {
      float yv = (hv[kb * 8 + e] - mu1) * rs1 * gv[e] + bv_[e];
      _Float16 hi = (_Float16)yv;
      ah1[kb][e] = hi;
      al1[kb][e] = (_Float16)(yv - (float)hi);
    }
  }
  // ---- k = (y@wk + bk)*DN ; v = y@wv + bv  (D-layout) ----
  const _Float16* wkh = whi + 44544; const _Float16* wkl = wlo + 44544;
  const _Float16* wvh = whi + 48640; const _Float16* wvl = wlo + 48640;
  f32x4 ka[4], va[4];
#pragma unroll
  for (int nt = 0; nt < 4; nt++) {
    float bb = bk[nt * 16 + lr];
    ka[nt] = f32x4{bb, bb, bb, bb};
    bb = bv[nt * 16 + lr];
    va[nt] = f32x4{bb, bb, bb, bb};
  }
#pragma unroll
  for (int kb = 0; kb < 2; kb++)
#pragma unroll
    for (int nt = 0; nt < 4; nt++) {
      int f = kb * 4 + nt;
      f16x8 bh = *(const f16x8*)(wkh + ((f * 64 + l) << 3));
      f16x8 bl = *(const f16x8*)(wkl + ((f * 64 + l) << 3));
      ka[nt] = __builtin_amdgcn_mfma_f32_16x16x32_f16(ah1[kb], bh, ka[nt], 0, 0, 0);
      ka[nt] = __builtin_amdgcn_mfma_f32_16x16x32_f16(ah1[kb], bl, ka[nt], 0, 0, 0);
      ka[nt] = __builtin_amdgcn_mfma_f32_16x16x32_f16(al1[kb], bh, ka[nt], 0, 0, 0);
      bh = *(const f16x8*)(wvh + ((f * 64 + l) << 3));
      bl = *(const f16x8*)(wvl + ((f * 64 + l) << 3));
      va[nt] = __builtin_amdgcn_mfma_f32_16x16x32_f16(ah1[kb], bh, va[nt], 0, 0, 0);
      va[nt] = __builtin_amdgcn_mfma_f32_16x16x32_f16(ah1[kb], bl, va[nt], 0, 0, 0);
      va[nt] = __builtin_amdgcn_mfma_f32_16x16x32_f16(al1[kb], bh, va[nt], 0, 0, 0);
    }
  // ---- store k*DN, v ; stage k into LDS for dd ----
#pragma unroll
  for (int nt = 0; nt < 4; nt++)
#pragma unroll
    for (int r = 0; r < 4; r++) {
      float kd = ka[nt][r] * DN;
      size_t idx = (size_t)(row0 + lg * 4 + r) * 64 + nt * 16 + lr;
      kout[idx] = kd;
      vout[idx] = va[nt][r];
      _Float16 hi = (_Float16)kd;
      kscr[w][0][lg * 4 + r][nt * 16 + lr] = hi;
      kscr[w][1][lg * 4 + r][nt * 16 + lr] = (_Float16)(kd - (float)hi);
    }
  // ---- dd = k @ proj^T per head, masked global max ----
  const _Float16* pjh = whi + 40960; const _Float16* pjl = wlo + 40960;
  float mymax = -3.0e38f;
#pragma unroll
  for (int hh = 0; hh < 2; hh++) {
    f16x8 akh = *(const f16x8*)(&kscr[w][0][lr][hh * 32 + lg * 8]);
    f16x8 akl = *(const f16x8*)(&kscr[w][1][lr][hh * 32 + lg * 8]);
#pragma unroll
    for (int nt = 0; nt < 7; nt++) {
      f32x4 dd = f32x4{0.f, 0.f, 0.f, 0.f};
      f16x8 bh = *(const f16x8*)(pjh + ((nt * 64 + l) << 3));
      f16x8 bl = *(const f16x8*)(pjl + ((nt * 64 + l) << 3));
      dd = __builtin_amdgcn_mfma_f32_16x16x32_f16(akh, bh, dd, 0, 0, 0);
      dd = __builtin_amdgcn_mfma_f32_16x16x32_f16(akh, bl, dd, 0, 0, 0);
      dd = __builtin_amdgcn_mfma_f32_16x16x32_f16(akl, bh, dd, 0, 0, 0);
      if (nt < 6 || lr < 14) {
        float m = fmaxf(fmaxf(dd[0], dd[1]), fmaxf(dd[2], dd[3]));
        mymax = fmaxf(mymax, m);
      }
    }
  }
  mymax = wmax64(mymax);
  if (l == 0) wm_s[w] = mymax;
  __syncthreads();
  if (tid == 0) {
    float m = fmaxf(fmaxf(wm_s[0], wm_s[1]), fmaxf(wm_s[2], wm_s[3]));
    unsigned u_ = __float_as_uint(m);
    unsigned mm = (u_ & 0x80000000u) ? ~u_ : (u_ | 0x80000000u);
    atomicMax(kmaxu, mm);
  }
}

// ====== MFMA kp features + ctx^T / ksum accumulation ======
__global__ __launch_bounds__(256) void k_kp_ctx(
    const float* __restrict__ kdbuf, const float* __restrict__ vbuf,
    const _Float16* __restrict__ pjh, const _Float16* __restrict__ pjl,
    const unsigned int* __restrict__ kmaxu,
    float* __restrict__ ksum_g, float* __restrict__ ctxT_g) {
  __shared__ float ctxred[32][113];
  const int tid = threadIdx.x, w = tid >> 6, l = tid & 63;
  const int lr = l & 15, lg = l >> 4;
  const int tok0 = blockIdx.x * 512;
  const int b = tok0 >> 14;
  unsigned mu = *kmaxu;
  float M = (mu & 0x80000000u) ? __uint_as_float(mu ^ 0x80000000u) : __uint_as_float(~mu);

  for (int hh = 0; hh < 2; hh++) {
    for (int i = tid; i < 32 * 113; i += 256) ((float*)ctxred)[i] = 0.f;
    float ksumacc[7];
#pragma unroll
    for (int nf = 0; nf < 7; nf++) ksumacc[nf] = 0.f;
    f32x4 ctxacc[2][7];
#pragma unroll
    for (int mtD = 0; mtD < 2; mtD++)
#pragma unroll
      for (int nf = 0; nf < 7; nf++) ctxacc[mtD][nf] = f32x4{0.f, 0.f, 0.f, 0.f};
    __syncthreads();

    for (int it = 0; it < 4; it++) {
      const int tb = tok0 + it * 128 + w * 32;
      f16x8 kAh[2], kAl[2];
      float diagv[2];
#pragma unroll
      for (int mtT = 0; mtT < 2; mtT++) {
        const float* kp_ = kdbuf + (size_t)(tb + mtT * 16 + lr) * 64 + hh * 32 + lg * 8;
        float4 a0 = *(const float4*)kp_;
        float4 a1 = *(const float4*)(kp_ + 4);
        float kv[8] = {a0.x, a0.y, a0.z, a0.w, a1.x, a1.y, a1.z, a1.w};
        float p = 0.f;
#pragma unroll
        for (int e = 0; e < 8; e++) {
          _Float16 hi = (_Float16)kv[e];
          kAh[mtT][e] = hi; kAl[mtT][e] = (_Float16)(kv[e] - (float)hi);
          p += kv[e] * kv[e];
        }
        p += __shfl_xor(p, 16); p += __shfl_xor(p, 32);
        diagv[mtT] = 0.5f * p;
      }
      float diagD[2][4];
#pragma unroll
      for (int mtT = 0; mtT < 2; mtT++)
#pragma unroll
        for (int r = 0; r < 4; r++)
          diagD[mtT][r] = __shfl(diagv[mtT], lg * 4 + r);
      f16x8 vAh[2], vAl[2];
#pragma unroll
      for (int mtD = 0; mtD < 2; mtD++) {
        const float* vp_ = vbuf + (size_t)(tb + lg * 8) * 64 + hh * 32 + mtD * 16 + lr;
#pragma unroll
        for (int e = 0; e < 8; e++) {
          float vv = vp_[(size_t)e * 64];
          _Float16 hi = (_Float16)vv;
          vAh[mtD][e] = hi; vAl[mtD][e] = (_Float16)(vv - (float)hi);
        }
      }
#pragma unroll
      for (int nf = 0; nf < 7; nf++) {
        f16x8 bh = *(const f16x8*)(pjh + ((nf * 64 + l) << 3));
        f16x8 bl = *(const f16x8*)(pjl + ((nf * 64 + l) << 3));
        float kpe[2][4];
#pragma unroll
        for (int mtT = 0; mtT < 2; mtT++) {
          f32x4 dd = f32x4{0.f, 0.f, 0.f, 0.f};
          dd = __builtin_amdgcn_mfma_f32_16x16x32_f16(kAh[mtT], bh, dd, 0, 0, 0);
          dd = __builtin_amdgcn_mfma_f32_16x16x32_f16(kAh[mtT], bl, dd, 0, 0, 0);
          dd = __builtin_amdgcn_mfma_f32_16x16x32_f16(kAl[mtT], bh, dd, 0, 0, 0);
#pragma unroll
          for (int r = 0; r < 4; r++) {
            float e_ = RATIO * (__expf(dd[r] - diagD[mtT][r] - M) + KEPS);
            if (nf == 6 && lr >= 14) e_ = 0.f;
            kpe[mtT][r] = e_;
            ksumacc[nf] += e_;
          }
        }
        f16x8 pbh, pbl;
#pragma unroll
        for (int e = 0; e < 8; e++) {
          int srcl = lr + ((((lg << 1) + (e >> 2)) & 3) << 4);
          float v0 = __shfl(kpe[0][e & 3], srcl);
          float v1 = __shfl(kpe[1][e & 3], srcl);
          float val = (lg >= 2) ? v1 : v0;
          _Float16 hi = (_Float16)val;
          pbh[e] = hi; pbl[e] = (_Float16)(val - (float)hi);
        }
#pragma unroll
        for (int mtD = 0; mtD < 2; mtD++) {
          ctxacc[mtD][nf] = __builtin_amdgcn_mfma_f32_16x16x32_f16(vAh[mtD], pbh, ctxacc[mtD][nf], 0, 0, 0);
          ctxacc[mtD][nf] = __builtin_amdgcn_mfma_f32_16x16x32_f16(vAh[mtD], pbl, ctxacc[mtD][nf], 0, 0, 0);
          ctxacc[mtD][nf] = __builtin_amdgcn_mfma_f32_16x16x32_f16(vAl[mtD], pbh, ctxacc[mtD][nf], 0, 0, 0);
        }
      }
    }
#pragma unroll
    for (int nf = 0; nf < 7; nf++) {
      float s = ksumacc[nf];
      s += __shfl_xor(s, 16); s += __shfl_xor(s, 32);
      int f = nf * 16 + lr;
      if (lg == 0 && f < F_) atomicAdd(&ksum_g[(b * 2 + hh) * F_ + f], s);
    }
#pragma unroll
    for (int mtD = 0; mtD < 2; mtD++)
#pragma unroll
      for (int nf = 0; nf < 7; nf++)
#pragma unroll
        for (int r = 0; r < 4; r++)
          atomicAdd(&ctxred[mtD * 16 + lg * 4 + r][nf * 16 + lr], ctxacc[mtD][nf][r]);
    __syncthreads();
    for (int i = tid; i < 32 * 112; i += 256) {
      int d = i / 112, f = i - d * 112;
      atomicAdd(&ctxT_g[((size_t)(b * 2 + hh) * 32 + d) * 112 + f], ctxred[d][f]);
    }
    __syncthreads();
  }
}

// ====== merged MFMA attention: LN1+Qproj+features+o, then wo+LN2+FF ======
__global__ __launch_bounds__(256) void k_attn(
    float* __restrict__ hbuf,
    const _Float16* __restrict__ whi, const _Float16* __restrict__ wlo,  // layer base
    const _Float16* __restrict__ ctxBh, const _Float16* __restrict__ ctxBl,
    const float* __restrict__ ksum_g,
    const float* __restrict__ ln1g, const float* __restrict__ ln1b,
    const float* __restrict__ bq,  const float* __restrict__ bo,
    const float* __restrict__ ln2g, const float* __restrict__ ln2b,
    const float* __restrict__ b1,  const float* __restrict__ b2) {
  __shared__ __align__(16) unsigned char scrA_[4][5632];
  __shared__ __align__(16) unsigned char scrB_[4][8704];
  const int tid = threadIdx.x, w = tid >> 6, l = tid & 63;
  const int lr = l & 15, lg = l >> 4;
  const int row0 = blockIdx.x * 64 + w * 16;
  const int b = (blockIdx.x * 64) >> 14;
  _Float16* qh = (_Float16*)scrA_[w];
  _Float16* ql = qh + 16 * 88;
  float*    oS = (float*)scrA_[w];
  _Float16* yh = (_Float16*)scrA_[w];
  _Float16* yl = yh + 16 * 88;
  _Float16* ph = (_Float16*)scrB_[w];
  _Float16* pl = ph + 16 * 136;

  float hv[16];
#pragma unroll
  for (int kb = 0; kb < 2; kb++) {
    const float* hp = hbuf + (size_t)(row0 + lr) * 64 + kb * 32 + lg * 8;
    float4 p0 = *(const float4*)hp;
    float4 p1 = *(const float4*)(hp + 4);
    hv[kb * 8 + 0] = p0.x; hv[kb * 8 + 1] = p0.y; hv[kb * 8 + 2] = p0.z; hv[kb * 8 + 3] = p0.w;
    hv[kb * 8 + 4] = p1.x; hv[kb * 8 + 5] = p1.y; hv[kb * 8 + 6] = p1.z; hv[kb * 8 + 7] = p1.w;
  }
  float s = 0.f;
#pragma unroll
  for (int i = 0; i < 16; i++) s += hv[i];
  s += __shfl_xor(s, 16); s += __shfl_xor(s, 32);
  float mu1 = s * (1.f / 64.f);
  float sq = 0.f;
#pragma unroll
  for (int i = 0; i < 16; i++) { float d = hv[i] - mu1; sq += d * d; }
  sq += __shfl_xor(sq, 16); sq += __shfl_xor(sq, 32);
  float rs1 = rsqrtf(sq * (1.f / 64.f) + 1e-5f);
  f16x8 ah1[2], al1[2];
#pragma unroll
  for (int kb = 0; kb < 2; kb++) {
    const float* gp = ln1g + kb * 32 + lg * 8;
    const float* bp = ln1b + kb * 32 + lg * 8;
    float4 g0 = *(const float4*)gp, g1 = *(const float4*)(gp + 4);
    float4 b0 = *(const float4*)bp, b1v_ = *(const float4*)(bp + 4);
    float gv[8] = {g0.x, g0.y, g0.z, g0.w, g1.x, g1.y, g1.z, g1.w};
    float bv[8] = {b0.x, b0.y, b0.z, b0.w, b1v_.x, b1v_.y, b1v_.z, b1v_.w};
#pragma unroll
    for (int e = 0; e < 8; e++) {
      float yv = (hv[kb * 8 + e] - mu1) * rs1 * gv[e] + bv[e];
      _Float16 hi = (_Float16)yv;
      ah1[kb][e] = hi;
      al1[kb][e] = (_Float16)(yv - (float)hi);
    }
  }
  const _Float16* wqh = whi + 36864; const _Float16* wql = wlo + 36864;
  f32x4 q[4];
#pragma unroll
  for (int nt = 0; nt < 4; nt++) {
    float bb = bq[nt * 16 + lr];
    q[nt] = f32x4{bb, bb, bb, bb};
  }
#pragma unroll
  for (int kb = 0; kb < 2; kb++)
#pragma unroll
    for (int nt = 0; nt < 4; nt++) {
      int f = kb * 4 + nt;
      f16x8 bh = *(const f16x8*)(wqh + ((f * 64 + l) << 3));
      f16x8 bl = *(const f16x8*)(wql + ((f * 64 + l) << 3));
      q[nt] = __builtin_amdgcn_mfma_f32_16x16x32_f16(ah1[kb], bh, q[nt], 0, 0, 0);
      q[nt] = __builtin_amdgcn_mfma_f32_16x16x32_f16(ah1[kb], bl, q[nt], 0, 0, 0);
      q[nt] = __builtin_amdgcn_mfma_f32_16x16x32_f16(al1[kb], bh, q[nt], 0, 0, 0);
    }
#pragma unroll
  for (int nt = 0; nt < 4; nt++)
#pragma unroll
    for (int r = 0; r < 4; r++) q[nt][r] *= DN;
  float diag[2][4];
#pragma unroll
  for (int hh = 0; hh < 2; hh++)
#pragma unroll
    for (int r = 0; r < 4; r++) {
      float t = q[hh * 2][r] * q[hh * 2][r] + q[hh * 2 + 1][r] * q[hh * 2 + 1][r];
      diag[hh][r] = 0.5f * rsum16(t);
    }
#pragma unroll
  for (int nt = 0; nt < 4; nt++)
#pragma unroll
    for (int r = 0; r < 4; r++) {
      float v = q[nt][r];
      _Float16 hi = (_Float16)v;
      qh[(lg * 4 + r) * 88 + nt * 16 + lr] = hi;
      ql[(lg * 4 + r) * 88 + nt * 16 + lr] = (_Float16)(v - (float)hi);
    }
  const _Float16* pjh = whi + 40960; const _Float16* pjl = wlo + 40960;
  float dinv[2][4];
  f32x4 oreg[2][2];
#pragma unroll
  for (int hh = 0; hh < 2; hh++) {
    f16x8 aqh = *(const f16x8*)(qh + lr * 88 + hh * 32 + lg * 8);
    f16x8 aql = *(const f16x8*)(ql + lr * 88 + hh * 32 + lg * 8);
    f32x4 dd[7];
#pragma unroll
    for (int nt = 0; nt < 7; nt++) {
      dd[nt] = f32x4{0.f, 0.f, 0.f, 0.f};
      f16x8 bh = *(const f16x8*)(pjh + ((nt * 64 + l) << 3));
      f16x8 bl = *(const f16x8*)(pjl + ((nt * 64 + l) << 3));
      dd[nt] = __builtin_amdgcn_mfma_f32_16x16x32_f16(aqh, bh, dd[nt], 0, 0, 0);
      dd[nt] = __builtin_amdgcn_mfma_f32_16x16x32_f16(aqh, bl, dd[nt], 0, 0, 0);
      dd[nt] = __builtin_amdgcn_mfma_f32_16x16x32_f16(aql, bh, dd[nt], 0, 0, 0);
    }
    float mrow[4];
#pragma unroll
    for (int r = 0; r < 4; r++) {
      float m = dd[0][r];
#pragma unroll
      for (int nt = 1; nt < 6; nt++) m = fmaxf(m, dd[nt][r]);
      float v6 = (lr < 14) ? dd[6][r] : -3.0e38f;
      mrow[r] = rmax16(fmaxf(m, v6));
    }
    float ks[7];
#pragma unroll
    for (int nt = 0; nt < 7; nt++) {
      int f = nt * 16 + lr;
      ks[nt] = (f < F_) ? ksum_g[(b * 2 + hh) * F_ + f] : 0.f;
    }
    float sp[4] = {0.f, 0.f, 0.f, 0.f};
#pragma unroll
    for (int nt = 0; nt < 7; nt++)
#pragma unroll
      for (int r = 0; r < 4; r++) {
        float e = 0.f;
        if (nt < 6 || lr < 14)
          e = RATIO * (__expf(dd[nt][r] - diag[hh][r] - mrow[r]) + KEPS);
        sp[r] += e * ks[nt];
        _Float16 hi = (_Float16)e;
        ph[(lg * 4 + r) * 136 + nt * 16 + lr] = hi;
        pl[(lg * 4 + r) * 136 + nt * 16 + lr] = (_Float16)(e - (float)hi);
      }
#pragma unroll
    for (int r = 0; r < 4; r++) {
      ph[(lg * 4 + r) * 136 + 112 + lr] = (_Float16)0.f;
      pl[(lg * 4 + r) * 136 + 112 + lr] = (_Float16)0.f;
    }
#pragma unroll
    for (int r = 0; r < 4; r++) dinv[hh][r] = 1.f / rsum16(sp[r]);
#pragma unroll
    for (int nt = 0; nt < 2; nt++) oreg[hh][nt] = f32x4{0.f, 0.f, 0.f, 0.f};
#pragma unroll
    for (int kb = 0; kb < 4; kb++) {
      f16x8 aph = *(const f16x8*)(ph + lr * 136 + kb * 32 + lg * 8);
      f16x8 apl = *(const f16x8*)(pl + lr * 136 + kb * 32 + lg * 8);
#pragma unroll
      for (int nt = 0; nt < 2; nt++) {
        size_t fi = (size_t)(((b * 2 + hh) * 8 + kb * 2 + nt) * 64 + l) * 8;
        f16x8 bh = *(const f16x8*)(ctxBh + fi);
        f16x8 bl = *(const f16x8*)(ctxBl + fi);
        oreg[hh][nt] = __builtin_amdgcn_mfma_f32_16x16x32_f16(aph, bh, oreg[hh][nt], 0, 0, 0);
        oreg[hh][nt] = __builtin_amdgcn_mfma_f32_16x16x32_f16(aph, bl, oreg[hh][nt], 0, 0, 0);
        oreg[hh][nt] = __builtin_amdgcn_mfma_f32_16x16x32_f16(apl, bh, oreg[hh][nt], 0, 0, 0);
      }
    }
  }
#pragma unroll
  for (int hh = 0; hh < 2; hh++)
#pragma unroll
    for (int nt = 0; nt < 2; nt++)
#pragma unroll
      for (int r = 0; r < 4; r++)
        oS[(lg * 4 + r) * 76 + hh * 32 + nt * 16 + lr] = oreg[hh][nt][r] * dinv[hh][r];
  f32x4 acc1[4];
#pragma unroll
  for (int nt = 0; nt < 4; nt++) {
    float bb = bo[nt * 16 + lr];
    acc1[nt] = f32x4{bb, bb, bb, bb};
  }
#pragma unroll
  for (int kb = 0; kb < 2; kb++) {
    float4 o0 = *(const float4*)(oS + lr * 76 + kb * 32 + lg * 8);
    float4 o1 = *(const float4*)(oS + lr * 76 + kb * 32 + lg * 8 + 4);
    float ov[8] = {o0.x, o0.y, o0.z, o0.w, o1.x, o1.y, o1.z, o1.w};
    f16x8 aoh, aol;
#pragma unroll
    for (int e = 0; e < 8; e++) {
      _Float16 hi = (_Float16)ov[e];
      aoh[e] = hi; aol[e] = (_Float16)(ov[e] - (float)hi);
    }
#pragma unroll
    for (int nt = 0; nt < 4; nt++) {
      int f = kb * 4 + nt;
      f16x8 bh = *(const f16x8*)(whi + ((f * 64 + l) << 3));
      f16x8 bl = *(const f16x8*)(wlo + ((f * 64 + l) << 3));
      acc1[nt] = __builtin_amdgcn_mfma_f32_16x16x32_f16(aoh, bh, acc1[nt], 0, 0, 0);
      acc1[nt] = __builtin_amdgcn_mfma_f32_16x16x32_f16(aoh, bl, acc1[nt], 0, 0, 0);
      acc1[nt] = __builtin_amdgcn_mfma_f32_16x16x32_f16(aol, bh, acc1[nt], 0, 0, 0);
    }
  }
  float hA[4][4];
#pragma unroll
  for (int nt = 0; nt < 4; nt++)
#pragma unroll
    for (int r = 0; r < 4; r++)
      hA[nt][r] = hbuf[(size_t)(row0 + lg * 4 + r) * 64 + nt * 16 + lr] + acc1[nt][r];
  float mu2[4], rs2[4];
#pragma unroll
  for (int r = 0; r < 4; r++) {
    float t = hA[0][r] + hA[1][r] + hA[2][r] + hA[3][r];
    mu2[r] = rsum16(t) * (1.f / 64.f);
  }
#pragma unroll
  for (int r = 0; r < 4; r++) {
    float t = 0.f;
#pragma unroll
    for (int nt = 0; nt < 4; nt++) { float d = hA[nt][r] - mu2[r]; t += d * d; }
    rs2[r] = rsqrtf(rsum16(t) * (1.f / 64.f) + 1e-5f);
  }
#pragma unroll
  for (int nt = 0; nt < 4; nt++) {
    float gc = ln2g[nt * 16 + lr], bc = ln2b[nt * 16 + lr];
#pragma unroll
    for (int r = 0; r < 4; r++) {
      float yv = (hA[nt][r] - mu2[r]) * rs2[r] * gc + bc;
      _Float16 hi = (_Float16)yv;
      yh[(lg * 4 + r) * 88 + nt * 16 + lr] = hi;
      yl[(lg * 4 + r) * 88 + nt * 16 + lr] = (_Float16)(yv - (float)hi);
    }
  }
  const _Float16* w1h = whi + 4096;  const _Float16* w1l = wlo + 4096;
  const _Float16* w2h = whi + 20480; const _Float16* w2l = wlo + 20480;
  f32x4 acc3[4];
#pragma unroll
  for (int nt = 0; nt < 4; nt++) {
    float bb = b2[nt * 16 + lr];
    acc3[nt] = f32x4{bb, bb, bb, bb};
  }
  for (int half = 0; half < 2; half++) {
    f32x4 acc2[8];
#pragma unroll
    for (int nt = 0; nt < 8; nt++) {
      float bb = b1[half * 128 + nt * 16 + lr];
      acc2[nt] = f32x4{bb, bb, bb, bb};
    }
#pragma unroll
    for (int kb = 0; kb < 2; kb++) {
      f16x8 ayh = *(const f16x8*)(yh + lr * 88 + kb * 32 + lg * 8);
      f16x8 ayl = *(const f16x8*)(yl + lr * 88 + kb * 32 + lg * 8);
#pragma unroll
      for (int nt = 0; nt < 8; nt++) {
        int f = kb * 16 + half * 8 + nt;
        f16x8 bh = *(const f16x8*)(w1h + ((f * 64 + l) << 3));
        f16x8 bl = *(const f16x8*)(w1l + ((f * 64 + l) << 3));
        acc2[nt] = __builtin_amdgcn_mfma_f32_16x16x32_f16(ayh, bh, acc2[nt], 0, 0, 0);
        acc2[nt] = __builtin_amdgcn_mfma_f32_16x16x32_f16(ayh, bl, acc2[nt], 0, 0, 0);
        acc2[nt] = __builtin_amdgcn_mfma_f32_16x16x32_f16(ayl, bh, acc2[nt], 0, 0, 0);
      }
    }
#pragma unroll
    for (int nt = 0; nt < 8; nt++)
#pragma unroll
      for (int r = 0; r < 4; r++) {
        float t = acc2[nt][r];
        float gl = 0.5f * t * (1.f + erff(t * 0.70710678118654752f));
        _Float16 hi = (_Float16)gl;
        ph[(lg * 4 + r) * 136 + nt * 16 + lr] = hi;
        pl[(lg * 4 + r) * 136 + nt * 16 + lr] = (_Float16)(gl - (float)hi);
      }
#pragma unroll
    for (int kb2 = 0; kb2 < 4; kb2++) {
      f16x8 ath = *(const f16x8*)(ph + lr * 136 + kb2 * 32 + lg * 8);
      f16x8 atl = *(const f16x8*)(pl + lr * 136 + kb2 * 32 + lg * 8);
#pragma unroll
      for (int nt = 0; nt < 4; nt++) {
        int f = (half * 4 + kb2) * 4 + nt;
        f16x8 bh = *(const f16x8*)(w2h + ((f * 64 + l) << 3));
        f16x8 bl = *(const f16x8*)(w2l + ((f * 64 + l) << 3));
        acc3[nt] = __builtin_amdgcn_mfma_f32_16x16x32_f16(ath, bh, acc3[nt], 0, 0, 0);
        acc3[nt] = __builtin_amdgcn_mfma_f32_16x16x32_f16(ath, bl, acc3[nt], 0, 0, 0);
        acc3[nt] = __builtin_amdgcn_mfma_f32_16x16x32_f16(atl, bh, acc3[nt], 0, 0, 0);
      }
    }
  }
#pragma unroll
  for (int nt = 0; nt < 4; nt++)
#pragma unroll
    for (int r = 0; r < 4; r++)
      hbuf[(size_t)(row0 + lg * 4 + r) * 64 + nt * 16 + lr] = hA[nt][r] + acc3[nt][r];
}

// ---------------- mean over N (partial) ----------------
__global__ __launch_bounds__(256) void k_colsum(const float* __restrict__ hbuf,
                                                float* __restrict__ colsum) {
  __shared__ float red[256];
  int bb = blockIdx.x >> 3, chunk = blockIdx.x & 7;
  int t = threadIdx.x;
  int c = t & 63, r0 = t >> 6;
  size_t base = ((size_t)bb * N_ + chunk * 2048 + r0) * 64 + c;
  float acc = 0.f;
  for (int s = 0; s < 512; s++) acc += hbuf[base + (size_t)s * 256];
  red[t] = acc;
  __syncthreads();
  if (t < 64) {
    float tot = red[t] + red[t + 64] + red[t + 128] + red[t + 192];
    atomicAdd(&colsum[bb * 64 + t], tot);
  }
}

// ---------------- classifier ----------------
__global__ __launch_bounds__(128) void k_logits(const float* __restrict__ colsum,
                                                const float* __restrict__ cw,
                                                const float* __restrict__ cb,
                                                float* __restrict__ out) {
  int t = threadIdx.x;
  if (t < 80) {
    int b = t / 10, kk = t - b * 10;
    float acc = 0.f;
    for (int c = 0; c < 64; c++) acc += colsum[b * 64 + c] * cw[c * 10 + kk];
    out[t] = acc * (1.f / 16384.f) + cb[kk];
  }
}

extern "C" void kernel_launch(void* const* d_in, const int* in_sizes, int n_in,
                              void* d_out, int out_size, void* d_ws, size_t ws_size,
                              hipStream_t stream) {
  const float* x    = (const float*)d_in[0];
  const float* emb  = (const float*)d_in[1];
  const float* ln1g = (const float*)d_in[2];
  const float* ln1b = (const float*)d_in[3];
  const float* wq   = (const float*)d_in[4];
  const float* bq   = (const float*)d_in[5];
  const float* wk   = (const float*)d_in[6];
  const float* bk   = (const float*)d_in[7];
  const float* wv   = (const float*)d_in[8];
  const float* bv   = (const float*)d_in[9];
  const float* wo   = (const float*)d_in[10];
  const float* bo   = (const float*)d_in[11];
  const float* proj = (const float*)d_in[12];
  const float* ln2g = (const float*)d_in[13];
  const float* ln2b = (const float*)d_in[14];
  const float* w1   = (const float*)d_in[15];
  const float* b1   = (const float*)d_in[16];
  const float* w2   = (const float*)d_in[17];
  const float* b2   = (const float*)d_in[18];
  const float* cw   = (const float*)d_in[19];
  const float* cb   = (const float*)d_in[20];

  float* h      = (float*)d_ws;                   // NTOK*64
  float* kb     = h + (size_t)NTOK * 64;          // NTOK*64 (k*dn)
  float* vb     = kb + (size_t)NTOK * 64;         // NTOK*64
  float* ctx    = vb + (size_t)NTOK * 64;         // ctxT: 16*32*112
  float* ksum   = ctx + CTXE;                     // 16*110
  unsigned* kmaxu = (unsigned*)(ksum + 16 * F_);  // 1
  float* colsum = (float*)(kmaxu + 1);            // 512
  uintptr_t wp = (uintptr_t)(colsum + 512);
  wp = (wp + 63) & ~(uintptr_t)63;
  _Float16* whi   = (_Float16*)wp;                // 4*WSEG
  _Float16* wlo   = whi + 4 * WSEG;               // 4*WSEG
  _Float16* ctxBh = wlo + 4 * WSEG;               // 65536
  _Float16* ctxBl = ctxBh + 65536;                // 65536

  hipMemsetAsync(ctx, 0, (size_t)(CTXE + 16 * F_ + 1 + 512) * sizeof(float), stream);
  k_prep<<<(4 * WSEG) / 256, 256, 0, stream>>>(wo, w1, w2, wq, proj, wk, wv, whi, wlo);
  k_embed<<<NTOK * 64 / 256, 256, 0, stream>>>(x, emb, h);
  for (int l = 0; l < 4; l++) {
    if (l) hipMemsetAsync(ctx, 0, (size_t)(CTXE + 16 * F_ + 1) * sizeof(float), stream);
    k_ln_kv<<<NTOK / 64, 256, 0, stream>>>(h, ln1g + 64 * l, ln1b + 64 * l,
                                           whi + (size_t)l * WSEG, wlo + (size_t)l * WSEG,
                                           bk + 64 * l, bv + 64 * l, kb, vb, kmaxu);
    k_kp_ctx<<<NTOK / 512, 256, 0, stream>>>(kb, vb,
                                             whi + (size_t)l * WSEG + 40960,
                                             wlo + (size_t)l * WSEG + 40960,
                                             kmaxu, ksum, ctx);
    k_ctxprep<<<256, 256, 0, stream>>>(ctx, ctxBh, ctxBl);
    k_attn<<<NTOK / 64, 256, 0, stream>>>(h, whi + (size_t)l * WSEG, wlo + (size_t)l * WSEG,
                                          ctxBh, ctxBl, ksum,
                                          ln1g + 64 * l, ln1b + 64 * l, bq + 64 * l,
                                          bo + 64 * l, ln2g + 64 * l, ln2b + 64 * l,
                                          b1 + 256 * l, b2 + 64 * l);
  }
  k_colsum<<<64, 256, 0, stream>>>(h, colsum);
  k_logits<<<1, 128, 0, stream>>>(colsum, cw, cb, (float*)d_out);
}